// Round 4
// baseline (820.164 us; speedup 1.0000x reference)
//
#include <hip/hip_runtime.h>

typedef unsigned short u16;
typedef short s16;
typedef s16 s16x8 __attribute__((ext_vector_type(8)));
typedef float f32x4 __attribute__((ext_vector_type(4)));

__device__ __forceinline__ float bf2f(u16 u){
  union { unsigned int i; float f; } v; v.i = ((unsigned int)u) << 16; return v.f;
}
__device__ __forceinline__ u16 f2bf(float f){
  union { float f; unsigned int u; } v; v.f = f;
  unsigned int r = (v.u + 0x7fffu + ((v.u >> 16) & 1u)) >> 16;
  return (u16)r;
}
// packed f32x2 -> bf16x2 (RNE, identical to f2bf) in ONE VALU op
__device__ __forceinline__ unsigned int cvtpk(float lo, float hi){
  unsigned int d;
  asm("v_cvt_pk_bf16_f32 %0, %1, %2" : "=v"(d) : "v"(lo), "v"(hi));
  return d;
}
__device__ __forceinline__ uint4 pack8(float4 a0, float4 a1){
  uint4 v;
  v.x = cvtpk(a0.x, a0.y); v.y = cvtpk(a0.z, a0.w);
  v.z = cvtpk(a1.x, a1.y); v.w = cvtpk(a1.z, a1.w);
  return v;
}
__device__ __forceinline__ float gelu_f(float x){
  return 0.5f * x * (1.f + erff(x * 0.70710678118654752440f));
}
__device__ __forceinline__ float ldw(const void* p, long i, int fl){
  return fl ? bf2f(((const u16*)p)[i]) : ((const float*)p)[i];
}
__device__ __forceinline__ float4 ldw4(const void* p, long i, int fl){
  if (fl){
    ushort4 w = *(const ushort4*)((const u16*)p + i);
    return make_float4(bf2f(w.x), bf2f(w.y), bf2f(w.z), bf2f(w.w));
  }
  return *(const float4*)((const float*)p + i);
}

// ---- DPP 16-lane butterfly reductions (VALU pipe, zero LDS traffic) ----
template<int C>
__device__ __forceinline__ float dppf(float x){
  return __int_as_float(__builtin_amdgcn_update_dpp(0, __float_as_int(x), C, 0xf, 0xf, true));
}
__device__ __forceinline__ float dppmax16(float v){
  v = fmaxf(v, dppf<0xB1>(v));
  v = fmaxf(v, dppf<0x4E>(v));
  v = fmaxf(v, dppf<0x141>(v));
  v = fmaxf(v, dppf<0x140>(v));
  return v;
}
__device__ __forceinline__ float dppsum16(float v){
  v += dppf<0xB1>(v);
  v += dppf<0x4E>(v);
  v += dppf<0x141>(v);
  v += dppf<0x140>(v);
  return v;
}

// ---------------- dtype sniffer (flag[0]=dtype, flag[1]=0 const) --------
__global__ __launch_bounds__(256) void k_sniff(const unsigned int* __restrict__ w,
                                               int n, int* __restrict__ flag){
  __shared__ int cnt[256];
  int c = 0;
  for (int i = threadIdx.x; i < n; i += 256){
    unsigned e = (w[i] >> 7) & 0xFFu;
    c += (e >= 120u && e <= 127u) ? 1 : 0;
  }
  cnt[threadIdx.x] = c; __syncthreads();
  for (int s = 128; s > 0; s >>= 1){
    if (threadIdx.x < s) cnt[threadIdx.x] += cnt[threadIdx.x + s];
    __syncthreads();
  }
  if (threadIdx.x == 0) flag[0] = (2 * cnt[0] > n) ? 1 : 0;
  if (threadIdx.x == 1) flag[1] = 0;
}

// ---- zero-pad xproj (48x256 -> 64x256) / dt_w (256x16 -> 256x64) / dt_b ----
__global__ __launch_bounds__(256) void k_pad(
  const void* __restrict__ wx, const void* __restrict__ wd,
  const void* __restrict__ bd,
  float* __restrict__ px, float* __restrict__ pd, float* __restrict__ pb,
  const int* __restrict__ flagp)
{
  int fl = *flagp;
  int i = blockIdx.x * 256 + threadIdx.x;
  if (i < 16384){
    int r = i >> 8, c = i & 255;
    px[i] = (r < 48) ? ldw(wx, r*256 + c, fl) : 0.f;
  } else if (i < 32768){
    int j = i - 16384;
    int n = j >> 6, k = j & 63;
    pd[j] = (k < 16) ? ldw(wd, n*16 + k, fl) : 0.f;
  } else if (i < 33024){
    pb[i - 32768] = ldw(bd, i - 32768, fl);
  }
}

// ---------------- MFMA GEMM (tile 64*MT x 64, MT=1 or 2) ----------------
// Flag indices select dtype per stream: flagp[idx] (0=input dtype, 1=fp32).
// outmode: 0 fp32, 2 dynamic, 3 bf16, 4 softplus(dt+2*bias) -> Cf, *xc -> C2.
template<int MT>
__global__ __launch_bounds__(256) void k_gemm_mfma_t(
  const void* __restrict__ A, int aflidx, int lda, int K, int N,
  const void* __restrict__ W, const void* __restrict__ W2, int nsplit, int wflidx,
  const void* __restrict__ bias,
  float* __restrict__ Cf, u16* __restrict__ Cb, int ldc,
  float* __restrict__ C2, int ldc2,
  const void* __restrict__ resid, int rflidx, int ldr,
  const void* __restrict__ csrc, int cflidx, float* __restrict__ cdst,
  float oscale, int act_gelu, int outmode, const int* __restrict__ flagp)
{
  const int fl  = flagp[0];
  const int afl = flagp[aflidx];
  const int wfl = flagp[wflidx];
  const int rfl = flagp[rflidx];
  const int cfl = flagp[cflidx];
  __shared__ u16 As[64*MT*72];
  __shared__ u16 Bs[64*72];
  const int tid = threadIdx.x;
  const int w = tid >> 6, lane = tid & 63, quad = lane >> 4, m = lane & 15;
  const int m0 = blockIdx.y * (64*MT), n0 = blockIdx.x << 6;
  const int srow = tid >> 2, sc0 = (tid & 3) << 4;
  const int reg2 = (n0 >= nsplit);
  const void* Wp = reg2 ? W2 : W;
  const int nbase = reg2 ? nsplit : 0;

  f32x4 acc[MT][4];
  #pragma unroll
  for (int rt = 0; rt < MT; ++rt)
    #pragma unroll
    for (int ct = 0; ct < 4; ++ct) acc[rt][ct] = (f32x4){0.f,0.f,0.f,0.f};

  for (int k0 = 0; k0 < K; k0 += 64){
    #pragma unroll
    for (int hh = 0; hh < MT; ++hh){
      long ab = (long)(m0 + hh*64 + srow) * lda + k0 + sc0;
      if (afl && !act_gelu){
        #pragma unroll
        for (int g = 0; g < 2; ++g)
          *(uint4*)&As[(hh*64+srow)*72 + sc0 + g*8] = *(const uint4*)((const u16*)A + ab + g*8);
      } else {
        #pragma unroll
        for (int g = 0; g < 2; ++g){
          float4 a0 = ldw4(A, ab + g*8, afl);
          float4 a1 = ldw4(A, ab + g*8 + 4, afl);
          if (act_gelu){
            a0.x=gelu_f(a0.x); a0.y=gelu_f(a0.y); a0.z=gelu_f(a0.z); a0.w=gelu_f(a0.w);
            a1.x=gelu_f(a1.x); a1.y=gelu_f(a1.y); a1.z=gelu_f(a1.z); a1.w=gelu_f(a1.w);
          }
          *(uint4*)&As[(hh*64+srow)*72 + sc0 + g*8] = pack8(a0, a1);
        }
      }
    }
    {
      long wb = (long)(n0 + srow - nbase) * K + k0 + sc0;
      if (wfl){
        #pragma unroll
        for (int g = 0; g < 2; ++g)
          *(uint4*)&Bs[srow*72 + sc0 + g*8] = *(const uint4*)((const u16*)Wp + wb + g*8);
      } else {
        #pragma unroll
        for (int g = 0; g < 2; ++g){
          float4 b0 = *(const float4*)((const float*)Wp + wb + g*8);
          float4 b1 = *(const float4*)((const float*)Wp + wb + g*8 + 4);
          *(uint4*)&Bs[srow*72 + sc0 + g*8] = pack8(b0, b1);
        }
      }
    }
    __syncthreads();

    s16x8 av[MT][2];
    #pragma unroll
    for (int rt = 0; rt < MT; ++rt)
      #pragma unroll
      for (int s = 0; s < 2; ++s)
        av[rt][s] = *(const s16x8*)&As[(w*16*MT + rt*16 + m)*72 + s*32 + quad*8];
    #pragma unroll
    for (int ct = 0; ct < 4; ++ct)
      #pragma unroll
      for (int s = 0; s < 2; ++s){
        s16x8 bv = *(const s16x8*)&Bs[(ct*16 + m)*72 + s*32 + quad*8];
        #pragma unroll
        for (int rt = 0; rt < MT; ++rt)
          acc[rt][ct] = __builtin_amdgcn_mfma_f32_16x16x32_bf16(av[rt][s], bv, acc[rt][ct], 0, 0, 0);
      }
    __syncthreads();
  }

  #pragma unroll
  for (int rt = 0; rt < MT; ++rt)
  #pragma unroll
  for (int r = 0; r < 4; ++r){
    int gm = m0 + w*16*MT + rt*16 + quad*4 + r;
    #pragma unroll
    for (int ct = 0; ct < 4; ++ct){
      int gn = n0 + ct*16 + m;
      float v = acc[rt][ct][r];
      if (reg2){
        C2[(long)gm * ldc2 + (gn - nsplit)] = v;
      } else if (outmode == 4){
        float bv = ldw(bias, gn, wfl);
        float dl = v + bv + bv;              // dt + 2*dt_bias (ref's double add)
        float delta = (dl > 20.f) ? dl : __logf(1.f + __expf(dl));
        Cf[(long)gm * ldc + gn] = delta;
        C2[(long)gm * ldc2 + gn] = delta * ldw(resid, (long)gm * ldr + gn, rfl);
      } else {
        if (bias) v += ldw(bias, gn, wfl);
        v *= oscale;
        if (resid) v += ldw(resid, (long)gm * ldr + gn, rfl);
        long off = (long)gm * ldc + gn;
        if (outmode == 2){
          if (fl) Cb[off] = f2bf(v); else Cf[off] = v;
        } else if (outmode == 3){
          Cb[off] = f2bf(v);
        } else {
          Cf[off] = v;
        }
        if (cdst) cdst[(long)gm * ldc + gn] = ldw(csrc, (long)gm * 256 + gn, cfl);
      }
    }
  }
}

// ---------------- z-batched MFMA GEMM (up to 4 independent problems) ----------------
// ldwq = weight row stride (elements); wkoff = per-z weight k-offset (split-K).
struct GB4 {
  const float* A[4]; const void* W[4]; const void* bias[4];
  float* Cf[4]; u16* Cb[4]; const float* resid[4];
  const void* csrc[4]; float* cdst[4]; float osc[4]; int cfl[4]; int wkoff[4];
};

template<int MT>
__global__ __launch_bounds__(256) void k_gemmb_t(
  GB4 gb, int lda, int K, int N, int ldc, int ldr, int ldwq,
  int act_gelu, int outmode, const int* __restrict__ flagp)
{
  const int fl = flagp[0];
  const int z = blockIdx.z;
  const float* A = gb.A[z]; const void* W = gb.W[z]; const void* bias = gb.bias[z];
  float* Cf = gb.Cf[z]; u16* Cb = gb.Cb[z]; const float* resid = gb.resid[z];
  const void* csrc = gb.csrc[z]; float* cdst = gb.cdst[z];
  const float osc = gb.osc[z];
  const int cfl = flagp[gb.cfl[z]];
  const int wkoff = gb.wkoff[z];

  __shared__ u16 As[64*MT*72];
  __shared__ u16 Bs[64*72];
  const int tid = threadIdx.x;
  const int w = tid >> 6, lane = tid & 63, quad = lane >> 4, m = lane & 15;
  const int m0 = blockIdx.y * (64*MT), n0 = blockIdx.x << 6;
  const int srow = tid >> 2, sc0 = (tid & 3) << 4;

  f32x4 acc[MT][4];
  #pragma unroll
  for (int rt = 0; rt < MT; ++rt)
    #pragma unroll
    for (int ct = 0; ct < 4; ++ct) acc[rt][ct] = (f32x4){0.f,0.f,0.f,0.f};

  for (int k0 = 0; k0 < K; k0 += 64){
    #pragma unroll
    for (int hh = 0; hh < MT; ++hh){
      const float* ar = A + (long)(m0 + hh*64 + srow) * lda + k0 + sc0;
      #pragma unroll
      for (int g = 0; g < 2; ++g){
        float4 a0 = *(const float4*)(ar + g*8);
        float4 a1 = *(const float4*)(ar + g*8 + 4);
        if (act_gelu){
          a0.x=gelu_f(a0.x); a0.y=gelu_f(a0.y); a0.z=gelu_f(a0.z); a0.w=gelu_f(a0.w);
          a1.x=gelu_f(a1.x); a1.y=gelu_f(a1.y); a1.z=gelu_f(a1.z); a1.w=gelu_f(a1.w);
        }
        *(uint4*)&As[(hh*64+srow)*72 + sc0 + g*8] = pack8(a0, a1);
      }
    }
    {
      long wb = (long)(n0 + srow) * ldwq + wkoff + k0 + sc0;
      if (fl){
        #pragma unroll
        for (int g = 0; g < 2; ++g)
          *(uint4*)&Bs[srow*72 + sc0 + g*8] = *(const uint4*)((const u16*)W + wb + g*8);
      } else {
        #pragma unroll
        for (int g = 0; g < 2; ++g){
          float4 b0 = *(const float4*)((const float*)W + wb + g*8);
          float4 b1 = *(const float4*)((const float*)W + wb + g*8 + 4);
          *(uint4*)&Bs[srow*72 + sc0 + g*8] = pack8(b0, b1);
        }
      }
    }
    __syncthreads();

    s16x8 av[MT][2];
    #pragma unroll
    for (int rt = 0; rt < MT; ++rt)
      #pragma unroll
      for (int s = 0; s < 2; ++s)
        av[rt][s] = *(const s16x8*)&As[(w*16*MT + rt*16 + m)*72 + s*32 + quad*8];
    #pragma unroll
    for (int ct = 0; ct < 4; ++ct)
      #pragma unroll
      for (int s = 0; s < 2; ++s){
        s16x8 bv = *(const s16x8*)&Bs[(ct*16 + m)*72 + s*32 + quad*8];
        #pragma unroll
        for (int rt = 0; rt < MT; ++rt)
          acc[rt][ct] = __builtin_amdgcn_mfma_f32_16x16x32_bf16(av[rt][s], bv, acc[rt][ct], 0, 0, 0);
      }
    __syncthreads();
  }

  #pragma unroll
  for (int rt = 0; rt < MT; ++rt)
  #pragma unroll
  for (int r = 0; r < 4; ++r){
    int gm = m0 + w*16*MT + rt*16 + quad*4 + r;
    #pragma unroll
    for (int ct = 0; ct < 4; ++ct){
      int gn = n0 + ct*16 + m;
      float v = acc[rt][ct][r];
      if (bias) v += ldw(bias, gn, fl);
      v *= osc;
      if (resid) v += resid[(long)gm * ldr + gn];
      long off = (long)gm * ldc + gn;
      if (outmode == 2){
        if (fl) Cb[off] = f2bf(v); else Cf[off] = v;
      } else if (outmode == 3){
        Cb[off] = f2bf(v);
      } else {
        Cf[off] = v;
      }
      if (cdst) cdst[(long)gm * ldc + gn] = ldw(csrc, (long)gm * 256 + gn, cfl);
    }
  }
}

// ---------------- QKV extract + rotary (bf16 out; q pre-scaled by 1/8) ----
__global__ __launch_bounds__(256) void k_rope(
  const float* __restrict__ qkv, const void* __restrict__ pe,
  u16* __restrict__ q, u16* __restrict__ k, u16* __restrict__ v,
  int L, int B, int H, const int* __restrict__ flagp)
{
  int fl = *flagp;
  int tid = threadIdx.x;
  int lq = tid >> 6, d = tid & 63;
  int l = blockIdx.x * 4 + lq;
  int bh = blockIdx.y; int b = bh / H; int h = bh % H;
  const float* row = qkv + ((long)b * L + l) * 768 + h * 192;
  float qv = row[d*3+0], kv = row[d*3+1], vv = row[d*3+2];
  int dn = (d & 1) ? (d - 1) : (d + 1);
  float qn = row[dn*3+0], kn = row[dn*3+1];
  float rq = (d & 1) ? qn : -qn;
  float rk = (d & 1) ? kn : -kn;
  long peo = ((long)b * L + l) * 64 + d;
  float p0 = ldw(pe, peo, fl);
  float p1 = ldw(pe, (long)B * L * 64 + peo, fl);
  long o = ((long)bh * L + l) * 64 + d;
  q[o] = f2bf((qv * p0 + rq * p1) * 0.125f);   // exact pow2 pre-scale
  k[o] = f2bf(kv * p0 + rk * p1);
  v[o] = f2bf(vv);
}

// ---------------- MFMA flash attention, bf16 in / fp32 partials out ------
// K-split via blockIdx.z (NZ=4). Vt/Ps key-block swizzle (bank-conflict-free).
// LDS-pipe-lean: DPP softmax reductions, b64 Vt scatter, b32 packed Ps writes
// (DPP xor1 pair exchange + v_cvt_pk_bf16_f32), defer-max (THR=8),
// separate Ps buffer (wave-private rows) -> 2 barriers per j-iter.
__global__ __launch_bounds__(256, 8) void k_attn_mfma(
  const u16* __restrict__ Q, long qsb, long qsh, long qsl,
  const u16* __restrict__ Kp, long ksb, long ksh, long ksl,
  const u16* __restrict__ Vp, long vsb, long vsh, long vsl,
  float* __restrict__ Opart, float* __restrict__ mpart, float* __restrict__ lpart,
  int L, int H, int kchunk)
{
  __shared__ u16 Kt[64*72];
  __shared__ u16 Vt[64*72];
  __shared__ u16 Ps[64*72];     // wave-private rows: no barrier needed around it
  const int tid  = threadIdx.x;
  const int w    = tid >> 6;
  const int lane = tid & 63;
  const int quad = lane >> 4;
  const int m    = lane & 15;
  const int bh = blockIdx.y, b = bh / H, h = bh % H;
  const int iq0 = blockIdx.x * 64;
  const int z = blockIdx.z;
  const long BHL = (long)gridDim.y * L;

  const u16* Qb = Q  + b*qsb + h*qsh;
  const u16* Kb = Kp + b*ksb + h*ksh;
  const u16* Vb = Vp + b*vsb + h*vsh;

  s16x8 aq[2];
  {
    const u16* qr = Qb + (long)(iq0 + w*16 + m) * qsl + quad*8;
    aq[0] = *(const s16x8*)(qr);
    aq[1] = *(const s16x8*)(qr + 32);
  }

  f32x4 o_acc[4];
  #pragma unroll
  for (int nt = 0; nt < 4; ++nt) o_acc[nt] = (f32x4){0.f,0.f,0.f,0.f};
  float mrow[4] = {-1e30f,-1e30f,-1e30f,-1e30f};
  float lrow[4] = {0.f,0.f,0.f,0.f};

  const int srow = tid >> 2, sc0 = (tid & 3) << 4;
  // Vt b64-packed scatter: thread = (4-key group kg, 4-dim group dg).
  // Invariant layout: Vt[dim*72 + ((2*(dim>>4)+(key>>3))&7)*8 + (key&7)] = V[key][dim]
  const int kg = tid & 15;
  const int dg = tid >> 4;
  const int vcb = ((((dg >> 2) * 2) + (kg >> 1)) & 7) * 8 + (kg & 1) * 4;
  const int modd = m & 1;
  const int pcolb = m & 6;
  const int jend = z * kchunk + kchunk;

  for (int j0 = z * kchunk; j0 < jend; j0 += 64){
    {
      const u16* kr = Kb + (long)(j0 + srow) * ksl + sc0;
      *(uint4*)&Kt[srow*72 + sc0]     = *(const uint4*)kr;
      *(uint4*)&Kt[srow*72 + sc0 + 8] = *(const uint4*)(kr + 8);
      const u16* vr = Vb + (long)(j0 + 4*kg) * vsl + 4*dg;
      ushort4 r0 = *(const ushort4*)(vr);
      ushort4 r1 = *(const ushort4*)(vr + vsl);
      ushort4 r2 = *(const ushort4*)(vr + 2*vsl);
      ushort4 r3 = *(const ushort4*)(vr + 3*vsl);
      u16* vt = &Vt[(4*dg)*72 + vcb];
      *(ushort4*)(vt)       = make_ushort4(r0.x, r1.x, r2.x, r3.x);
      *(ushort4*)(vt + 72)  = make_ushort4(r0.y, r1.y, r2.y, r3.y);
      *(ushort4*)(vt + 144) = make_ushort4(r0.z, r1.z, r2.z, r3.z);
      *(ushort4*)(vt + 216) = make_ushort4(r0.w, r1.w, r2.w, r3.w);
    }
    __syncthreads();

    float sv[4][4];
    #pragma unroll
    for (int ct = 0; ct < 4; ++ct){
      f32x4 acc = (f32x4){0.f,0.f,0.f,0.f};
      #pragma unroll
      for (int s = 0; s < 2; ++s){
        s16x8 bk = *(const s16x8*)&Kt[(ct*16 + m)*72 + s*32 + quad*8];
        acc = __builtin_amdgcn_mfma_f32_16x16x32_bf16(aq[s], bk, acc, 0, 0, 0);
      }
      #pragma unroll
      for (int r = 0; r < 4; ++r) sv[ct][r] = acc[r];
    }

    // tile max per row; defer-max: only rescale when growth > THR=8
    float v0s[4];
    int need = 0;
    #pragma unroll
    for (int r = 0; r < 4; ++r){
      float v0 = fmaxf(fmaxf(sv[0][r], sv[1][r]), fmaxf(sv[2][r], sv[3][r]));
      v0 = dppmax16(v0);
      v0s[r] = v0;
      need |= (v0 > mrow[r] + 8.f) ? 1 : 0;
    }
    if (__any(need)){
      float alpha[4];
      #pragma unroll
      for (int r = 0; r < 4; ++r){
        float mn = fmaxf(mrow[r], v0s[r]);
        alpha[r] = __expf(mrow[r] - mn);
        mrow[r] = mn;
        lrow[r] *= alpha[r];
      }
      #pragma unroll
      for (int nt = 0; nt < 4; ++nt)
        #pragma unroll
        for (int r = 0; r < 4; ++r) o_acc[nt][r] *= alpha[r];
    }
    float rsum[4] = {0.f,0.f,0.f,0.f};
    #pragma unroll
    for (int ct = 0; ct < 4; ++ct)
      #pragma unroll
      for (int r = 0; r < 4; ++r){
        float p = __expf(sv[ct][r] - mrow[r]);
        sv[ct][r] = p;
        rsum[r] += p;
      }
    #pragma unroll
    for (int r = 0; r < 4; ++r)
      lrow[r] += dppsum16(rsum[r]);

    // Ps packed b32 writes: even-m lanes write rows rr/{0,1}, odd-m rows {2,3}.
    // pair = keys (ct*16 + (m&~1), +1); layout identical to scalar version.
    #pragma unroll
    for (int ct = 0; ct < 4; ++ct){
      const int kb = (2*w + 2*ct + (m >> 3)) & 7;
      const int col = (kb << 3) | pcolb;
      #pragma unroll
      for (int rr = 0; rr < 2; ++rr){
        float nb_lo = dppf<0xB1>(sv[ct][rr]);       // neighbor's r=rr
        float nb_hi = dppf<0xB1>(sv[ct][2+rr]);     // neighbor's r=2+rr
        float lo = modd ? nb_hi       : sv[ct][rr];
        float hi = modd ? sv[ct][2+rr] : nb_lo;
        unsigned int pk = cvtpk(lo, hi);
        int row = w*16 + quad*4 + rr + 2*modd;
        *(unsigned int*)&Ps[row*72 + col] = pk;
      }
    }
    asm volatile("s_waitcnt lgkmcnt(0)" ::: "memory");  // own-wave rows RAW

    s16x8 ap[2];
    #pragma unroll
    for (int s = 0; s < 2; ++s)
      ap[s] = *(const s16x8*)&Ps[(w*16 + m)*72 + (((2*w + 4*s + quad) & 7) << 3)];
    #pragma unroll
    for (int nt = 0; nt < 4; ++nt)
      #pragma unroll
      for (int s = 0; s < 2; ++s){
        s16x8 bv = *(const s16x8*)&Vt[(nt*16 + m)*72 + (((2*nt + 4*s + quad) & 7) << 3)];
        o_acc[nt] = __builtin_amdgcn_mfma_f32_16x16x32_bf16(ap[s], bv, o_acc[nt], 0, 0, 0);
      }
    __syncthreads();
  }

  const long zOoff = (long)z * BHL * 64;
  #pragma unroll
  for (int r = 0; r < 4; ++r){
    int iq = iq0 + w*16 + quad*4 + r;
    long rowid = ((long)b*L + iq) * H + h;
    #pragma unroll
    for (int nt = 0; nt < 4; ++nt)
      Opart[zOoff + rowid*64 + nt*16 + m] = o_acc[nt][r];
    if (m == 0){
      mpart[(long)z*BHL + rowid] = mrow[r];
      lpart[(long)z*BHL + rowid] = lrow[r];
    }
  }
}

// ---------------- attention split combine (4-way, fp32 partials) --------
__global__ __launch_bounds__(256) void k_attn_comb(
  const float* Opart, const float* mpart, const float* lpart,
  float* O, long BHL)
{
  long i = (long)blockIdx.x * 256 + threadIdx.x;
  long row = i >> 6;
  float mv[4];
  float M = -1e30f;
  #pragma unroll
  for (int z = 0; z < 4; ++z){
    mv[z] = mpart[(long)z*BHL + row];
    M = fmaxf(M, mv[z]);
  }
  long N64 = BHL * 64;
  float T = 0.f, acc = 0.f;
  #pragma unroll
  for (int z = 0; z < 4; ++z){
    float wz = __expf(mv[z] - M);
    T   += lpart[(long)z*BHL + row] * wz;
    acc += Opart[(long)z*N64 + i] * wz;
  }
  O[i] = acc / T;
}

// ---------------- depthwise conv K=5 SAME + silu (x and z paths batched) --
__global__ __launch_bounds__(256) void k_conv2(
  const float* __restrict__ xz,
  const void* __restrict__ wx, const void* __restrict__ wz,
  float* __restrict__ outx, float* __restrict__ outz,
  int L, const int* __restrict__ flagp)
{
  int fl = *flagp;
  int c = threadIdx.x;
  int bl = blockIdx.x; int b = bl / L, l = bl % L;
  int choff = blockIdx.y ? 256 : 0;
  const void* w = blockIdx.y ? wz : wx;
  float* out = blockIdx.y ? outz : outx;
  const float* base = xz + ((long)b * L) * 512 + choff + c;
  float s = 0.f;
  #pragma unroll
  for (int kk = 0; kk < 5; ++kk){
    int ll = l + kk - 2;
    if (ll >= 0 && ll < L) s += base[(long)ll * 512] * ldw(w, c*5 + kk, fl);
  }
  out[((long)b * L + l) * 256 + c] = s / (1.f + __expf(-s));   // silu
}

// ---------------- chunk-parallel selective scan (xdbl ld 64) ----------------
#define SC_CS 64
#define SC_NC 32

__global__ __launch_bounds__(256) void k_scan1(
  const float* __restrict__ delta, const float* __restrict__ dxc,
  const float* __restrict__ xdbl, const void* __restrict__ Alog,
  float* __restrict__ E_out, float* __restrict__ F_out,
  int L, const int* __restrict__ flagp)
{
  int fl = *flagp;
  int tid = threadIdx.x;
  int g = tid >> 4, n = tid & 15;
  int gid = blockIdx.x * 16 + g;
  int chunk = gid & (SC_NC - 1);
  int p = gid >> 5;
  int b = p >> 8, d = p & 255;
  float A = -__expf(ldw(Alog, d*16 + n, fl));
  const float* dtp = delta + (long)b*L*256 + d;
  const float* dxp = dxc   + (long)b*L*256 + d;
  const float* xdb = xdbl + (long)b*L*64;
  int l0 = chunk * SC_CS;
  float E = 1.f, F = 0.f;
  for (int i = 0; i < SC_CS; i += 4){
    float e[4], u[4];
    #pragma unroll
    for (int j = 0; j < 4; ++j){
      int l = l0 + i + j;
      e[j] = __expf(dtp[(long)l*256] * A);
      u[j] = dxp[(long)l*256] * xdb[l*64 + 16 + n];
    }
    F = e[0]*F + u[0]; F = e[1]*F + u[1];
    F = e[2]*F + u[2]; F = e[3]*F + u[3];
    E *= (e[0]*e[1]) * (e[2]*e[3]);
  }
  long idx = (long)(p*16 + n) * SC_NC + chunk;
  E_out[idx] = E; F_out[idx] = F;
}

__global__ __launch_bounds__(256) void k_scan2(
  const float* __restrict__ E, const float* __restrict__ F,
  float* __restrict__ Hin)
{
  int pn = blockIdx.x * 256 + threadIdx.x;
  const float* Ep = E + (long)pn * SC_NC;
  const float* Fp = F + (long)pn * SC_NC;
  float* Hp = Hin + (long)pn * SC_NC;
  float h = 0.f;
  #pragma unroll
  for (int c = 0; c < SC_NC; ++c){
    Hp[c] = h;
    h = Ep[c] * h + Fp[c];
  }
}

__global__ __launch_bounds__(256) void k_scan3(
  const float* __restrict__ delta, const float* __restrict__ dxc,
  const float* __restrict__ xc, const float* __restrict__ xdbl,
  const void* __restrict__ Alog, const void* __restrict__ Dp,
  const float* __restrict__ Hin, float* __restrict__ y,
  int L, const int* __restrict__ flagp)
{
  int fl = *flagp;
  int tid = threadIdx.x;
  int g = tid >> 4, n = tid & 15;
  int gid = blockIdx.x * 16 + g;
  int chunk = gid & (SC_NC - 1);
  int p = gid >> 5;
  int b = p >> 8, d = p & 255;
  float A = -__expf(ldw(Alog, d*16 + n, fl));
  float Dv = ldw(Dp, d, fl);
  const float* dtp = delta + (long)b*L*256 + d;
  const float* dxp = dxc   + (long)b*L*256 + d;
  const float* xcb = xc    + (long)b*L*256 + d;
  const float* xdb = xdbl + (long)b*L*64;
  float* yb = y + (long)b*L*256 + d;
  long idx = (long)(p*16 + n) * SC_NC + chunk;
  float h = Hin[idx];
  int l0 = chunk * SC_CS;
  for (int i = 0; i < SC_CS; i += 4){
    float e[4], u[4], cm[4], xv[4];
    #pragma unroll
    for (int j = 0; j < 4; ++j){
      int l = l0 + i + j;
      e[j]  = __expf(dtp[(long)l*256] * A);
      u[j]  = dxp[(long)l*256] * xdb[l*64 + 16 + n];
      cm[j] = xdb[l*64 + 32 + n];
      xv[j] = xcb[(long)l*256];
    }
    float s0, s1, s2, s3;
    h = e[0]*h + u[0]; s0 = h * cm[0];
    h = e[1]*h + u[1]; s1 = h * cm[1];
    h = e[2]*h + u[2]; s2 = h * cm[2];
    h = e[3]*h + u[3]; s3 = h * cm[3];
    s0 += __shfl_xor(s0, 1, 16); s1 += __shfl_xor(s1, 1, 16);
    s2 += __shfl_xor(s2, 1, 16); s3 += __shfl_xor(s3, 1, 16);
    s0 += __shfl_xor(s0, 2, 16); s1 += __shfl_xor(s1, 2, 16);
    s2 += __shfl_xor(s2, 2, 16); s3 += __shfl_xor(s3, 2, 16);
    s0 += __shfl_xor(s0, 4, 16); s1 += __shfl_xor(s1, 4, 16);
    s2 += __shfl_xor(s2, 4, 16); s3 += __shfl_xor(s3, 4, 16);
    s0 += __shfl_xor(s0, 8, 16); s1 += __shfl_xor(s1, 8, 16);
    s2 += __shfl_xor(s2, 8, 16); s3 += __shfl_xor(s3, 8, 16);
    if (n < 4){
      float out = (n == 0) ? s0 + Dv*xv[0] : (n == 1) ? s1 + Dv*xv[1]
                : (n == 2) ? s2 + Dv*xv[2] : s3 + Dv*xv[3];
      yb[(long)(l0 + i + n)*256] = out;
    }
  }
}

// ---------------- LayerNorm over rows of 512 (h += h2 partial, in place) --
__global__ __launch_bounds__(256) void k_ln(float* __restrict__ h,
                                            const float* __restrict__ h2,
                                            const void* __restrict__ g,
                                            const void* __restrict__ beta,
                                            const int* __restrict__ flagp)
{
  int fl = *flagp;
  int row = blockIdx.x * 4 + (threadIdx.x >> 6);
  int lane = threadIdx.x & 63;
  float* hr = h + (long)row * 512;
  const float* h2r = h2 + (long)row * 512;
  float v[8]; float s = 0.f, ss = 0.f;
  #pragma unroll
  for (int i = 0; i < 8; ++i){
    v[i] = hr[lane + 64*i] + h2r[lane + 64*i];
    s += v[i]; ss += v[i]*v[i];
  }
  #pragma unroll
  for (int off = 1; off < 64; off <<= 1){ s += __shfl_xor(s, off); ss += __shfl_xor(ss, off); }
  float mean = s * (1.f/512.f);
  float var  = ss * (1.f/512.f) - mean * mean;
  float rs = rsqrtf(var + 1e-5f);
  #pragma unroll
  for (int i = 0; i < 8; ++i){
    int c = lane + 64*i;
    hr[c] = (v[i] - mean) * rs * ldw(g, c, fl) + ldw(beta, c, fl);
  }
}

// two-buffer LN with split-K partial sum (cross-attn i=0/1 batched)
__global__ __launch_bounds__(256) void k_ln2(
  float* __restrict__ hA, const float* __restrict__ hA2,
  float* __restrict__ hB, const float* __restrict__ hB2,
  const void* __restrict__ g, const void* __restrict__ beta,
  const int* __restrict__ flagp)
{
  int fl = *flagp;
  int r = blockIdx.x * 4 + (threadIdx.x >> 6);
  float* hbase = (r < 4096) ? hA : hB;
  const float* h2base = (r < 4096) ? hA2 : hB2;
  int row = r & 4095;
  int lane = threadIdx.x & 63;
  float* hr = hbase + (long)row * 512;
  const float* h2r = h2base + (long)row * 512;
  float v[8]; float s = 0.f, ss = 0.f;
  #pragma unroll
  for (int i = 0; i < 8; ++i){
    v[i] = hr[lane + 64*i] + h2r[lane + 64*i];
    s += v[i]; ss += v[i]*v[i];
  }
  #pragma unroll
  for (int off = 1; off < 64; off <<= 1){ s += __shfl_xor(s, off); ss += __shfl_xor(ss, off); }
  float mean = s * (1.f/512.f);
  float var  = ss * (1.f/512.f) - mean * mean;
  float rs = rsqrtf(var + 1e-5f);
  #pragma unroll
  for (int i = 0; i < 8; ++i){
    int c = lane + 64*i;
    hr[c] = (v[i] - mean) * rs * ldw(g, c, fl) + ldw(beta, c, fl);
  }
}

extern "C" void kernel_launch(void* const* d_in, const int* in_sizes, int n_in,
                              void* d_out, int out_size, void* d_ws, size_t ws_size,
                              hipStream_t stream)
{
  const int B_ = 2, L_ = 2048, H_ = 4;
  const long BLE = (long)B_ * L_ * 256;       // 1,048,576
  const long BHL = (long)B_ * H_ * L_;        // 16,384
  const long SCN = (long)2 * 256 * 16 * SC_NC;

  int* flagp = (int*)d_ws;
  float* base = (float*)d_ws + 64;

  // ---- workspace map (units of BLE fp32 unless noted) ----
  float* P8    = base;
  float* cat   = P8;                      // ld 768 / 1024 (4 BLE max)
  float* xdbl  = P8 + 4*BLE;              // B*L*64
  float* delta = P8 + 5*BLE;              // 1 BLE
  float* scE   = P8 + 6*BLE;
  float* scF   = scE + SCN;
  float* scH   = scE + 2*SCN;             // 3*SCN = 786,432 < 1 BLE
  float* ob    = P8 + 7*BLE;              // attn out
  float* dbuf[2] = { base + 8*BLE, base + 9*BLE };
  float* hbuf  = base + 10*BLE;           // 2 BLE
  float* xcb   = base + 12*BLE;
  float* zcb   = base + 13*BLE;
  float* mml   = base + 14*BLE;           // 8*BHL (z=4 uses 4)
  float* mll   = mml + 8*BHL;             // 8*BHL
  float* px    = mll + 8*BHL;             // 16,384 (xproj padded 64x256)
  float* pd    = px + 16384;              // 16,384 (dt_w padded 256x64)
  float* pb    = pd + 16384;              // 256    (dt_b fp32)

  const void* in[35];
  for (int i = 0; i < 35 && i < n_in; ++i) in[i] = d_in[i];

  k_sniff<<<1, 256, 0, stream>>>((const unsigned int*)in[0], 2048, flagp);
  k_pad<<<130, 256, 0, stream>>>(in[17], in[18], in[19], px, pd, pb, flagp);

  const int BIG = 1 << 30;
  const long sbP = (long)H_ * L_ * 64, shP = (long)L_ * 64, slP = 64;   // (B,H,L,64)
  const long sbF = (long)L_ * 256,     shF = 64,            slF = 256;  // (B,L,256)
  const dim3 gAttn(L_/64, B_*H_, 4);      // z-split 4 (8 was occupancy-neutral, 2x HBM)
  const int kchunk = L_ / 4;

  // ---------------- per-descriptor: mamba_attention ----------------
  for (int i = 0; i < 2; ++i){
    float* d = dbuf[i];
    u16* qm = (u16*)xcb;                  // bf16 q (0.5 BLE)
    u16* km = qm + 1048576;               // bf16 k
    u16* vm = (u16*)zcb;                  // bf16 v
    float* y  = hbuf + BLE;               // scan3 output (1 BLE)
    // merged qkv (N 0..767 -> cat ld 768) + xz (768..1279 -> hbuf ld 512), 128M tile
    k_gemm_mfma_t<2><<<dim3(20, 32), 256, 0, stream>>>(
        in[i], 0, 256, 256, 1280, in[4], in[14], 768, 0, in[5],
        cat, nullptr, 768, hbuf, 512,
        nullptr, 1, 0, nullptr, 1, nullptr,
        1.f, 0, 0, flagp);
    k_rope<<<dim3(L_/4, B_*H_), 256, 0, stream>>>(cat, in[2+i],
        qm, km, vm, L_, B_, H_, flagp);
    k_attn_mfma<<<gAttn, 256, 0, stream>>>(qm, sbP, shP, slP,
                                           km, sbP, shP, slP,
                                           vm, sbP, shP, slP,
                                           P8, mml, mll, L_, H_, kchunk);
    k_attn_comb<<<(int)(BLE/256), 256, 0, stream>>>(P8, mml, mll, ob, BHL);
    k_conv2<<<dim3(B_*L_, 2), 256, 0, stream>>>(hbuf, in[15], in[16], xcb, zcb, L_, flagp);
    // xproj (padded N=64, fp32 weights) into xdbl ld 64
    k_gemm_mfma_t<1><<<dim3(1, 64), 256, 0, stream>>>(
        xcb, 1, 256, 256, 64, px, nullptr, BIG, 1, nullptr,
        xdbl, nullptr, 64, nullptr, 0,
        nullptr, 1, 0, nullptr, 1, nullptr,
        1.f, 0, 0, flagp);
    // dt (padded K=64, fp32 weights+bias) + fused softplus -> delta, dxc
    k_gemm_mfma_t<1><<<dim3(4, 64), 256, 0, stream>>>(
        xdbl, 1, 64, 64, 256, pd, nullptr, BIG, 1, pb,
        delta, nullptr, 256, hbuf, 256,
        xcb, 1, 256, nullptr, 1, nullptr,
        1.f, 0, 4, flagp);
    k_scan1<<<1024, 256, 0, stream>>>(delta, hbuf, xdbl, in[20], scE, scF, L_, flagp);
    k_scan2<<<32, 256, 0, stream>>>(scE, scF, scH);
    k_scan3<<<1024, 256, 0, stream>>>(delta, hbuf, xcb, xdbl, in[20], in[21], scH, y, L_, flagp);
    // batched s_x / c_x / o-proj (+fused raw-input->cat copy) into cat (ld 1024), 128M tile
    {
      GB4 gb = {};
      gb.cfl[0] = gb.cfl[1] = gb.cfl[3] = 1;
      gb.A[0] = y;   gb.W[0] = in[22]; gb.Cf[0] = cat + 512; gb.osc[0] = 1.f;
      gb.A[1] = zcb; gb.W[1] = in[22]; gb.Cf[1] = cat + 768; gb.osc[1] = 1.f;
      gb.A[2] = ob;  gb.W[2] = in[6];  gb.bias[2] = in[7];   gb.Cf[2] = cat + 256;
      gb.csrc[2] = in[i]; gb.cdst[2] = cat; gb.osc[2] = 1.f; gb.cfl[2] = 0;
      k_gemmb_t<2><<<dim3(4, 32, 3), 256, 0, stream>>>(gb, 256, 256, 256, 1024, 0, 256, 0, 0, flagp);
    }
    // ffn1 split-K=2: z0 = cat[:,0:512] @ W[:,0:512]^T (+bias), z1 = rest; 128M tile
    {
      GB4 gb = {};
      gb.cfl[0] = gb.cfl[1] = 1;
      gb.A[0] = cat;       gb.W[0] = in[8]; gb.bias[0] = in[9]; gb.Cf[0] = hbuf; gb.osc[0] = 1.f;
      gb.A[1] = cat + 512; gb.W[1] = in[8]; gb.wkoff[1] = 512;  gb.Cf[1] = xcb;  gb.osc[1] = 1.f;
      k_gemmb_t<2><<<dim3(8, 32, 2), 256, 0, stream>>>(gb, 1024, 512, 512, 512, 0, 1024, 0, 0, flagp);
    }
    k_ln<<<1024, 256, 0, stream>>>(hbuf, xcb, in[10], in[11], flagp);
    // ffn2: gelu(A) @ W^T + bias + raw-input residual (dtype-flag-aware)
    k_gemm_mfma_t<1><<<dim3(4, 64), 256, 0, stream>>>(
        hbuf, 1, 512, 512, 256, in[12], nullptr, BIG, 0, in[13],
        d, nullptr, 256, nullptr, 0,
        in[i], 0, 256, nullptr, 1, nullptr,
        1.f, 1, 0, flagp);
  }

  // ---------------- cross attention ----------------
  const float s4 = 0.35355339059327373f;  // 64^-0.25
  u16* qc = (u16*)hbuf;                   // cross q/k/v/o bf16 pack into hbuf
  u16* kc = qc + 1048576;
  u16* vc = kc + 1048576;
  u16* oc = vc + 1048576;
  float* catA  = P8;                      // ld 512 (2 BLE)
  float* catB  = P8 + 2*BLE;              // ld 512 (2 BLE)
  float* hbufB = P8 + 4*BLE;              // 2 BLE
  float* partB = P8 + 6*BLE;              // 2 BLE
  {
    GB4 gb = {};
    gb.cfl[0] = gb.cfl[1] = gb.cfl[2] = gb.cfl[3] = 1;
    gb.A[0] = dbuf[0]; gb.W[0] = in[23]; gb.bias[0] = in[24]; gb.Cb[0] = qc; gb.osc[0] = s4;
    gb.A[1] = dbuf[1]; gb.W[1] = in[23]; gb.bias[1] = in[24]; gb.Cb[1] = kc; gb.osc[1] = s4;
    gb.A[2] = dbuf[0]; gb.W[2] = in[25]; gb.bias[2] = in[26]; gb.Cb[2] = vc; gb.osc[2] = 1.f;
    gb.A[3] = dbuf[1]; gb.W[3] = in[25]; gb.bias[3] = in[26]; gb.Cb[3] = oc; gb.osc[3] = 1.f;
    k_gemmb_t<2><<<dim3(4, 32, 4), 256, 0, stream>>>(gb, 256, 256, 256, 256, 0, 256, 0, 3, flagp);
  }
  k_attn_mfma<<<gAttn, 256, 0, stream>>>(qc, sbF, shF, slF, kc, sbF, shF, slF,
                                         oc, sbF, shF, slF,
                                         P8, mml, mll, L_, H_, kchunk);
  k_attn_comb<<<(int)(BLE/256), 256, 0, stream>>>(P8, mml, mll, xcb, BHL);
  k_attn_mfma<<<gAttn, 256, 0, stream>>>(kc, sbF, shF, slF, qc, sbF, shF, slF,
                                         vc, sbF, shF, slF,
                                         P8, mml, mll, L_, H_, kchunk);
  k_attn_comb<<<(int)(BLE/256), 256, 0, stream>>>(P8, mml, mll, zcb, BHL);
  {
    GB4 gb = {};
    gb.cfl[0] = gb.cfl[1] = 1;
    gb.A[0] = xcb; gb.W[0] = in[27]; gb.bias[0] = in[28]; gb.Cf[0] = catA + 256;
    gb.csrc[0] = dbuf[0]; gb.cdst[0] = catA; gb.osc[0] = 1.f;
    gb.A[1] = zcb; gb.W[1] = in[27]; gb.bias[1] = in[28]; gb.Cf[1] = catB + 256;
    gb.csrc[1] = dbuf[1]; gb.cdst[1] = catB; gb.osc[1] = 1.f;
    k_gemmb_t<1><<<dim3(4, 64, 2), 256, 0, stream>>>(gb, 256, 256, 256, 512, 0, 256, 0, 0, flagp);
  }
  // ca-ffn1 split-K=2 per descriptor (z=4 total); bias on z0/z2 only; 128M tile
  {
    GB4 gb = {};
    gb.cfl[0] = gb.cfl[1] = gb.cfl[2] = gb.cfl[3] = 1;
    gb.A[0] = catA;       gb.W[0] = in[29]; gb.bias[0] = in[30]; gb.Cf[0] = hbuf;  gb.osc[0] = 1.f;
    gb.A[1] = catA + 256; gb.W[1] = in[29]; gb.wkoff[1] = 256;   gb.Cf[1] = xcb;   gb.osc[1] = 1.f;
    gb.A[2] = catB;       gb.W[2] = in[29]; gb.bias[2] = in[30]; gb.Cf[2] = hbufB; gb.osc[2] = 1.f;
    gb.A[3] = catB + 256; gb.W[3] = in[29]; gb.wkoff[3] = 256;   gb.Cf[3] = partB; gb.osc[3] = 1.f;
    k_gemmb_t<2><<<dim3(8, 32, 4), 256, 0, stream>>>(gb, 512, 256, 512, 512, 0, 512, 0, 0, flagp);
  }
  k_ln2<<<2048, 256, 0, stream>>>(hbuf, xcb, hbufB, partB, in[31], in[32], flagp);
  {
    GB4 gb = {};
    gb.cfl[0] = gb.cfl[1] = 1;
    gb.A[0] = hbuf;  gb.W[0] = in[33]; gb.bias[0] = in[34]; gb.resid[0] = dbuf[0];
    gb.Cf[0] = (float*)d_out; gb.Cb[0] = (u16*)d_out; gb.osc[0] = 1.f;
    gb.A[1] = hbufB; gb.W[1] = in[33]; gb.bias[1] = in[34]; gb.resid[1] = dbuf[1];
    gb.Cf[1] = (float*)d_out + BLE; gb.Cb[1] = (u16*)d_out + BLE; gb.osc[1] = 1.f;
    k_gemmb_t<1><<<dim3(4, 64, 2), 256, 0, stream>>>(gb, 512, 512, 256, 256, 256, 512, 1, 2, flagp);
  }
}

// Round 5
// 803.522 us; speedup vs baseline: 1.0207x; 1.0207x over previous
//
#include <hip/hip_runtime.h>

typedef unsigned short u16;
typedef short s16;
typedef s16 s16x8 __attribute__((ext_vector_type(8)));
typedef float f32x4 __attribute__((ext_vector_type(4)));

__device__ __forceinline__ float bf2f(u16 u){
  union { unsigned int i; float f; } v; v.i = ((unsigned int)u) << 16; return v.f;
}
__device__ __forceinline__ u16 f2bf(float f){
  union { float f; unsigned int u; } v; v.f = f;
  unsigned int r = (v.u + 0x7fffu + ((v.u >> 16) & 1u)) >> 16;
  return (u16)r;
}
// packed f32x2 -> bf16x2 (RNE, identical to f2bf) in ONE VALU op
__device__ __forceinline__ unsigned int cvtpk(float lo, float hi){
  unsigned int d;
  asm("v_cvt_pk_bf16_f32 %0, %1, %2" : "=v"(d) : "v"(lo), "v"(hi));
  return d;
}
__device__ __forceinline__ uint4 pack8(float4 a0, float4 a1){
  uint4 v;
  v.x = cvtpk(a0.x, a0.y); v.y = cvtpk(a0.z, a0.w);
  v.z = cvtpk(a1.x, a1.y); v.w = cvtpk(a1.z, a1.w);
  return v;
}
__device__ __forceinline__ s16x8 pack8v(float4 a0, float4 a1){
  union { uint4 u; s16x8 s; } c;
  c.u = pack8(a0, a1);
  return c.s;
}
__device__ __forceinline__ float gelu_f(float x){
  return 0.5f * x * (1.f + erff(x * 0.70710678118654752440f));
}
__device__ __forceinline__ float4 gelu4(float4 a){
  return make_float4(gelu_f(a.x), gelu_f(a.y), gelu_f(a.z), gelu_f(a.w));
}
__device__ __forceinline__ float ldw(const void* p, long i, int fl){
  return fl ? bf2f(((const u16*)p)[i]) : ((const float*)p)[i];
}
__device__ __forceinline__ float4 ldw4(const void* p, long i, int fl){
  if (fl){
    ushort4 w = *(const ushort4*)((const u16*)p + i);
    return make_float4(bf2f(w.x), bf2f(w.y), bf2f(w.z), bf2f(w.w));
  }
  return *(const float4*)((const float*)p + i);
}

// ---- DPP 16-lane butterfly reductions (VALU pipe, zero LDS traffic) ----
template<int C>
__device__ __forceinline__ float dppf(float x){
  return __int_as_float(__builtin_amdgcn_update_dpp(0, __float_as_int(x), C, 0xf, 0xf, true));
}
__device__ __forceinline__ float dppmax16(float v){
  v = fmaxf(v, dppf<0xB1>(v));
  v = fmaxf(v, dppf<0x4E>(v));
  v = fmaxf(v, dppf<0x141>(v));
  v = fmaxf(v, dppf<0x140>(v));
  return v;
}
__device__ __forceinline__ float dppsum16(float v){
  v += dppf<0xB1>(v);
  v += dppf<0x4E>(v);
  v += dppf<0x141>(v);
  v += dppf<0x140>(v);
  return v;
}

// ---------------- dtype sniffer (flag[0]=dtype, flag[1]=0 const) --------
__global__ __launch_bounds__(256) void k_sniff(const unsigned int* __restrict__ w,
                                               int n, int* __restrict__ flag){
  __shared__ int cnt[256];
  int c = 0;
  for (int i = threadIdx.x; i < n; i += 256){
    unsigned e = (w[i] >> 7) & 0xFFu;
    c += (e >= 120u && e <= 127u) ? 1 : 0;
  }
  cnt[threadIdx.x] = c; __syncthreads();
  for (int s = 128; s > 0; s >>= 1){
    if (threadIdx.x < s) cnt[threadIdx.x] += cnt[threadIdx.x + s];
    __syncthreads();
  }
  if (threadIdx.x == 0) flag[0] = (2 * cnt[0] > n) ? 1 : 0;
  if (threadIdx.x == 1) flag[1] = 0;
}

// ---- zero-pad xproj (48x256 -> 64x256) / dt_w (256x16 -> 256x64) / dt_b ----
__global__ __launch_bounds__(256) void k_pad(
  const void* __restrict__ wx, const void* __restrict__ wd,
  const void* __restrict__ bd,
  float* __restrict__ px, float* __restrict__ pd, float* __restrict__ pb,
  const int* __restrict__ flagp)
{
  int fl = *flagp;
  int i = blockIdx.x * 256 + threadIdx.x;
  if (i < 16384){
    int r = i >> 8, c = i & 255;
    px[i] = (r < 48) ? ldw(wx, r*256 + c, fl) : 0.f;
  } else if (i < 32768){
    int j = i - 16384;
    int n = j >> 6, k = j & 63;
    pd[j] = (k < 16) ? ldw(wd, n*16 + k, fl) : 0.f;
  } else if (i < 33024){
    pb[i - 32768] = ldw(bd, i - 32768, fl);
  }
}

// ---------------- MFMA GEMM (64x64 tile, A-direct: no As LDS) ----------------
// A fragments load straight from global per lane (same cache lines staging
// read; As tile had no cross-wave reuse). Bs keeps LDS (4-wave reuse).
// outmode: 0 fp32, 2 dynamic, 3 bf16, 4 softplus(dt+2*bias) -> Cf, *xc -> C2.
__global__ __launch_bounds__(256) void k_gemm_mfma(
  const void* __restrict__ A, int aflidx, int lda, int K, int N,
  const void* __restrict__ W, const void* __restrict__ W2, int nsplit, int wflidx,
  const void* __restrict__ bias,
  float* __restrict__ Cf, u16* __restrict__ Cb, int ldc,
  float* __restrict__ C2, int ldc2,
  const void* __restrict__ resid, int rflidx, int ldr,
  const void* __restrict__ csrc, int cflidx, float* __restrict__ cdst,
  float oscale, int act_gelu, int outmode, const int* __restrict__ flagp)
{
  const int fl  = flagp[0];
  const int afl = flagp[aflidx];
  const int wfl = flagp[wflidx];
  const int rfl = flagp[rflidx];
  const int cfl = flagp[cflidx];
  __shared__ u16 Bs[64*72];
  const int tid = threadIdx.x;
  const int w = tid >> 6, lane = tid & 63, quad = lane >> 4, m = lane & 15;
  const int m0 = blockIdx.y << 6, n0 = blockIdx.x << 6;
  const int srow = tid >> 2, sc0 = (tid & 3) << 4;
  const int reg2 = (n0 >= nsplit);
  const void* Wp = reg2 ? W2 : W;
  const int nbase = reg2 ? nsplit : 0;
  const long arow = (long)(m0 + w*16 + m) * lda;   // this lane's A row

  f32x4 acc[4];
  #pragma unroll
  for (int ct = 0; ct < 4; ++ct) acc[ct] = (f32x4){0.f,0.f,0.f,0.f};

  for (int k0 = 0; k0 < K; k0 += 64){
    {
      long wb = (long)(n0 + srow - nbase) * K + k0 + sc0;
      if (wfl){
        #pragma unroll
        for (int g = 0; g < 2; ++g)
          *(uint4*)&Bs[srow*72 + sc0 + g*8] = *(const uint4*)((const u16*)Wp + wb + g*8);
      } else {
        #pragma unroll
        for (int g = 0; g < 2; ++g){
          float4 b0 = *(const float4*)((const float*)Wp + wb + g*8);
          float4 b1 = *(const float4*)((const float*)Wp + wb + g*8 + 4);
          *(uint4*)&Bs[srow*72 + sc0 + g*8] = pack8(b0, b1);
        }
      }
    }
    // A-direct fragment load (no LDS)
    s16x8 av[2];
    if (afl && !act_gelu){
      const u16* ar = (const u16*)A + arow + k0 + quad*8;
      av[0] = *(const s16x8*)(ar);
      av[1] = *(const s16x8*)(ar + 32);
    } else {
      #pragma unroll
      for (int s = 0; s < 2; ++s){
        float4 a0 = ldw4(A, arow + k0 + s*32 + quad*8, afl);
        float4 a1 = ldw4(A, arow + k0 + s*32 + quad*8 + 4, afl);
        if (act_gelu){ a0 = gelu4(a0); a1 = gelu4(a1); }
        av[s] = pack8v(a0, a1);
      }
    }
    __syncthreads();

    #pragma unroll
    for (int ct = 0; ct < 4; ++ct)
      #pragma unroll
      for (int s = 0; s < 2; ++s){
        s16x8 bv = *(const s16x8*)&Bs[(ct*16 + m)*72 + s*32 + quad*8];
        acc[ct] = __builtin_amdgcn_mfma_f32_16x16x32_bf16(av[s], bv, acc[ct], 0, 0, 0);
      }
    __syncthreads();
  }

  #pragma unroll
  for (int r = 0; r < 4; ++r){
    int gm = m0 + w*16 + quad*4 + r;
    #pragma unroll
    for (int ct = 0; ct < 4; ++ct){
      int gn = n0 + ct*16 + m;
      float v = acc[ct][r];
      if (reg2){
        C2[(long)gm * ldc2 + (gn - nsplit)] = v;
      } else if (outmode == 4){
        float bv = ldw(bias, gn, wfl);
        float dl = v + bv + bv;              // dt + 2*dt_bias (ref's double add)
        float delta = (dl > 20.f) ? dl : __logf(1.f + __expf(dl));
        Cf[(long)gm * ldc + gn] = delta;
        C2[(long)gm * ldc2 + gn] = delta * ldw(resid, (long)gm * ldr + gn, rfl);
      } else {
        if (bias) v += ldw(bias, gn, wfl);
        v *= oscale;
        if (resid) v += ldw(resid, (long)gm * ldr + gn, rfl);
        long off = (long)gm * ldc + gn;
        if (outmode == 2){
          if (fl) Cb[off] = f2bf(v); else Cf[off] = v;
        } else if (outmode == 3){
          Cb[off] = f2bf(v);
        } else {
          Cf[off] = v;
        }
        if (cdst) cdst[(long)gm * ldc + gn] = ldw(csrc, (long)gm * 256 + gn, cfl);
      }
    }
  }
}

// ---------------- z-batched MFMA GEMM (up to 4 independent problems) ----------------
// ldwq = weight row stride (elements); wkoff = per-z weight k-offset (split-K).
// A-direct (fp32 A), Bs staged in LDS.
struct GB4 {
  const float* A[4]; const void* W[4]; const void* bias[4];
  float* Cf[4]; u16* Cb[4]; const float* resid[4];
  const void* csrc[4]; float* cdst[4]; float osc[4]; int cfl[4]; int wkoff[4];
};

__global__ __launch_bounds__(256) void k_gemmb(
  GB4 gb, int lda, int K, int N, int ldc, int ldr, int ldwq,
  int act_gelu, int outmode, const int* __restrict__ flagp)
{
  const int fl = flagp[0];
  const int z = blockIdx.z;
  const float* A = gb.A[z]; const void* W = gb.W[z]; const void* bias = gb.bias[z];
  float* Cf = gb.Cf[z]; u16* Cb = gb.Cb[z]; const float* resid = gb.resid[z];
  const void* csrc = gb.csrc[z]; float* cdst = gb.cdst[z];
  const float osc = gb.osc[z];
  const int cfl = flagp[gb.cfl[z]];
  const int wkoff = gb.wkoff[z];

  __shared__ u16 Bs[64*72];
  const int tid = threadIdx.x;
  const int w = tid >> 6, lane = tid & 63, quad = lane >> 4, m = lane & 15;
  const int m0 = blockIdx.y << 6, n0 = blockIdx.x << 6;
  const int srow = tid >> 2, sc0 = (tid & 3) << 4;
  const float* arow = A + (long)(m0 + w*16 + m) * lda;

  f32x4 acc[4];
  #pragma unroll
  for (int ct = 0; ct < 4; ++ct) acc[ct] = (f32x4){0.f,0.f,0.f,0.f};

  for (int k0 = 0; k0 < K; k0 += 64){
    {
      long wb = (long)(n0 + srow) * ldwq + wkoff + k0 + sc0;
      if (fl){
        #pragma unroll
        for (int g = 0; g < 2; ++g)
          *(uint4*)&Bs[srow*72 + sc0 + g*8] = *(const uint4*)((const u16*)W + wb + g*8);
      } else {
        #pragma unroll
        for (int g = 0; g < 2; ++g){
          float4 b0 = *(const float4*)((const float*)W + wb + g*8);
          float4 b1 = *(const float4*)((const float*)W + wb + g*8 + 4);
          *(uint4*)&Bs[srow*72 + sc0 + g*8] = pack8(b0, b1);
        }
      }
    }
    s16x8 av[2];
    #pragma unroll
    for (int s = 0; s < 2; ++s){
      float4 a0 = *(const float4*)(arow + k0 + s*32 + quad*8);
      float4 a1 = *(const float4*)(arow + k0 + s*32 + quad*8 + 4);
      if (act_gelu){ a0 = gelu4(a0); a1 = gelu4(a1); }
      av[s] = pack8v(a0, a1);
    }
    __syncthreads();

    #pragma unroll
    for (int ct = 0; ct < 4; ++ct)
      #pragma unroll
      for (int s = 0; s < 2; ++s){
        s16x8 bv = *(const s16x8*)&Bs[(ct*16 + m)*72 + s*32 + quad*8];
        acc[ct] = __builtin_amdgcn_mfma_f32_16x16x32_bf16(av[s], bv, acc[ct], 0, 0, 0);
      }
    __syncthreads();
  }

  #pragma unroll
  for (int r = 0; r < 4; ++r){
    int gm = m0 + w*16 + quad*4 + r;
    #pragma unroll
    for (int ct = 0; ct < 4; ++ct){
      int gn = n0 + ct*16 + m;
      float v = acc[ct][r];
      if (bias) v += ldw(bias, gn, fl);
      v *= osc;
      if (resid) v += resid[(long)gm * ldr + gn];
      long off = (long)gm * ldc + gn;
      if (outmode == 2){
        if (fl) Cb[off] = f2bf(v); else Cf[off] = v;
      } else if (outmode == 3){
        Cb[off] = f2bf(v);
      } else {
        Cf[off] = v;
      }
      if (cdst) cdst[(long)gm * ldc + gn] = ldw(csrc, (long)gm * 256 + gn, cfl);
    }
  }
}

// ---------------- QKV extract + rotary (bf16 out; q pre-scaled by 1/8) ----
__global__ __launch_bounds__(256) void k_rope(
  const float* __restrict__ qkv, const void* __restrict__ pe,
  u16* __restrict__ q, u16* __restrict__ k, u16* __restrict__ v,
  int L, int B, int H, const int* __restrict__ flagp)
{
  int fl = *flagp;
  int tid = threadIdx.x;
  int lq = tid >> 6, d = tid & 63;
  int l = blockIdx.x * 4 + lq;
  int bh = blockIdx.y; int b = bh / H; int h = bh % H;
  const float* row = qkv + ((long)b * L + l) * 768 + h * 192;
  float qv = row[d*3+0], kv = row[d*3+1], vv = row[d*3+2];
  int dn = (d & 1) ? (d - 1) : (d + 1);
  float qn = row[dn*3+0], kn = row[dn*3+1];
  float rq = (d & 1) ? qn : -qn;
  float rk = (d & 1) ? kn : -kn;
  long peo = ((long)b * L + l) * 64 + d;
  float p0 = ldw(pe, peo, fl);
  float p1 = ldw(pe, (long)B * L * 64 + peo, fl);
  long o = ((long)bh * L + l) * 64 + d;
  q[o] = f2bf((qv * p0 + rq * p1) * 0.125f);   // exact pow2 pre-scale
  k[o] = f2bf(kv * p0 + rk * p1);
  v[o] = f2bf(vv);
}

// ---------------- MFMA flash attention, bf16 in / fp32 partials out ------
// K-split via blockIdx.z (NZ=4). Vt/Ps key-block swizzle (bank-conflict-free).
// LDS-pipe-lean: DPP softmax reductions, b64 Vt scatter, b32 packed Ps writes
// (DPP xor1 pair exchange + v_cvt_pk_bf16_f32), defer-max (THR=8),
// separate Ps buffer (wave-private rows) -> 2 barriers per j-iter.
__global__ __launch_bounds__(256, 8) void k_attn_mfma(
  const u16* __restrict__ Q, long qsb, long qsh, long qsl,
  const u16* __restrict__ Kp, long ksb, long ksh, long ksl,
  const u16* __restrict__ Vp, long vsb, long vsh, long vsl,
  float* __restrict__ Opart, float* __restrict__ mpart, float* __restrict__ lpart,
  int L, int H, int kchunk)
{
  __shared__ u16 Kt[64*72];
  __shared__ u16 Vt[64*72];
  __shared__ u16 Ps[64*72];     // wave-private rows: no barrier needed around it
  const int tid  = threadIdx.x;
  const int w    = tid >> 6;
  const int lane = tid & 63;
  const int quad = lane >> 4;
  const int m    = lane & 15;
  const int bh = blockIdx.y, b = bh / H, h = bh % H;
  const int iq0 = blockIdx.x * 64;
  const int z = blockIdx.z;
  const long BHL = (long)gridDim.y * L;

  const u16* Qb = Q  + b*qsb + h*qsh;
  const u16* Kb = Kp + b*ksb + h*ksh;
  const u16* Vb = Vp + b*vsb + h*vsh;

  s16x8 aq[2];
  {
    const u16* qr = Qb + (long)(iq0 + w*16 + m) * qsl + quad*8;
    aq[0] = *(const s16x8*)(qr);
    aq[1] = *(const s16x8*)(qr + 32);
  }

  f32x4 o_acc[4];
  #pragma unroll
  for (int nt = 0; nt < 4; ++nt) o_acc[nt] = (f32x4){0.f,0.f,0.f,0.f};
  float mrow[4] = {-1e30f,-1e30f,-1e30f,-1e30f};
  float lrow[4] = {0.f,0.f,0.f,0.f};

  const int srow = tid >> 2, sc0 = (tid & 3) << 4;
  // Vt b64-packed scatter: thread = (4-key group kg, 4-dim group dg).
  // Invariant layout: Vt[dim*72 + ((2*(dim>>4)+(key>>3))&7)*8 + (key&7)] = V[key][dim]
  const int kg = tid & 15;
  const int dg = tid >> 4;
  const int vcb = ((((dg >> 2) * 2) + (kg >> 1)) & 7) * 8 + (kg & 1) * 4;
  const int modd = m & 1;
  const int pcolb = m & 6;
  const int jend = z * kchunk + kchunk;

  for (int j0 = z * kchunk; j0 < jend; j0 += 64){
    {
      const u16* kr = Kb + (long)(j0 + srow) * ksl + sc0;
      *(uint4*)&Kt[srow*72 + sc0]     = *(const uint4*)kr;
      *(uint4*)&Kt[srow*72 + sc0 + 8] = *(const uint4*)(kr + 8);
      const u16* vr = Vb + (long)(j0 + 4*kg) * vsl + 4*dg;
      ushort4 r0 = *(const ushort4*)(vr);
      ushort4 r1 = *(const ushort4*)(vr + vsl);
      ushort4 r2 = *(const ushort4*)(vr + 2*vsl);
      ushort4 r3 = *(const ushort4*)(vr + 3*vsl);
      u16* vt = &Vt[(4*dg)*72 + vcb];
      *(ushort4*)(vt)       = make_ushort4(r0.x, r1.x, r2.x, r3.x);
      *(ushort4*)(vt + 72)  = make_ushort4(r0.y, r1.y, r2.y, r3.y);
      *(ushort4*)(vt + 144) = make_ushort4(r0.z, r1.z, r2.z, r3.z);
      *(ushort4*)(vt + 216) = make_ushort4(r0.w, r1.w, r2.w, r3.w);
    }
    __syncthreads();

    float sv[4][4];
    #pragma unroll
    for (int ct = 0; ct < 4; ++ct){
      f32x4 acc = (f32x4){0.f,0.f,0.f,0.f};
      #pragma unroll
      for (int s = 0; s < 2; ++s){
        s16x8 bk = *(const s16x8*)&Kt[(ct*16 + m)*72 + s*32 + quad*8];
        acc = __builtin_amdgcn_mfma_f32_16x16x32_bf16(aq[s], bk, acc, 0, 0, 0);
      }
      #pragma unroll
      for (int r = 0; r < 4; ++r) sv[ct][r] = acc[r];
    }

    // tile max per row; defer-max: only rescale when growth > THR=8
    float v0s[4];
    int need = 0;
    #pragma unroll
    for (int r = 0; r < 4; ++r){
      float v0 = fmaxf(fmaxf(sv[0][r], sv[1][r]), fmaxf(sv[2][r], sv[3][r]));
      v0 = dppmax16(v0);
      v0s[r] = v0;
      need |= (v0 > mrow[r] + 8.f) ? 1 : 0;
    }
    if (__any(need)){
      float alpha[4];
      #pragma unroll
      for (int r = 0; r < 4; ++r){
        float mn = fmaxf(mrow[r], v0s[r]);
        alpha[r] = __expf(mrow[r] - mn);
        mrow[r] = mn;
        lrow[r] *= alpha[r];
      }
      #pragma unroll
      for (int nt = 0; nt < 4; ++nt)
        #pragma unroll
        for (int r = 0; r < 4; ++r) o_acc[nt][r] *= alpha[r];
    }
    float rsum[4] = {0.f,0.f,0.f,0.f};
    #pragma unroll
    for (int ct = 0; ct < 4; ++ct)
      #pragma unroll
      for (int r = 0; r < 4; ++r){
        float p = __expf(sv[ct][r] - mrow[r]);
        sv[ct][r] = p;
        rsum[r] += p;
      }
    #pragma unroll
    for (int r = 0; r < 4; ++r)
      lrow[r] += dppsum16(rsum[r]);

    // Ps packed b32 writes: even-m lanes write rows rr/{0,1}, odd-m rows {2,3}.
    // pair = keys (ct*16 + (m&~1), +1); layout identical to scalar version.
    #pragma unroll
    for (int ct = 0; ct < 4; ++ct){
      const int kb = (2*w + 2*ct + (m >> 3)) & 7;
      const int col = (kb << 3) | pcolb;
      #pragma unroll
      for (int rr = 0; rr < 2; ++rr){
        float nb_lo = dppf<0xB1>(sv[ct][rr]);       // neighbor's r=rr
        float nb_hi = dppf<0xB1>(sv[ct][2+rr]);     // neighbor's r=2+rr
        float lo = modd ? nb_hi       : sv[ct][rr];
        float hi = modd ? sv[ct][2+rr] : nb_lo;
        unsigned int pk = cvtpk(lo, hi);
        int row = w*16 + quad*4 + rr + 2*modd;
        *(unsigned int*)&Ps[row*72 + col] = pk;
      }
    }
    asm volatile("s_waitcnt lgkmcnt(0)" ::: "memory");  // own-wave rows RAW

    s16x8 ap[2];
    #pragma unroll
    for (int s = 0; s < 2; ++s)
      ap[s] = *(const s16x8*)&Ps[(w*16 + m)*72 + (((2*w + 4*s + quad) & 7) << 3)];
    #pragma unroll
    for (int nt = 0; nt < 4; ++nt)
      #pragma unroll
      for (int s = 0; s < 2; ++s){
        s16x8 bv = *(const s16x8*)&Vt[(nt*16 + m)*72 + (((2*nt + 4*s + quad) & 7) << 3)];
        o_acc[nt] = __builtin_amdgcn_mfma_f32_16x16x32_bf16(ap[s], bv, o_acc[nt], 0, 0, 0);
      }
    __syncthreads();
  }

  const long zOoff = (long)z * BHL * 64;
  #pragma unroll
  for (int r = 0; r < 4; ++r){
    int iq = iq0 + w*16 + quad*4 + r;
    long rowid = ((long)b*L + iq) * H + h;
    #pragma unroll
    for (int nt = 0; nt < 4; ++nt)
      Opart[zOoff + rowid*64 + nt*16 + m] = o_acc[nt][r];
    if (m == 0){
      mpart[(long)z*BHL + rowid] = mrow[r];
      lpart[(long)z*BHL + rowid] = lrow[r];
    }
  }
}

// ---------------- attention split combine (4-way, fp32 partials) --------
__global__ __launch_bounds__(256) void k_attn_comb(
  const float* Opart, const float* mpart, const float* lpart,
  float* O, long BHL)
{
  long i = (long)blockIdx.x * 256 + threadIdx.x;
  long row = i >> 6;
  float mv[4];
  float M = -1e30f;
  #pragma unroll
  for (int z = 0; z < 4; ++z){
    mv[z] = mpart[(long)z*BHL + row];
    M = fmaxf(M, mv[z]);
  }
  long N64 = BHL * 64;
  float T = 0.f, acc = 0.f;
  #pragma unroll
  for (int z = 0; z < 4; ++z){
    float wz = __expf(mv[z] - M);
    T   += lpart[(long)z*BHL + row] * wz;
    acc += Opart[(long)z*N64 + i] * wz;
  }
  O[i] = acc / T;
}

// ---------------- depthwise conv K=5 SAME + silu (x and z paths batched) --
__global__ __launch_bounds__(256) void k_conv2(
  const float* __restrict__ xz,
  const void* __restrict__ wx, const void* __restrict__ wz,
  float* __restrict__ outx, float* __restrict__ outz,
  int L, const int* __restrict__ flagp)
{
  int fl = *flagp;
  int c = threadIdx.x;
  int bl = blockIdx.x; int b = bl / L, l = bl % L;
  int choff = blockIdx.y ? 256 : 0;
  const void* w = blockIdx.y ? wz : wx;
  float* out = blockIdx.y ? outz : outx;
  const float* base = xz + ((long)b * L) * 512 + choff + c;
  float s = 0.f;
  #pragma unroll
  for (int kk = 0; kk < 5; ++kk){
    int ll = l + kk - 2;
    if (ll >= 0 && ll < L) s += base[(long)ll * 512] * ldw(w, c*5 + kk, fl);
  }
  out[((long)b * L + l) * 256 + c] = s / (1.f + __expf(-s));   // silu
}

// ---------------- chunk-parallel selective scan (xdbl ld 64) ----------------
#define SC_CS 64
#define SC_NC 32

__global__ __launch_bounds__(256) void k_scan1(
  const float* __restrict__ delta, const float* __restrict__ dxc,
  const float* __restrict__ xdbl, const void* __restrict__ Alog,
  float* __restrict__ E_out, float* __restrict__ F_out,
  int L, const int* __restrict__ flagp)
{
  int fl = *flagp;
  int tid = threadIdx.x;
  int g = tid >> 4, n = tid & 15;
  int gid = blockIdx.x * 16 + g;
  int chunk = gid & (SC_NC - 1);
  int p = gid >> 5;
  int b = p >> 8, d = p & 255;
  float A = -__expf(ldw(Alog, d*16 + n, fl));
  const float* dtp = delta + (long)b*L*256 + d;
  const float* dxp = dxc   + (long)b*L*256 + d;
  const float* xdb = xdbl + (long)b*L*64;
  int l0 = chunk * SC_CS;
  float E = 1.f, F = 0.f;
  for (int i = 0; i < SC_CS; i += 4){
    float e[4], u[4];
    #pragma unroll
    for (int j = 0; j < 4; ++j){
      int l = l0 + i + j;
      e[j] = __expf(dtp[(long)l*256] * A);
      u[j] = dxp[(long)l*256] * xdb[l*64 + 16 + n];
    }
    F = e[0]*F + u[0]; F = e[1]*F + u[1];
    F = e[2]*F + u[2]; F = e[3]*F + u[3];
    E *= (e[0]*e[1]) * (e[2]*e[3]);
  }
  long idx = (long)(p*16 + n) * SC_NC + chunk;
  E_out[idx] = E; F_out[idx] = F;
}

__global__ __launch_bounds__(256) void k_scan2(
  const float* __restrict__ E, const float* __restrict__ F,
  float* __restrict__ Hin)
{
  int pn = blockIdx.x * 256 + threadIdx.x;
  const float* Ep = E + (long)pn * SC_NC;
  const float* Fp = F + (long)pn * SC_NC;
  float* Hp = Hin + (long)pn * SC_NC;
  float h = 0.f;
  #pragma unroll
  for (int c = 0; c < SC_NC; ++c){
    Hp[c] = h;
    h = Ep[c] * h + Fp[c];
  }
}

__global__ __launch_bounds__(256) void k_scan3(
  const float* __restrict__ delta, const float* __restrict__ dxc,
  const float* __restrict__ xc, const float* __restrict__ xdbl,
  const void* __restrict__ Alog, const void* __restrict__ Dp,
  const float* __restrict__ Hin, float* __restrict__ y,
  int L, const int* __restrict__ flagp)
{
  int fl = *flagp;
  int tid = threadIdx.x;
  int g = tid >> 4, n = tid & 15;
  int gid = blockIdx.x * 16 + g;
  int chunk = gid & (SC_NC - 1);
  int p = gid >> 5;
  int b = p >> 8, d = p & 255;
  float A = -__expf(ldw(Alog, d*16 + n, fl));
  float Dv = ldw(Dp, d, fl);
  const float* dtp = delta + (long)b*L*256 + d;
  const float* dxp = dxc   + (long)b*L*256 + d;
  const float* xcb = xc    + (long)b*L*256 + d;
  const float* xdb = xdbl + (long)b*L*64;
  float* yb = y + (long)b*L*256 + d;
  long idx = (long)(p*16 + n) * SC_NC + chunk;
  float h = Hin[idx];
  int l0 = chunk * SC_CS;
  for (int i = 0; i < SC_CS; i += 4){
    float e[4], u[4], cm[4], xv[4];
    #pragma unroll
    for (int j = 0; j < 4; ++j){
      int l = l0 + i + j;
      e[j]  = __expf(dtp[(long)l*256] * A);
      u[j]  = dxp[(long)l*256] * xdb[l*64 + 16 + n];
      cm[j] = xdb[l*64 + 32 + n];
      xv[j] = xcb[(long)l*256];
    }
    float s0, s1, s2, s3;
    h = e[0]*h + u[0]; s0 = h * cm[0];
    h = e[1]*h + u[1]; s1 = h * cm[1];
    h = e[2]*h + u[2]; s2 = h * cm[2];
    h = e[3]*h + u[3]; s3 = h * cm[3];
    s0 += __shfl_xor(s0, 1, 16); s1 += __shfl_xor(s1, 1, 16);
    s2 += __shfl_xor(s2, 1, 16); s3 += __shfl_xor(s3, 1, 16);
    s0 += __shfl_xor(s0, 2, 16); s1 += __shfl_xor(s1, 2, 16);
    s2 += __shfl_xor(s2, 2, 16); s3 += __shfl_xor(s3, 2, 16);
    s0 += __shfl_xor(s0, 4, 16); s1 += __shfl_xor(s1, 4, 16);
    s2 += __shfl_xor(s2, 4, 16); s3 += __shfl_xor(s3, 4, 16);
    s0 += __shfl_xor(s0, 8, 16); s1 += __shfl_xor(s1, 8, 16);
    s2 += __shfl_xor(s2, 8, 16); s3 += __shfl_xor(s3, 8, 16);
    if (n < 4){
      float out = (n == 0) ? s0 + Dv*xv[0] : (n == 1) ? s1 + Dv*xv[1]
                : (n == 2) ? s2 + Dv*xv[2] : s3 + Dv*xv[3];
      yb[(long)(l0 + i + n)*256] = out;
    }
  }
}

// ---------------- LayerNorm over rows of 512 (h += h2 partial, in place) --
__global__ __launch_bounds__(256) void k_ln(float* __restrict__ h,
                                            const float* __restrict__ h2,
                                            const void* __restrict__ g,
                                            const void* __restrict__ beta,
                                            const int* __restrict__ flagp)
{
  int fl = *flagp;
  int row = blockIdx.x * 4 + (threadIdx.x >> 6);
  int lane = threadIdx.x & 63;
  float* hr = h + (long)row * 512;
  const float* h2r = h2 + (long)row * 512;
  float v[8]; float s = 0.f, ss = 0.f;
  #pragma unroll
  for (int i = 0; i < 8; ++i){
    v[i] = hr[lane + 64*i] + h2r[lane + 64*i];
    s += v[i]; ss += v[i]*v[i];
  }
  #pragma unroll
  for (int off = 1; off < 64; off <<= 1){ s += __shfl_xor(s, off); ss += __shfl_xor(ss, off); }
  float mean = s * (1.f/512.f);
  float var  = ss * (1.f/512.f) - mean * mean;
  float rs = rsqrtf(var + 1e-5f);
  #pragma unroll
  for (int i = 0; i < 8; ++i){
    int c = lane + 64*i;
    hr[c] = (v[i] - mean) * rs * ldw(g, c, fl) + ldw(beta, c, fl);
  }
}

// two-buffer LN with split-K partial sum (cross-attn i=0/1 batched)
__global__ __launch_bounds__(256) void k_ln2(
  float* __restrict__ hA, const float* __restrict__ hA2,
  float* __restrict__ hB, const float* __restrict__ hB2,
  const void* __restrict__ g, const void* __restrict__ beta,
  const int* __restrict__ flagp)
{
  int fl = *flagp;
  int r = blockIdx.x * 4 + (threadIdx.x >> 6);
  float* hbase = (r < 4096) ? hA : hB;
  const float* h2base = (r < 4096) ? hA2 : hB2;
  int row = r & 4095;
  int lane = threadIdx.x & 63;
  float* hr = hbase + (long)row * 512;
  const float* h2r = h2base + (long)row * 512;
  float v[8]; float s = 0.f, ss = 0.f;
  #pragma unroll
  for (int i = 0; i < 8; ++i){
    v[i] = hr[lane + 64*i] + h2r[lane + 64*i];
    s += v[i]; ss += v[i]*v[i];
  }
  #pragma unroll
  for (int off = 1; off < 64; off <<= 1){ s += __shfl_xor(s, off); ss += __shfl_xor(ss, off); }
  float mean = s * (1.f/512.f);
  float var  = ss * (1.f/512.f) - mean * mean;
  float rs = rsqrtf(var + 1e-5f);
  #pragma unroll
  for (int i = 0; i < 8; ++i){
    int c = lane + 64*i;
    hr[c] = (v[i] - mean) * rs * ldw(g, c, fl) + ldw(beta, c, fl);
  }
}

extern "C" void kernel_launch(void* const* d_in, const int* in_sizes, int n_in,
                              void* d_out, int out_size, void* d_ws, size_t ws_size,
                              hipStream_t stream)
{
  const int B_ = 2, L_ = 2048, H_ = 4;
  const long BLE = (long)B_ * L_ * 256;       // 1,048,576
  const long BHL = (long)B_ * H_ * L_;        // 16,384
  const long SCN = (long)2 * 256 * 16 * SC_NC;

  int* flagp = (int*)d_ws;
  float* base = (float*)d_ws + 64;

  // ---- workspace map (units of BLE fp32 unless noted) ----
  float* P8    = base;
  float* cat   = P8;                      // ld 768 / 1024 (4 BLE max)
  float* xdbl  = P8 + 4*BLE;              // B*L*64
  float* delta = P8 + 5*BLE;              // 1 BLE
  float* scE   = P8 + 6*BLE;
  float* scF   = scE + SCN;
  float* scH   = scE + 2*SCN;             // 3*SCN = 786,432 < 1 BLE
  float* ob    = P8 + 7*BLE;              // attn out
  float* dbuf[2] = { base + 8*BLE, base + 9*BLE };
  float* hbuf  = base + 10*BLE;           // 2 BLE
  float* xcb   = base + 12*BLE;
  float* zcb   = base + 13*BLE;
  float* mml   = base + 14*BLE;           // 8*BHL (z=4 uses 4)
  float* mll   = mml + 8*BHL;             // 8*BHL
  float* px    = mll + 8*BHL;             // 16,384 (xproj padded 64x256)
  float* pd    = px + 16384;              // 16,384 (dt_w padded 256x64)
  float* pb    = pd + 16384;              // 256    (dt_b fp32)

  const void* in[35];
  for (int i = 0; i < 35 && i < n_in; ++i) in[i] = d_in[i];

  k_sniff<<<1, 256, 0, stream>>>((const unsigned int*)in[0], 2048, flagp);
  k_pad<<<130, 256, 0, stream>>>(in[17], in[18], in[19], px, pd, pb, flagp);

  const int BIG = 1 << 30;
  const long sbP = (long)H_ * L_ * 64, shP = (long)L_ * 64, slP = 64;   // (B,H,L,64)
  const long sbF = (long)L_ * 256,     shF = 64,            slF = 256;  // (B,L,256)
  const dim3 gAttn(L_/64, B_*H_, 4);      // z-split 4 (8 was occupancy-neutral, 2x HBM)
  const int kchunk = L_ / 4;

  // ---------------- per-descriptor: mamba_attention ----------------
  for (int i = 0; i < 2; ++i){
    float* d = dbuf[i];
    u16* qm = (u16*)xcb;                  // bf16 q (0.5 BLE)
    u16* km = qm + 1048576;               // bf16 k
    u16* vm = (u16*)zcb;                  // bf16 v
    float* y  = hbuf + BLE;               // scan3 output (1 BLE)
    // merged qkv (N 0..767 -> cat ld 768) + xz (768..1279 -> hbuf ld 512)
    k_gemm_mfma<<<dim3(20, 64), 256, 0, stream>>>(
        in[i], 0, 256, 256, 1280, in[4], in[14], 768, 0, in[5],
        cat, nullptr, 768, hbuf, 512,
        nullptr, 1, 0, nullptr, 1, nullptr,
        1.f, 0, 0, flagp);
    k_rope<<<dim3(L_/4, B_*H_), 256, 0, stream>>>(cat, in[2+i],
        qm, km, vm, L_, B_, H_, flagp);
    k_attn_mfma<<<gAttn, 256, 0, stream>>>(qm, sbP, shP, slP,
                                           km, sbP, shP, slP,
                                           vm, sbP, shP, slP,
                                           P8, mml, mll, L_, H_, kchunk);
    k_attn_comb<<<(int)(BLE/256), 256, 0, stream>>>(P8, mml, mll, ob, BHL);
    k_conv2<<<dim3(B_*L_, 2), 256, 0, stream>>>(hbuf, in[15], in[16], xcb, zcb, L_, flagp);
    // xproj (padded N=64, fp32 weights) into xdbl ld 64
    k_gemm_mfma<<<dim3(1, 64), 256, 0, stream>>>(
        xcb, 1, 256, 256, 64, px, nullptr, BIG, 1, nullptr,
        xdbl, nullptr, 64, nullptr, 0,
        nullptr, 1, 0, nullptr, 1, nullptr,
        1.f, 0, 0, flagp);
    // dt (padded K=64, fp32 weights+bias) + fused softplus -> delta, dxc
    k_gemm_mfma<<<dim3(4, 64), 256, 0, stream>>>(
        xdbl, 1, 64, 64, 256, pd, nullptr, BIG, 1, pb,
        delta, nullptr, 256, hbuf, 256,
        xcb, 1, 256, nullptr, 1, nullptr,
        1.f, 0, 4, flagp);
    k_scan1<<<1024, 256, 0, stream>>>(delta, hbuf, xdbl, in[20], scE, scF, L_, flagp);
    k_scan2<<<32, 256, 0, stream>>>(scE, scF, scH);
    k_scan3<<<1024, 256, 0, stream>>>(delta, hbuf, xcb, xdbl, in[20], in[21], scH, y, L_, flagp);
    // batched s_x / c_x / o-proj (+fused raw-input->cat copy) into cat (ld 1024)
    {
      GB4 gb = {};
      gb.cfl[0] = gb.cfl[1] = gb.cfl[3] = 1;
      gb.A[0] = y;   gb.W[0] = in[22]; gb.Cf[0] = cat + 512; gb.osc[0] = 1.f;
      gb.A[1] = zcb; gb.W[1] = in[22]; gb.Cf[1] = cat + 768; gb.osc[1] = 1.f;
      gb.A[2] = ob;  gb.W[2] = in[6];  gb.bias[2] = in[7];   gb.Cf[2] = cat + 256;
      gb.csrc[2] = in[i]; gb.cdst[2] = cat; gb.osc[2] = 1.f; gb.cfl[2] = 0;
      k_gemmb<<<dim3(4, 64, 3), 256, 0, stream>>>(gb, 256, 256, 256, 1024, 0, 256, 0, 0, flagp);
    }
    // ffn1 split-K=2: z0 = cat[:,0:512] @ W[:,0:512]^T (+bias), z1 = rest
    {
      GB4 gb = {};
      gb.cfl[0] = gb.cfl[1] = 1;
      gb.A[0] = cat;       gb.W[0] = in[8]; gb.bias[0] = in[9]; gb.Cf[0] = hbuf; gb.osc[0] = 1.f;
      gb.A[1] = cat + 512; gb.W[1] = in[8]; gb.wkoff[1] = 512;  gb.Cf[1] = xcb;  gb.osc[1] = 1.f;
      k_gemmb<<<dim3(8, 64, 2), 256, 0, stream>>>(gb, 1024, 512, 512, 512, 0, 1024, 0, 0, flagp);
    }
    k_ln<<<1024, 256, 0, stream>>>(hbuf, xcb, in[10], in[11], flagp);
    // ffn2: gelu(A) @ W^T + bias + raw-input residual (dtype-flag-aware)
    k_gemm_mfma<<<dim3(4, 64), 256, 0, stream>>>(
        hbuf, 1, 512, 512, 256, in[12], nullptr, BIG, 0, in[13],
        d, nullptr, 256, nullptr, 0,
        in[i], 0, 256, nullptr, 1, nullptr,
        1.f, 1, 0, flagp);
  }

  // ---------------- cross attention ----------------
  const float s4 = 0.35355339059327373f;  // 64^-0.25
  u16* qc = (u16*)hbuf;                   // cross q/k/v/o bf16 pack into hbuf
  u16* kc = qc + 1048576;
  u16* vc = kc + 1048576;
  u16* oc = vc + 1048576;
  float* catA  = P8;                      // ld 512 (2 BLE)
  float* catB  = P8 + 2*BLE;              // ld 512 (2 BLE)
  float* hbufB = P8 + 4*BLE;              // 2 BLE
  float* partB = P8 + 6*BLE;              // 2 BLE
  {
    GB4 gb = {};
    gb.cfl[0] = gb.cfl[1] = gb.cfl[2] = gb.cfl[3] = 1;
    gb.A[0] = dbuf[0]; gb.W[0] = in[23]; gb.bias[0] = in[24]; gb.Cb[0] = qc; gb.osc[0] = s4;
    gb.A[1] = dbuf[1]; gb.W[1] = in[23]; gb.bias[1] = in[24]; gb.Cb[1] = kc; gb.osc[1] = s4;
    gb.A[2] = dbuf[0]; gb.W[2] = in[25]; gb.bias[2] = in[26]; gb.Cb[2] = vc; gb.osc[2] = 1.f;
    gb.A[3] = dbuf[1]; gb.W[3] = in[25]; gb.bias[3] = in[26]; gb.Cb[3] = oc; gb.osc[3] = 1.f;
    k_gemmb<<<dim3(4, 64, 4), 256, 0, stream>>>(gb, 256, 256, 256, 256, 0, 256, 0, 3, flagp);
  }
  k_attn_mfma<<<gAttn, 256, 0, stream>>>(qc, sbF, shF, slF, kc, sbF, shF, slF,
                                         oc, sbF, shF, slF,
                                         P8, mml, mll, L_, H_, kchunk);
  k_attn_comb<<<(int)(BLE/256), 256, 0, stream>>>(P8, mml, mll, xcb, BHL);
  k_attn_mfma<<<gAttn, 256, 0, stream>>>(kc, sbF, shF, slF, qc, sbF, shF, slF,
                                         vc, sbF, shF, slF,
                                         P8, mml, mll, L_, H_, kchunk);
  k_attn_comb<<<(int)(BLE/256), 256, 0, stream>>>(P8, mml, mll, zcb, BHL);
  {
    GB4 gb = {};
    gb.cfl[0] = gb.cfl[1] = 1;
    gb.A[0] = xcb; gb.W[0] = in[27]; gb.bias[0] = in[28]; gb.Cf[0] = catA + 256;
    gb.csrc[0] = dbuf[0]; gb.cdst[0] = catA; gb.osc[0] = 1.f;
    gb.A[1] = zcb; gb.W[1] = in[27]; gb.bias[1] = in[28]; gb.Cf[1] = catB + 256;
    gb.csrc[1] = dbuf[1]; gb.cdst[1] = catB; gb.osc[1] = 1.f;
    k_gemmb<<<dim3(4, 64, 2), 256, 0, stream>>>(gb, 256, 256, 256, 512, 0, 256, 0, 0, flagp);
  }
  // ca-ffn1 split-K=2 per descriptor (z=4 total); bias on z0/z2 only
  {
    GB4 gb = {};
    gb.cfl[0] = gb.cfl[1] = gb.cfl[2] = gb.cfl[3] = 1;
    gb.A[0] = catA;       gb.W[0] = in[29]; gb.bias[0] = in[30]; gb.Cf[0] = hbuf;  gb.osc[0] = 1.f;
    gb.A[1] = catA + 256; gb.W[1] = in[29]; gb.wkoff[1] = 256;   gb.Cf[1] = xcb;   gb.osc[1] = 1.f;
    gb.A[2] = catB;       gb.W[2] = in[29]; gb.bias[2] = in[30]; gb.Cf[2] = hbufB; gb.osc[2] = 1.f;
    gb.A[3] = catB + 256; gb.W[3] = in[29]; gb.wkoff[3] = 256;   gb.Cf[3] = partB; gb.osc[3] = 1.f;
    k_gemmb<<<dim3(8, 64, 4), 256, 0, stream>>>(gb, 512, 256, 512, 512, 0, 512, 0, 0, flagp);
  }
  k_ln2<<<2048, 256, 0, stream>>>(hbuf, xcb, hbufB, partB, in[31], in[32], flagp);
  {
    GB4 gb = {};
    gb.cfl[0] = gb.cfl[1] = 1;
    gb.A[0] = hbuf;  gb.W[0] = in[33]; gb.bias[0] = in[34]; gb.resid[0] = dbuf[0];
    gb.Cf[0] = (float*)d_out; gb.Cb[0] = (u16*)d_out; gb.osc[0] = 1.f;
    gb.A[1] = hbufB; gb.W[1] = in[33]; gb.bias[1] = in[34]; gb.resid[1] = dbuf[1];
    gb.Cf[1] = (float*)d_out + BLE; gb.Cb[1] = (u16*)d_out + BLE; gb.osc[1] = 1.f;
    k_gemmb<<<dim3(4, 64, 2), 256, 0, stream>>>(gb, 512, 512, 256, 256, 256, 512, 1, 2, flagp);
  }
}

// Round 6
// 706.042 us; speedup vs baseline: 1.1616x; 1.1381x over previous
//
#include <hip/hip_runtime.h>

typedef unsigned short u16;
typedef short s16;
typedef s16 s16x8 __attribute__((ext_vector_type(8)));
typedef float f32x4 __attribute__((ext_vector_type(4)));

__device__ __forceinline__ float bf2f(u16 u){
  union { unsigned int i; float f; } v; v.i = ((unsigned int)u) << 16; return v.f;
}
__device__ __forceinline__ u16 f2bf(float f){
  union { float f; unsigned int u; } v; v.f = f;
  unsigned int r = (v.u + 0x7fffu + ((v.u >> 16) & 1u)) >> 16;
  return (u16)r;
}
// packed f32x2 -> bf16x2 (RNE, identical to f2bf) in ONE VALU op
__device__ __forceinline__ unsigned int cvtpk(float lo, float hi){
  unsigned int d;
  asm("v_cvt_pk_bf16_f32 %0, %1, %2" : "=v"(d) : "v"(lo), "v"(hi));
  return d;
}
__device__ __forceinline__ uint4 pack8(float4 a0, float4 a1){
  uint4 v;
  v.x = cvtpk(a0.x, a0.y); v.y = cvtpk(a0.z, a0.w);
  v.z = cvtpk(a1.x, a1.y); v.w = cvtpk(a1.z, a1.w);
  return v;
}
__device__ __forceinline__ float gelu_f(float x){
  return 0.5f * x * (1.f + erff(x * 0.70710678118654752440f));
}
__device__ __forceinline__ float ldw(const void* p, long i, int fl){
  return fl ? bf2f(((const u16*)p)[i]) : ((const float*)p)[i];
}
__device__ __forceinline__ float4 ldw4(const void* p, long i, int fl){
  if (fl){
    ushort4 w = *(const ushort4*)((const u16*)p + i);
    return make_float4(bf2f(w.x), bf2f(w.y), bf2f(w.z), bf2f(w.w));
  }
  return *(const float4*)((const float*)p + i);
}

// ---- DPP 16-lane butterfly reductions (VALU pipe, zero LDS traffic) ----
template<int C>
__device__ __forceinline__ float dppf(float x){
  return __int_as_float(__builtin_amdgcn_update_dpp(0, __float_as_int(x), C, 0xf, 0xf, true));
}
__device__ __forceinline__ float dppmax16(float v){
  v = fmaxf(v, dppf<0xB1>(v));
  v = fmaxf(v, dppf<0x4E>(v));
  v = fmaxf(v, dppf<0x141>(v));
  v = fmaxf(v, dppf<0x140>(v));
  return v;
}
__device__ __forceinline__ float dppsum16(float v){
  v += dppf<0xB1>(v);
  v += dppf<0x4E>(v);
  v += dppf<0x141>(v);
  v += dppf<0x140>(v);
  return v;
}

// ---------------- dtype sniffer (flag[0]=dtype, flag[1]=0 const) --------
__global__ __launch_bounds__(256) void k_sniff(const unsigned int* __restrict__ w,
                                               int n, int* __restrict__ flag){
  __shared__ int cnt[256];
  int c = 0;
  for (int i = threadIdx.x; i < n; i += 256){
    unsigned e = (w[i] >> 7) & 0xFFu;
    c += (e >= 120u && e <= 127u) ? 1 : 0;
  }
  cnt[threadIdx.x] = c; __syncthreads();
  for (int s = 128; s > 0; s >>= 1){
    if (threadIdx.x < s) cnt[threadIdx.x] += cnt[threadIdx.x + s];
    __syncthreads();
  }
  if (threadIdx.x == 0) flag[0] = (2 * cnt[0] > n) ? 1 : 0;
  if (threadIdx.x == 1) flag[1] = 0;
}

// ---- zero-pad xproj (48x256 -> 64x256) / dt_w (256x16 -> 256x64) / dt_b ----
__global__ __launch_bounds__(256) void k_pad(
  const void* __restrict__ wx, const void* __restrict__ wd,
  const void* __restrict__ bd,
  float* __restrict__ px, float* __restrict__ pd, float* __restrict__ pb,
  const int* __restrict__ flagp)
{
  int fl = *flagp;
  int i = blockIdx.x * 256 + threadIdx.x;
  if (i < 16384){
    int r = i >> 8, c = i & 255;
    px[i] = (r < 48) ? ldw(wx, r*256 + c, fl) : 0.f;
  } else if (i < 32768){
    int j = i - 16384;
    int n = j >> 6, k = j & 63;
    pd[j] = (k < 16) ? ldw(wd, n*16 + k, fl) : 0.f;
  } else if (i < 33024){
    pb[i - 32768] = ldw(bd, i - 32768, fl);
  }
}

// ---------------- MFMA GEMM (round-3 staged form; best measured) ----------------
// outmode: 0 fp32, 2 dynamic, 3 bf16, 4 softplus(dt+2*bias) -> Cf, *xc -> C2.
__global__ __launch_bounds__(256) void k_gemm_mfma(
  const void* __restrict__ A, int aflidx, int lda, int K, int N,
  const void* __restrict__ W, const void* __restrict__ W2, int nsplit, int wflidx,
  const void* __restrict__ bias,
  float* __restrict__ Cf, u16* __restrict__ Cb, int ldc,
  float* __restrict__ C2, int ldc2,
  const void* __restrict__ resid, int rflidx, int ldr,
  const void* __restrict__ csrc, int cflidx, float* __restrict__ cdst,
  float oscale, int act_gelu, int outmode, const int* __restrict__ flagp)
{
  const int fl  = flagp[0];
  const int afl = flagp[aflidx];
  const int wfl = flagp[wflidx];
  const int rfl = flagp[rflidx];
  const int cfl = flagp[cflidx];
  __shared__ u16 As[64*72];
  __shared__ u16 Bs[64*72];
  const int tid = threadIdx.x;
  const int w = tid >> 6, lane = tid & 63, quad = lane >> 4, m = lane & 15;
  const int m0 = blockIdx.y << 6, n0 = blockIdx.x << 6;
  const int srow = tid >> 2, sc0 = (tid & 3) << 4;
  const int reg2 = (n0 >= nsplit);
  const void* Wp = reg2 ? W2 : W;
  const int nbase = reg2 ? nsplit : 0;

  f32x4 acc[4];
  #pragma unroll
  for (int ct = 0; ct < 4; ++ct) acc[ct] = (f32x4){0.f,0.f,0.f,0.f};

  for (int k0 = 0; k0 < K; k0 += 64){
    {
      long ab = (long)(m0 + srow) * lda + k0 + sc0;
      if (afl && !act_gelu){
        #pragma unroll
        for (int g = 0; g < 2; ++g)
          *(uint4*)&As[srow*72 + sc0 + g*8] = *(const uint4*)((const u16*)A + ab + g*8);
      } else {
        #pragma unroll
        for (int g = 0; g < 2; ++g){
          float4 a0 = ldw4(A, ab + g*8, afl);
          float4 a1 = ldw4(A, ab + g*8 + 4, afl);
          if (act_gelu){
            a0.x=gelu_f(a0.x); a0.y=gelu_f(a0.y); a0.z=gelu_f(a0.z); a0.w=gelu_f(a0.w);
            a1.x=gelu_f(a1.x); a1.y=gelu_f(a1.y); a1.z=gelu_f(a1.z); a1.w=gelu_f(a1.w);
          }
          *(uint4*)&As[srow*72 + sc0 + g*8] = pack8(a0, a1);
        }
      }
    }
    {
      long wb = (long)(n0 + srow - nbase) * K + k0 + sc0;
      if (wfl){
        #pragma unroll
        for (int g = 0; g < 2; ++g)
          *(uint4*)&Bs[srow*72 + sc0 + g*8] = *(const uint4*)((const u16*)Wp + wb + g*8);
      } else {
        #pragma unroll
        for (int g = 0; g < 2; ++g){
          float4 b0 = *(const float4*)((const float*)Wp + wb + g*8);
          float4 b1 = *(const float4*)((const float*)Wp + wb + g*8 + 4);
          *(uint4*)&Bs[srow*72 + sc0 + g*8] = pack8(b0, b1);
        }
      }
    }
    __syncthreads();

    s16x8 av[2];
    #pragma unroll
    for (int s = 0; s < 2; ++s)
      av[s] = *(const s16x8*)&As[(w*16 + m)*72 + s*32 + quad*8];
    #pragma unroll
    for (int ct = 0; ct < 4; ++ct)
      #pragma unroll
      for (int s = 0; s < 2; ++s){
        s16x8 bv = *(const s16x8*)&Bs[(ct*16 + m)*72 + s*32 + quad*8];
        acc[ct] = __builtin_amdgcn_mfma_f32_16x16x32_bf16(av[s], bv, acc[ct], 0, 0, 0);
      }
    __syncthreads();
  }

  #pragma unroll
  for (int r = 0; r < 4; ++r){
    int gm = m0 + w*16 + quad*4 + r;
    #pragma unroll
    for (int ct = 0; ct < 4; ++ct){
      int gn = n0 + ct*16 + m;
      float v = acc[ct][r];
      if (reg2){
        C2[(long)gm * ldc2 + (gn - nsplit)] = v;
      } else if (outmode == 4){
        float bv = ldw(bias, gn, wfl);
        float dl = v + bv + bv;              // dt + 2*dt_bias (ref's double add)
        float delta = (dl > 20.f) ? dl : __logf(1.f + __expf(dl));
        Cf[(long)gm * ldc + gn] = delta;
        C2[(long)gm * ldc2 + gn] = delta * ldw(resid, (long)gm * ldr + gn, rfl);
      } else {
        if (bias) v += ldw(bias, gn, wfl);
        v *= oscale;
        if (resid) v += ldw(resid, (long)gm * ldr + gn, rfl);
        long off = (long)gm * ldc + gn;
        if (outmode == 2){
          if (fl) Cb[off] = f2bf(v); else Cf[off] = v;
        } else if (outmode == 3){
          Cb[off] = f2bf(v);
        } else {
          Cf[off] = v;
        }
        if (cdst) cdst[(long)gm * ldc + gn] = ldw(csrc, (long)gm * 256 + gn, cfl);
      }
    }
  }
}

// ---------------- z-batched MFMA GEMM (up to 8 independent problems) ----------------
// ldwq = weight row stride; wkoff = per-z weight k-offset (split-K).
// rfli[z] = flag index for resid dtype (0=input dtype, 1=fp32).
struct GB8 {
  const float* A[8]; const void* W[8]; const void* bias[8];
  float* Cf[8]; u16* Cb[8]; const void* resid[8];
  const void* csrc[8]; float* cdst[8]; float osc[8];
  int cfl[8]; int wkoff[8]; int rfli[8];
};

__global__ __launch_bounds__(256) void k_gemmb(
  GB8 gb, int lda, int K, int N, int ldc, int ldr, int ldwq,
  int act_gelu, int outmode, const int* __restrict__ flagp)
{
  const int fl = flagp[0];
  const int z = blockIdx.z;
  const float* A = gb.A[z]; const void* W = gb.W[z]; const void* bias = gb.bias[z];
  float* Cf = gb.Cf[z]; u16* Cb = gb.Cb[z]; const void* resid = gb.resid[z];
  const void* csrc = gb.csrc[z]; float* cdst = gb.cdst[z];
  const float osc = gb.osc[z];
  const int cfl = flagp[gb.cfl[z]];
  const int rfl = flagp[gb.rfli[z]];
  const int wkoff = gb.wkoff[z];

  __shared__ u16 As[64*72];
  __shared__ u16 Bs[64*72];
  const int tid = threadIdx.x;
  const int w = tid >> 6, lane = tid & 63, quad = lane >> 4, m = lane & 15;
  const int m0 = blockIdx.y << 6, n0 = blockIdx.x << 6;
  const int srow = tid >> 2, sc0 = (tid & 3) << 4;

  f32x4 acc[4];
  #pragma unroll
  for (int ct = 0; ct < 4; ++ct) acc[ct] = (f32x4){0.f,0.f,0.f,0.f};

  for (int k0 = 0; k0 < K; k0 += 64){
    {
      const float* ar = A + (long)(m0 + srow) * lda + k0 + sc0;
      #pragma unroll
      for (int g = 0; g < 2; ++g){
        float4 a0 = *(const float4*)(ar + g*8);
        float4 a1 = *(const float4*)(ar + g*8 + 4);
        if (act_gelu){
          a0.x=gelu_f(a0.x); a0.y=gelu_f(a0.y); a0.z=gelu_f(a0.z); a0.w=gelu_f(a0.w);
          a1.x=gelu_f(a1.x); a1.y=gelu_f(a1.y); a1.z=gelu_f(a1.z); a1.w=gelu_f(a1.w);
        }
        *(uint4*)&As[srow*72 + sc0 + g*8] = pack8(a0, a1);
      }
    }
    {
      long wb = (long)(n0 + srow) * ldwq + wkoff + k0 + sc0;
      if (fl){
        #pragma unroll
        for (int g = 0; g < 2; ++g)
          *(uint4*)&Bs[srow*72 + sc0 + g*8] = *(const uint4*)((const u16*)W + wb + g*8);
      } else {
        #pragma unroll
        for (int g = 0; g < 2; ++g){
          float4 b0 = *(const float4*)((const float*)W + wb + g*8);
          float4 b1 = *(const float4*)((const float*)W + wb + g*8 + 4);
          *(uint4*)&Bs[srow*72 + sc0 + g*8] = pack8(b0, b1);
        }
      }
    }
    __syncthreads();

    s16x8 av[2];
    #pragma unroll
    for (int s = 0; s < 2; ++s)
      av[s] = *(const s16x8*)&As[(w*16 + m)*72 + s*32 + quad*8];
    #pragma unroll
    for (int ct = 0; ct < 4; ++ct)
      #pragma unroll
      for (int s = 0; s < 2; ++s){
        s16x8 bv = *(const s16x8*)&Bs[(ct*16 + m)*72 + s*32 + quad*8];
        acc[ct] = __builtin_amdgcn_mfma_f32_16x16x32_bf16(av[s], bv, acc[ct], 0, 0, 0);
      }
    __syncthreads();
  }

  #pragma unroll
  for (int r = 0; r < 4; ++r){
    int gm = m0 + w*16 + quad*4 + r;
    #pragma unroll
    for (int ct = 0; ct < 4; ++ct){
      int gn = n0 + ct*16 + m;
      float v = acc[ct][r];
      if (bias) v += ldw(bias, gn, fl);
      v *= osc;
      if (resid) v += ldw(resid, (long)gm * ldr + gn, rfl);
      long off = (long)gm * ldc + gn;
      if (outmode == 2){
        if (fl) Cb[off] = f2bf(v); else Cf[off] = v;
      } else if (outmode == 3){
        Cb[off] = f2bf(v);
      } else {
        Cf[off] = v;
      }
      if (cdst) cdst[(long)gm * ldc + gn] = ldw(csrc, (long)gm * 256 + gn, cfl);
    }
  }
}

// ---------------- QKV extract + rotary, 2-descriptor batched --------------
// grid.y = 16: bh = dsc*8 + b*4 + h. Output bf16 head-major (bh,L,64).
__global__ __launch_bounds__(256) void k_rope(
  const float* __restrict__ qkv0, const float* __restrict__ qkv1,
  const void* __restrict__ pe0, const void* __restrict__ pe1,
  u16* __restrict__ q, u16* __restrict__ k, u16* __restrict__ v,
  int L, int B, int H, const int* __restrict__ flagp)
{
  int fl = *flagp;
  int tid = threadIdx.x;
  int lq = tid >> 6, d = tid & 63;
  int l = blockIdx.x * 4 + lq;
  int bh = blockIdx.y;
  int dsc = bh >> 3;
  int bh7 = bh & 7;
  int b = bh7 >> 2, h = bh7 & 3;
  const float* qkv = dsc ? qkv1 : qkv0;
  const void* pe = dsc ? pe1 : pe0;
  const float* row = qkv + ((long)b * L + l) * 768 + h * 192;
  float qv = row[d*3+0], kv = row[d*3+1], vv = row[d*3+2];
  int dn = (d & 1) ? (d - 1) : (d + 1);
  float qn = row[dn*3+0], kn = row[dn*3+1];
  float rq = (d & 1) ? qn : -qn;
  float rk = (d & 1) ? kn : -kn;
  long peo = ((long)b * L + l) * 64 + d;
  float p0 = ldw(pe, peo, fl);
  float p1 = ldw(pe, (long)B * L * 64 + peo, fl);
  long o = ((long)bh * L + l) * 64 + d;
  q[o] = f2bf((qv * p0 + rq * p1) * 0.125f);   // exact pow2 pre-scale
  k[o] = f2bf(kv * p0 + rk * p1);
  v[o] = f2bf(vv);
}

// ---------------- MFMA flash attention, bf16 in / fp32 partials out ------
// K-split via blockIdx.z (NZ=4). Pseudo-batch via blockIdx.y (incl. descriptor).
__global__ __launch_bounds__(256, 8) void k_attn_mfma(
  const u16* __restrict__ Q, long qsb, long qsh, long qsl,
  const u16* __restrict__ Kp, long ksb, long ksh, long ksl,
  const u16* __restrict__ Vp, long vsb, long vsh, long vsl,
  float* __restrict__ Opart, float* __restrict__ mpart, float* __restrict__ lpart,
  int L, int H, int kchunk)
{
  __shared__ u16 Kt[64*72];
  __shared__ u16 Vt[64*72];
  __shared__ u16 Ps[64*72];     // wave-private rows: no barrier needed around it
  const int tid  = threadIdx.x;
  const int w    = tid >> 6;
  const int lane = tid & 63;
  const int quad = lane >> 4;
  const int m    = lane & 15;
  const int bh = blockIdx.y, b = bh / H, h = bh % H;
  const int iq0 = blockIdx.x * 64;
  const int z = blockIdx.z;
  const long BHL = (long)gridDim.y * L;

  const u16* Qb = Q  + b*qsb + h*qsh;
  const u16* Kb = Kp + b*ksb + h*ksh;
  const u16* Vb = Vp + b*vsb + h*vsh;

  s16x8 aq[2];
  {
    const u16* qr = Qb + (long)(iq0 + w*16 + m) * qsl + quad*8;
    aq[0] = *(const s16x8*)(qr);
    aq[1] = *(const s16x8*)(qr + 32);
  }

  f32x4 o_acc[4];
  #pragma unroll
  for (int nt = 0; nt < 4; ++nt) o_acc[nt] = (f32x4){0.f,0.f,0.f,0.f};
  float mrow[4] = {-1e30f,-1e30f,-1e30f,-1e30f};
  float lrow[4] = {0.f,0.f,0.f,0.f};

  const int srow = tid >> 2, sc0 = (tid & 3) << 4;
  const int kg = tid & 15;
  const int dg = tid >> 4;
  const int vcb = ((((dg >> 2) * 2) + (kg >> 1)) & 7) * 8 + (kg & 1) * 4;
  const int modd = m & 1;
  const int pcolb = m & 6;
  const int jend = z * kchunk + kchunk;

  for (int j0 = z * kchunk; j0 < jend; j0 += 64){
    {
      const u16* kr = Kb + (long)(j0 + srow) * ksl + sc0;
      *(uint4*)&Kt[srow*72 + sc0]     = *(const uint4*)kr;
      *(uint4*)&Kt[srow*72 + sc0 + 8] = *(const uint4*)(kr + 8);
      const u16* vr = Vb + (long)(j0 + 4*kg) * vsl + 4*dg;
      ushort4 r0 = *(const ushort4*)(vr);
      ushort4 r1 = *(const ushort4*)(vr + vsl);
      ushort4 r2 = *(const ushort4*)(vr + 2*vsl);
      ushort4 r3 = *(const ushort4*)(vr + 3*vsl);
      u16* vt = &Vt[(4*dg)*72 + vcb];
      *(ushort4*)(vt)       = make_ushort4(r0.x, r1.x, r2.x, r3.x);
      *(ushort4*)(vt + 72)  = make_ushort4(r0.y, r1.y, r2.y, r3.y);
      *(ushort4*)(vt + 144) = make_ushort4(r0.z, r1.z, r2.z, r3.z);
      *(ushort4*)(vt + 216) = make_ushort4(r0.w, r1.w, r2.w, r3.w);
    }
    __syncthreads();

    float sv[4][4];
    #pragma unroll
    for (int ct = 0; ct < 4; ++ct){
      f32x4 acc = (f32x4){0.f,0.f,0.f,0.f};
      #pragma unroll
      for (int s = 0; s < 2; ++s){
        s16x8 bk = *(const s16x8*)&Kt[(ct*16 + m)*72 + s*32 + quad*8];
        acc = __builtin_amdgcn_mfma_f32_16x16x32_bf16(aq[s], bk, acc, 0, 0, 0);
      }
      #pragma unroll
      for (int r = 0; r < 4; ++r) sv[ct][r] = acc[r];
    }

    // tile max per row; defer-max: only rescale when growth > THR=8
    float v0s[4];
    int need = 0;
    #pragma unroll
    for (int r = 0; r < 4; ++r){
      float v0 = fmaxf(fmaxf(sv[0][r], sv[1][r]), fmaxf(sv[2][r], sv[3][r]));
      v0 = dppmax16(v0);
      v0s[r] = v0;
      need |= (v0 > mrow[r] + 8.f) ? 1 : 0;
    }
    if (__any(need)){
      float alpha[4];
      #pragma unroll
      for (int r = 0; r < 4; ++r){
        float mn = fmaxf(mrow[r], v0s[r]);
        alpha[r] = __expf(mrow[r] - mn);
        mrow[r] = mn;
        lrow[r] *= alpha[r];
      }
      #pragma unroll
      for (int nt = 0; nt < 4; ++nt)
        #pragma unroll
        for (int r = 0; r < 4; ++r) o_acc[nt][r] *= alpha[r];
    }
    float rsum[4] = {0.f,0.f,0.f,0.f};
    #pragma unroll
    for (int ct = 0; ct < 4; ++ct)
      #pragma unroll
      for (int r = 0; r < 4; ++r){
        float p = __expf(sv[ct][r] - mrow[r]);
        sv[ct][r] = p;
        rsum[r] += p;
      }
    #pragma unroll
    for (int r = 0; r < 4; ++r)
      lrow[r] += dppsum16(rsum[r]);

    // Ps packed b32 writes (DPP xor1 pair exchange + cvt_pk)
    #pragma unroll
    for (int ct = 0; ct < 4; ++ct){
      const int kb = (2*w + 2*ct + (m >> 3)) & 7;
      const int col = (kb << 3) | pcolb;
      #pragma unroll
      for (int rr = 0; rr < 2; ++rr){
        float nb_lo = dppf<0xB1>(sv[ct][rr]);
        float nb_hi = dppf<0xB1>(sv[ct][2+rr]);
        float lo = modd ? nb_hi       : sv[ct][rr];
        float hi = modd ? sv[ct][2+rr] : nb_lo;
        unsigned int pk = cvtpk(lo, hi);
        int row = w*16 + quad*4 + rr + 2*modd;
        *(unsigned int*)&Ps[row*72 + col] = pk;
      }
    }
    asm volatile("s_waitcnt lgkmcnt(0)" ::: "memory");  // own-wave rows RAW

    s16x8 ap[2];
    #pragma unroll
    for (int s = 0; s < 2; ++s)
      ap[s] = *(const s16x8*)&Ps[(w*16 + m)*72 + (((2*w + 4*s + quad) & 7) << 3)];
    #pragma unroll
    for (int nt = 0; nt < 4; ++nt)
      #pragma unroll
      for (int s = 0; s < 2; ++s){
        s16x8 bv = *(const s16x8*)&Vt[(nt*16 + m)*72 + (((2*nt + 4*s + quad) & 7) << 3)];
        o_acc[nt] = __builtin_amdgcn_mfma_f32_16x16x32_bf16(ap[s], bv, o_acc[nt], 0, 0, 0);
      }
    __syncthreads();
  }

  const long zOoff = (long)z * BHL * 64;
  #pragma unroll
  for (int r = 0; r < 4; ++r){
    int iq = iq0 + w*16 + quad*4 + r;
    long rowid = ((long)b*L + iq) * H + h;
    #pragma unroll
    for (int nt = 0; nt < 4; ++nt)
      Opart[zOoff + rowid*64 + nt*16 + m] = o_acc[nt][r];
    if (m == 0){
      mpart[(long)z*BHL + rowid] = mrow[r];
      lpart[(long)z*BHL + rowid] = lrow[r];
    }
  }
}

// ---------------- attention split combine (4-way, fp32 partials) --------
__global__ __launch_bounds__(256) void k_attn_comb(
  const float* Opart, const float* mpart, const float* lpart,
  float* O, long BHL)
{
  long i = (long)blockIdx.x * 256 + threadIdx.x;
  long row = i >> 6;
  float mv[4];
  float M = -1e30f;
  #pragma unroll
  for (int z = 0; z < 4; ++z){
    mv[z] = mpart[(long)z*BHL + row];
    M = fmaxf(M, mv[z]);
  }
  long N64 = BHL * 64;
  float T = 0.f, acc = 0.f;
  #pragma unroll
  for (int z = 0; z < 4; ++z){
    float wz = __expf(mv[z] - M);
    T   += lpart[(long)z*BHL + row] * wz;
    acc += Opart[(long)z*N64 + i] * wz;
  }
  O[i] = acc / T;
}

// ---------------- depthwise conv K=5 SAME + silu (batched pseudo-b) ------
__global__ __launch_bounds__(256) void k_conv2(
  const float* __restrict__ xz,
  const void* __restrict__ wx, const void* __restrict__ wz,
  float* __restrict__ outx, float* __restrict__ outz,
  int L, const int* __restrict__ flagp)
{
  int fl = *flagp;
  int c = threadIdx.x;
  int bl = blockIdx.x; int b = bl / L, l = bl % L;
  int choff = blockIdx.y ? 256 : 0;
  const void* w = blockIdx.y ? wz : wx;
  float* out = blockIdx.y ? outz : outx;
  const float* base = xz + ((long)b * L) * 512 + choff + c;
  float s = 0.f;
  #pragma unroll
  for (int kk = 0; kk < 5; ++kk){
    int ll = l + kk - 2;
    if (ll >= 0 && ll < L) s += base[(long)ll * 512] * ldw(w, c*5 + kk, fl);
  }
  out[((long)b * L + l) * 256 + c] = s / (1.f + __expf(-s));   // silu
}

// ---------------- chunk-parallel selective scan (xdbl ld 64) ----------------
// Batched: pseudo-b in [0,4) (descriptor*2 + batch); NP = #pseudo-b * 256.
#define SC_CS 64
#define SC_NC 32

__global__ __launch_bounds__(256) void k_scan1(
  const float* __restrict__ delta, const float* __restrict__ dxc,
  const float* __restrict__ xdbl, const void* __restrict__ Alog,
  float* __restrict__ E_out, float* __restrict__ F_out,
  int L, const int* __restrict__ flagp)
{
  int fl = *flagp;
  int tid = threadIdx.x;
  int g = tid >> 4, n = tid & 15;
  int gid = blockIdx.x * 16 + g;
  int chunk = gid & (SC_NC - 1);
  int p = gid >> 5;
  int b = p >> 8, d = p & 255;
  float A = -__expf(ldw(Alog, d*16 + n, fl));
  const float* dtp = delta + (long)b*L*256 + d;
  const float* dxp = dxc   + (long)b*L*256 + d;
  const float* xdb = xdbl + (long)b*L*64;
  int l0 = chunk * SC_CS;
  float E = 1.f, F = 0.f;
  for (int i = 0; i < SC_CS; i += 4){
    float e[4], u[4];
    #pragma unroll
    for (int j = 0; j < 4; ++j){
      int l = l0 + i + j;
      e[j] = __expf(dtp[(long)l*256] * A);
      u[j] = dxp[(long)l*256] * xdb[l*64 + 16 + n];
    }
    F = e[0]*F + u[0]; F = e[1]*F + u[1];
    F = e[2]*F + u[2]; F = e[3]*F + u[3];
    E *= (e[0]*e[1]) * (e[2]*e[3]);
  }
  long idx = (long)(p*16 + n) * SC_NC + chunk;
  E_out[idx] = E; F_out[idx] = F;
}

__global__ __launch_bounds__(256) void k_scan2(
  const float* __restrict__ E, const float* __restrict__ F,
  float* __restrict__ Hin)
{
  int pn = blockIdx.x * 256 + threadIdx.x;
  const float* Ep = E + (long)pn * SC_NC;
  const float* Fp = F + (long)pn * SC_NC;
  float* Hp = Hin + (long)pn * SC_NC;
  float h = 0.f;
  #pragma unroll
  for (int c = 0; c < SC_NC; ++c){
    Hp[c] = h;
    h = Ep[c] * h + Fp[c];
  }
}

__global__ __launch_bounds__(256) void k_scan3(
  const float* __restrict__ delta, const float* __restrict__ dxc,
  const float* __restrict__ xc, const float* __restrict__ xdbl,
  const void* __restrict__ Alog, const void* __restrict__ Dp,
  const float* __restrict__ Hin, float* __restrict__ y,
  int L, const int* __restrict__ flagp)
{
  int fl = *flagp;
  int tid = threadIdx.x;
  int g = tid >> 4, n = tid & 15;
  int gid = blockIdx.x * 16 + g;
  int chunk = gid & (SC_NC - 1);
  int p = gid >> 5;
  int b = p >> 8, d = p & 255;
  float A = -__expf(ldw(Alog, d*16 + n, fl));
  float Dv = ldw(Dp, d, fl);
  const float* dtp = delta + (long)b*L*256 + d;
  const float* dxp = dxc   + (long)b*L*256 + d;
  const float* xcb = xc    + (long)b*L*256 + d;
  const float* xdb = xdbl + (long)b*L*64;
  float* yb = y + (long)b*L*256 + d;
  long idx = (long)(p*16 + n) * SC_NC + chunk;
  float h = Hin[idx];
  int l0 = chunk * SC_CS;
  for (int i = 0; i < SC_CS; i += 4){
    float e[4], u[4], cm[4], xv[4];
    #pragma unroll
    for (int j = 0; j < 4; ++j){
      int l = l0 + i + j;
      e[j]  = __expf(dtp[(long)l*256] * A);
      u[j]  = dxp[(long)l*256] * xdb[l*64 + 16 + n];
      cm[j] = xdb[l*64 + 32 + n];
      xv[j] = xcb[(long)l*256];
    }
    float s0, s1, s2, s3;
    h = e[0]*h + u[0]; s0 = h * cm[0];
    h = e[1]*h + u[1]; s1 = h * cm[1];
    h = e[2]*h + u[2]; s2 = h * cm[2];
    h = e[3]*h + u[3]; s3 = h * cm[3];
    s0 += __shfl_xor(s0, 1, 16); s1 += __shfl_xor(s1, 1, 16);
    s2 += __shfl_xor(s2, 1, 16); s3 += __shfl_xor(s3, 1, 16);
    s0 += __shfl_xor(s0, 2, 16); s1 += __shfl_xor(s1, 2, 16);
    s2 += __shfl_xor(s2, 2, 16); s3 += __shfl_xor(s3, 2, 16);
    s0 += __shfl_xor(s0, 4, 16); s1 += __shfl_xor(s1, 4, 16);
    s2 += __shfl_xor(s2, 4, 16); s3 += __shfl_xor(s3, 4, 16);
    s0 += __shfl_xor(s0, 8, 16); s1 += __shfl_xor(s1, 8, 16);
    s2 += __shfl_xor(s2, 8, 16); s3 += __shfl_xor(s3, 8, 16);
    if (n < 4){
      float out = (n == 0) ? s0 + Dv*xv[0] : (n == 1) ? s1 + Dv*xv[1]
                : (n == 2) ? s2 + Dv*xv[2] : s3 + Dv*xv[3];
      yb[(long)(l0 + i + n)*256] = out;
    }
  }
}

// two-buffer LN with split-K partial sum (both descriptors batched)
__global__ __launch_bounds__(256) void k_ln2(
  float* __restrict__ hA, const float* __restrict__ hA2,
  float* __restrict__ hB, const float* __restrict__ hB2,
  const void* __restrict__ g, const void* __restrict__ beta,
  const int* __restrict__ flagp)
{
  int fl = *flagp;
  int r = blockIdx.x * 4 + (threadIdx.x >> 6);
  float* hbase = (r < 4096) ? hA : hB;
  const float* h2base = (r < 4096) ? hA2 : hB2;
  int row = r & 4095;
  int lane = threadIdx.x & 63;
  float* hr = hbase + (long)row * 512;
  const float* h2r = h2base + (long)row * 512;
  float v[8]; float s = 0.f, ss = 0.f;
  #pragma unroll
  for (int i = 0; i < 8; ++i){
    v[i] = hr[lane + 64*i] + h2r[lane + 64*i];
    s += v[i]; ss += v[i]*v[i];
  }
  #pragma unroll
  for (int off = 1; off < 64; off <<= 1){ s += __shfl_xor(s, off); ss += __shfl_xor(ss, off); }
  float mean = s * (1.f/512.f);
  float var  = ss * (1.f/512.f) - mean * mean;
  float rs = rsqrtf(var + 1e-5f);
  #pragma unroll
  for (int i = 0; i < 8; ++i){
    int c = lane + 64*i;
    hr[c] = (v[i] - mean) * rs * ldw(g, c, fl) + ldw(beta, c, fl);
  }
}

extern "C" void kernel_launch(void* const* d_in, const int* in_sizes, int n_in,
                              void* d_out, int out_size, void* d_ws, size_t ws_size,
                              hipStream_t stream)
{
  const int B_ = 2, L_ = 2048, H_ = 4;
  const long BLE = (long)B_ * L_ * 256;       // 1,048,576 floats
  const long BHLb = 2L * B_ * H_ * L_;        // 32,768 (batched pseudo-heads)
  const long BHLc = (long)B_ * H_ * L_;       // 16,384 (cross)

  int* flagp = (int*)d_ws;
  float* base = (float*)d_ws + 64;

  // ---- generous descriptor-major workspace map (ws = 256 MiB = 64 BLE) ----
  float* cat0   = base + 0*BLE;    // 3 BLE, ld 768
  float* cat1   = base + 3*BLE;    // 3 BLE
  float* xz01   = base + 6*BLE;    // 4 BLE, pseudo-b ld 512
  u16*   q01    = (u16*)(base + 10*BLE);   // 1 BLE each (16 heads x L x 64 bf16)
  u16*   k01    = (u16*)(base + 11*BLE);
  u16*   v01    = (u16*)(base + 12*BLE);
  float* Opart  = base + 13*BLE;   // 8 BLE (4 z-planes x 2 BLE batched)
  float* ob01   = base + 21*BLE;   // 2 BLE
  float* mml    = base + 23*BLE;   // 4*32768
  float* mll    = mml + 4*32768;   // fits within 1 BLE slot
  float* xc01   = base + 24*BLE;   // 2 BLE
  float* zc01   = base + 26*BLE;   // 2 BLE
  float* xdbl01 = base + 28*BLE;   // 0.5 BLE
  float* delta01= base + 29*BLE;   // 2 BLE
  float* dxc01  = base + 31*BLE;   // 2 BLE
  float* scE    = base + 33*BLE;   // 0.5 BLE
  float* scF    = scE + 524288;
  float* scH    = scF + 524288;    // ends +34.5
  float* y01    = base + 35*BLE;   // 2 BLE
  float* catc0  = base + 37*BLE;   // 4 BLE, ld 1024
  float* catc1  = base + 41*BLE;   // 4 BLE
  float* h0     = base + 45*BLE;   // 2 BLE, ld 512
  float* part0  = base + 47*BLE;   // 2 BLE
  float* h1     = base + 49*BLE;   // 2 BLE
  float* part1  = base + 51*BLE;   // 2 BLE
  float* dbuf0  = base + 53*BLE;
  float* dbuf1  = base + 54*BLE;
  u16*   qc     = (u16*)(base + 55*BLE);   // cross q/k/v/o bf16, 0.5 BLE each
  u16*   kc     = qc + 1048576;
  u16*   vc     = kc + 1048576;
  u16*   oc     = vc + 1048576;            // ends +57
  float* catA   = base + 57*BLE;   // 2 BLE, ld 512
  float* catB   = base + 59*BLE;   // 2 BLE
  float* px     = base + 61*BLE;   // 16,384
  float* pd     = px + 16384;      // 16,384
  float* pb     = pd + 16384;      // 256

  const void* in[35];
  for (int i = 0; i < 35 && i < n_in; ++i) in[i] = d_in[i];

  k_sniff<<<1, 256, 0, stream>>>((const unsigned int*)in[0], 2048, flagp);
  k_pad<<<130, 256, 0, stream>>>(in[17], in[18], in[19], px, pd, pb, flagp);

  const int BIG = 1 << 30;
  const long sbP = (long)H_ * L_ * 64, shP = (long)L_ * 64, slP = 64;   // per pseudo-b
  const long sbF = (long)L_ * 256,     shF = 64,            slF = 256;  // (B,L,256)
  const int kchunk = L_ / 4;

  // ---------------- batched mamba_attention (both descriptors) ----------------
  // merged qkv (N 0..767 -> cat ld 768) + xz (768..1279 -> xz ld 512), per desc
  k_gemm_mfma<<<dim3(20, 64), 256, 0, stream>>>(
      in[0], 0, 256, 256, 1280, in[4], in[14], 768, 0, in[5],
      cat0, nullptr, 768, xz01, 512,
      nullptr, 1, 0, nullptr, 1, nullptr, 1.f, 0, 0, flagp);
  k_gemm_mfma<<<dim3(20, 64), 256, 0, stream>>>(
      in[1], 0, 256, 256, 1280, in[4], in[14], 768, 0, in[5],
      cat1, nullptr, 768, xz01 + 2*BLE, 512,
      nullptr, 1, 0, nullptr, 1, nullptr, 1.f, 0, 0, flagp);
  k_rope<<<dim3(L_/4, 16), 256, 0, stream>>>(cat0, cat1, in[2], in[3],
      q01, k01, v01, L_, B_, H_, flagp);
  k_attn_mfma<<<dim3(L_/64, 16, 4), 256, 0, stream>>>(
      q01, sbP, shP, slP, k01, sbP, shP, slP, v01, sbP, shP, slP,
      Opart, mml, mll, L_, H_, kchunk);
  k_attn_comb<<<8192, 256, 0, stream>>>(Opart, mml, mll, ob01, BHLb);
  k_conv2<<<dim3(2*B_*L_, 2), 256, 0, stream>>>(xz01, in[15], in[16], xc01, zc01, L_, flagp);
  // xproj (padded N=64, fp32 weights) into xdbl ld 64; M=8192 both descs
  k_gemm_mfma<<<dim3(1, 128), 256, 0, stream>>>(
      xc01, 1, 256, 256, 64, px, nullptr, BIG, 1, nullptr,
      xdbl01, nullptr, 64, nullptr, 0,
      nullptr, 1, 0, nullptr, 1, nullptr, 1.f, 0, 0, flagp);
  // dt (padded K=64) + fused softplus -> delta, dxc; M=8192
  k_gemm_mfma<<<dim3(4, 128), 256, 0, stream>>>(
      xdbl01, 1, 64, 64, 256, pd, nullptr, BIG, 1, pb,
      delta01, nullptr, 256, dxc01, 256,
      xc01, 1, 256, nullptr, 1, nullptr, 1.f, 0, 4, flagp);
  k_scan1<<<2048, 256, 0, stream>>>(delta01, dxc01, xdbl01, in[20], scE, scF, L_, flagp);
  k_scan2<<<64, 256, 0, stream>>>(scE, scF, scH);
  k_scan3<<<2048, 256, 0, stream>>>(delta01, dxc01, xc01, xdbl01, in[20], in[21], scH, y01, L_, flagp);
  // batched s_x / c_x / o-proj (+fused raw-input->cat copy), z=6
  {
    GB8 gb = {};
    gb.A[0] = y01;        gb.W[0] = in[22]; gb.Cf[0] = catc0 + 512; gb.osc[0] = 1.f; gb.cfl[0] = 1;
    gb.A[1] = zc01;       gb.W[1] = in[22]; gb.Cf[1] = catc0 + 768; gb.osc[1] = 1.f; gb.cfl[1] = 1;
    gb.A[2] = ob01;       gb.W[2] = in[6];  gb.bias[2] = in[7];     gb.Cf[2] = catc0 + 256;
    gb.csrc[2] = in[0];   gb.cdst[2] = catc0; gb.osc[2] = 1.f;      gb.cfl[2] = 0;
    gb.A[3] = y01 + BLE;  gb.W[3] = in[22]; gb.Cf[3] = catc1 + 512; gb.osc[3] = 1.f; gb.cfl[3] = 1;
    gb.A[4] = zc01 + BLE; gb.W[4] = in[22]; gb.Cf[4] = catc1 + 768; gb.osc[4] = 1.f; gb.cfl[4] = 1;
    gb.A[5] = ob01 + BLE; gb.W[5] = in[6];  gb.bias[5] = in[7];     gb.Cf[5] = catc1 + 256;
    gb.csrc[5] = in[1];   gb.cdst[5] = catc1; gb.osc[5] = 1.f;      gb.cfl[5] = 0;
    k_gemmb<<<dim3(4, 64, 6), 256, 0, stream>>>(gb, 256, 256, 256, 1024, 0, 256, 0, 0, flagp);
  }
  // ffn1 split-K=2 per descriptor (z=4)
  {
    GB8 gb = {};
    gb.cfl[0] = gb.cfl[1] = gb.cfl[2] = gb.cfl[3] = 1;
    gb.A[0] = catc0;       gb.W[0] = in[8]; gb.bias[0] = in[9]; gb.Cf[0] = h0;    gb.osc[0] = 1.f;
    gb.A[1] = catc0 + 512; gb.W[1] = in[8]; gb.wkoff[1] = 512;  gb.Cf[1] = part0; gb.osc[1] = 1.f;
    gb.A[2] = catc1;       gb.W[2] = in[8]; gb.bias[2] = in[9]; gb.Cf[2] = h1;    gb.osc[2] = 1.f;
    gb.A[3] = catc1 + 512; gb.W[3] = in[8]; gb.wkoff[3] = 512;  gb.Cf[3] = part1; gb.osc[3] = 1.f;
    k_gemmb<<<dim3(8, 64, 4), 256, 0, stream>>>(gb, 1024, 512, 512, 512, 0, 1024, 0, 0, flagp);
  }
  k_ln2<<<2048, 256, 0, stream>>>(h0, part0, h1, part1, in[10], in[11], flagp);
  // ffn2: gelu(h) @ W^T + bias + raw-input residual (dtype-aware), z=2
  {
    GB8 gb = {};
    gb.cfl[0] = gb.cfl[1] = 1;
    gb.A[0] = h0; gb.W[0] = in[12]; gb.bias[0] = in[13]; gb.resid[0] = in[0]; gb.rfli[0] = 0;
    gb.Cf[0] = dbuf0; gb.osc[0] = 1.f;
    gb.A[1] = h1; gb.W[1] = in[12]; gb.bias[1] = in[13]; gb.resid[1] = in[1]; gb.rfli[1] = 0;
    gb.Cf[1] = dbuf1; gb.osc[1] = 1.f;
    k_gemmb<<<dim3(4, 64, 2), 256, 0, stream>>>(gb, 512, 512, 256, 256, 256, 512, 1, 0, flagp);
  }

  // ---------------- cross attention ----------------
  const float s4 = 0.35355339059327373f;  // 64^-0.25
  float* cm0 = xc01;           // cross comb outputs reuse xc slots
  float* cm1 = xc01 + BLE;
  {
    GB8 gb = {};
    gb.cfl[0] = gb.cfl[1] = gb.cfl[2] = gb.cfl[3] = 1;
    gb.A[0] = dbuf0; gb.W[0] = in[23]; gb.bias[0] = in[24]; gb.Cb[0] = qc; gb.osc[0] = s4;
    gb.A[1] = dbuf1; gb.W[1] = in[23]; gb.bias[1] = in[24]; gb.Cb[1] = kc; gb.osc[1] = s4;
    gb.A[2] = dbuf0; gb.W[2] = in[25]; gb.bias[2] = in[26]; gb.Cb[2] = vc; gb.osc[2] = 1.f;
    gb.A[3] = dbuf1; gb.W[3] = in[25]; gb.bias[3] = in[26]; gb.Cb[3] = oc; gb.osc[3] = 1.f;
    k_gemmb<<<dim3(4, 64, 4), 256, 0, stream>>>(gb, 256, 256, 256, 256, 0, 256, 0, 3, flagp);
  }
  k_attn_mfma<<<dim3(L_/64, B_*H_, 4), 256, 0, stream>>>(
      qc, sbF, shF, slF, kc, sbF, shF, slF, oc, sbF, shF, slF,
      Opart, mml, mll, L_, H_, kchunk);
  k_attn_comb<<<4096, 256, 0, stream>>>(Opart, mml, mll, cm0, BHLc);
  k_attn_mfma<<<dim3(L_/64, B_*H_, 4), 256, 0, stream>>>(
      kc, sbF, shF, slF, qc, sbF, shF, slF, vc, sbF, shF, slF,
      Opart, mml, mll, L_, H_, kchunk);
  k_attn_comb<<<4096, 256, 0, stream>>>(Opart, mml, mll, cm1, BHLc);
  {
    GB8 gb = {};
    gb.cfl[0] = gb.cfl[1] = 1;
    gb.A[0] = cm0; gb.W[0] = in[27]; gb.bias[0] = in[28]; gb.Cf[0] = catA + 256;
    gb.csrc[0] = dbuf0; gb.cdst[0] = catA; gb.osc[0] = 1.f;
    gb.A[1] = cm1; gb.W[1] = in[27]; gb.bias[1] = in[28]; gb.Cf[1] = catB + 256;
    gb.csrc[1] = dbuf1; gb.cdst[1] = catB; gb.osc[1] = 1.f;
    k_gemmb<<<dim3(4, 64, 2), 256, 0, stream>>>(gb, 256, 256, 256, 512, 0, 256, 0, 0, flagp);
  }
  // ca-ffn1 split-K=2 per descriptor (z=4)
  {
    GB8 gb = {};
    gb.cfl[0] = gb.cfl[1] = gb.cfl[2] = gb.cfl[3] = 1;
    gb.A[0] = catA;       gb.W[0] = in[29]; gb.bias[0] = in[30]; gb.Cf[0] = h0;    gb.osc[0] = 1.f;
    gb.A[1] = catA + 256; gb.W[1] = in[29]; gb.wkoff[1] = 256;   gb.Cf[1] = part0; gb.osc[1] = 1.f;
    gb.A[2] = catB;       gb.W[2] = in[29]; gb.bias[2] = in[30]; gb.Cf[2] = h1;    gb.osc[2] = 1.f;
    gb.A[3] = catB + 256; gb.W[3] = in[29]; gb.wkoff[3] = 256;   gb.Cf[3] = part1; gb.osc[3] = 1.f;
    k_gemmb<<<dim3(8, 64, 4), 256, 0, stream>>>(gb, 512, 256, 512, 512, 0, 512, 0, 0, flagp);
  }
  k_ln2<<<2048, 256, 0, stream>>>(h0, part0, h1, part1, in[31], in[32], flagp);
  {
    GB8 gb = {};
    gb.cfl[0] = gb.cfl[1] = 1;
    gb.rfli[0] = gb.rfli[1] = 1;
    gb.A[0] = h0; gb.W[0] = in[33]; gb.bias[0] = in[34]; gb.resid[0] = dbuf0;
    gb.Cf[0] = (float*)d_out; gb.Cb[0] = (u16*)d_out; gb.osc[0] = 1.f;
    gb.A[1] = h1; gb.W[1] = in[33]; gb.bias[1] = in[34]; gb.resid[1] = dbuf1;
    gb.Cf[1] = (float*)d_out + BLE; gb.Cb[1] = (u16*)d_out + BLE; gb.osc[1] = 1.f;
    k_gemmb<<<dim3(4, 64, 2), 256, 0, stream>>>(gb, 512, 512, 256, 256, 256, 512, 1, 2, flagp);
  }
}

// Round 7
// 657.830 us; speedup vs baseline: 1.2468x; 1.0733x over previous
//
#include <hip/hip_runtime.h>

typedef unsigned short u16;
typedef short s16;
typedef s16 s16x8 __attribute__((ext_vector_type(8)));
typedef float f32x4 __attribute__((ext_vector_type(4)));

__device__ __forceinline__ float bf2f(u16 u){
  union { unsigned int i; float f; } v; v.i = ((unsigned int)u) << 16; return v.f;
}
__device__ __forceinline__ u16 f2bf(float f){
  union { float f; unsigned int u; } v; v.f = f;
  unsigned int r = (v.u + 0x7fffu + ((v.u >> 16) & 1u)) >> 16;
  return (u16)r;
}
// packed f32x2 -> bf16x2 (RNE, identical to f2bf) in ONE VALU op
__device__ __forceinline__ unsigned int cvtpk(float lo, float hi){
  unsigned int d;
  asm("v_cvt_pk_bf16_f32 %0, %1, %2" : "=v"(d) : "v"(lo), "v"(hi));
  return d;
}
__device__ __forceinline__ uint4 pack8(float4 a0, float4 a1){
  uint4 v;
  v.x = cvtpk(a0.x, a0.y); v.y = cvtpk(a0.z, a0.w);
  v.z = cvtpk(a1.x, a1.y); v.w = cvtpk(a1.z, a1.w);
  return v;
}
__device__ __forceinline__ float gelu_f(float x){
  return 0.5f * x * (1.f + erff(x * 0.70710678118654752440f));
}
__device__ __forceinline__ float ldw(const void* p, long i, int fl){
  return fl ? bf2f(((const u16*)p)[i]) : ((const float*)p)[i];
}
__device__ __forceinline__ float4 ldw4(const void* p, long i, int fl){
  if (fl){
    ushort4 w = *(const ushort4*)((const u16*)p + i);
    return make_float4(bf2f(w.x), bf2f(w.y), bf2f(w.z), bf2f(w.w));
  }
  return *(const float4*)((const float*)p + i);
}

// ---- DPP 16-lane butterfly reductions (VALU pipe, zero LDS traffic) ----
template<int C>
__device__ __forceinline__ float dppf(float x){
  return __int_as_float(__builtin_amdgcn_update_dpp(0, __float_as_int(x), C, 0xf, 0xf, true));
}
__device__ __forceinline__ float dppmax16(float v){
  v = fmaxf(v, dppf<0xB1>(v));
  v = fmaxf(v, dppf<0x4E>(v));
  v = fmaxf(v, dppf<0x141>(v));
  v = fmaxf(v, dppf<0x140>(v));
  return v;
}
__device__ __forceinline__ float dppsum16(float v){
  v += dppf<0xB1>(v);
  v += dppf<0x4E>(v);
  v += dppf<0x141>(v);
  v += dppf<0x140>(v);
  return v;
}

// ---------------- dtype sniffer (flag[0]=dtype, flag[1]=0 const) --------
__global__ __launch_bounds__(256) void k_sniff(const unsigned int* __restrict__ w,
                                               int n, int* __restrict__ flag){
  __shared__ int cnt[256];
  int c = 0;
  for (int i = threadIdx.x; i < n; i += 256){
    unsigned e = (w[i] >> 7) & 0xFFu;
    c += (e >= 120u && e <= 127u) ? 1 : 0;
  }
  cnt[threadIdx.x] = c; __syncthreads();
  for (int s = 128; s > 0; s >>= 1){
    if (threadIdx.x < s) cnt[threadIdx.x] += cnt[threadIdx.x + s];
    __syncthreads();
  }
  if (threadIdx.x == 0) flag[0] = (2 * cnt[0] > n) ? 1 : 0;
  if (threadIdx.x == 1) flag[1] = 0;
}

// ---- zero-pad xproj (48x256 -> 64x256) / dt_w (256x16 -> 256x64) / dt_b ----
__global__ __launch_bounds__(256) void k_pad(
  const void* __restrict__ wx, const void* __restrict__ wd,
  const void* __restrict__ bd,
  float* __restrict__ px, float* __restrict__ pd, float* __restrict__ pb,
  const int* __restrict__ flagp)
{
  int fl = *flagp;
  int i = blockIdx.x * 256 + threadIdx.x;
  if (i < 16384){
    int r = i >> 8, c = i & 255;
    px[i] = (r < 48) ? ldw(wx, r*256 + c, fl) : 0.f;
  } else if (i < 32768){
    int j = i - 16384;
    int n = j >> 6, k = j & 63;
    pd[j] = (k < 16) ? ldw(wd, n*16 + k, fl) : 0.f;
  } else if (i < 33024){
    pb[i - 32768] = ldw(bd, i - 32768, fl);
  }
}

// ---------------- MFMA GEMM (staged 64x64 tile) ----------------
// outmode: 0 fp32, 2 dynamic, 3 bf16,
//          4 softplus(dt+2*bias) -> Cf TRANSPOSED (d-major, ld=ldc),
//            delta*resid -> C2 TRANSPOSED (ld=ldc2).
__global__ __launch_bounds__(256) void k_gemm_mfma(
  const void* __restrict__ A, int aflidx, int lda, int K, int N,
  const void* __restrict__ W, const void* __restrict__ W2, int nsplit, int wflidx,
  const void* __restrict__ bias,
  float* __restrict__ Cf, u16* __restrict__ Cb, int ldc,
  float* __restrict__ C2, int ldc2,
  const void* __restrict__ resid, int rflidx, int ldr,
  const void* __restrict__ csrc, int cflidx, float* __restrict__ cdst,
  float oscale, int act_gelu, int outmode, const int* __restrict__ flagp)
{
  const int fl  = flagp[0];
  const int afl = flagp[aflidx];
  const int wfl = flagp[wflidx];
  const int rfl = flagp[rflidx];
  const int cfl = flagp[cflidx];
  __shared__ u16 As[64*72];
  __shared__ u16 Bs[64*72];
  const int tid = threadIdx.x;
  const int w = tid >> 6, lane = tid & 63, quad = lane >> 4, m = lane & 15;
  const int m0 = blockIdx.y << 6, n0 = blockIdx.x << 6;
  const int srow = tid >> 2, sc0 = (tid & 3) << 4;
  const int reg2 = (n0 >= nsplit);
  const void* Wp = reg2 ? W2 : W;
  const int nbase = reg2 ? nsplit : 0;

  f32x4 acc[4];
  #pragma unroll
  for (int ct = 0; ct < 4; ++ct) acc[ct] = (f32x4){0.f,0.f,0.f,0.f};

  for (int k0 = 0; k0 < K; k0 += 64){
    {
      long ab = (long)(m0 + srow) * lda + k0 + sc0;
      if (afl && !act_gelu){
        #pragma unroll
        for (int g = 0; g < 2; ++g)
          *(uint4*)&As[srow*72 + sc0 + g*8] = *(const uint4*)((const u16*)A + ab + g*8);
      } else {
        #pragma unroll
        for (int g = 0; g < 2; ++g){
          float4 a0 = ldw4(A, ab + g*8, afl);
          float4 a1 = ldw4(A, ab + g*8 + 4, afl);
          if (act_gelu){
            a0.x=gelu_f(a0.x); a0.y=gelu_f(a0.y); a0.z=gelu_f(a0.z); a0.w=gelu_f(a0.w);
            a1.x=gelu_f(a1.x); a1.y=gelu_f(a1.y); a1.z=gelu_f(a1.z); a1.w=gelu_f(a1.w);
          }
          *(uint4*)&As[srow*72 + sc0 + g*8] = pack8(a0, a1);
        }
      }
    }
    {
      long wb = (long)(n0 + srow - nbase) * K + k0 + sc0;
      if (wfl){
        #pragma unroll
        for (int g = 0; g < 2; ++g)
          *(uint4*)&Bs[srow*72 + sc0 + g*8] = *(const uint4*)((const u16*)Wp + wb + g*8);
      } else {
        #pragma unroll
        for (int g = 0; g < 2; ++g){
          float4 b0 = *(const float4*)((const float*)Wp + wb + g*8);
          float4 b1 = *(const float4*)((const float*)Wp + wb + g*8 + 4);
          *(uint4*)&Bs[srow*72 + sc0 + g*8] = pack8(b0, b1);
        }
      }
    }
    __syncthreads();

    s16x8 av[2];
    #pragma unroll
    for (int s = 0; s < 2; ++s)
      av[s] = *(const s16x8*)&As[(w*16 + m)*72 + s*32 + quad*8];
    #pragma unroll
    for (int ct = 0; ct < 4; ++ct)
      #pragma unroll
      for (int s = 0; s < 2; ++s){
        s16x8 bv = *(const s16x8*)&Bs[(ct*16 + m)*72 + s*32 + quad*8];
        acc[ct] = __builtin_amdgcn_mfma_f32_16x16x32_bf16(av[s], bv, acc[ct], 0, 0, 0);
      }
    __syncthreads();
  }

  if (outmode == 4){
    // transposed float4 stores: acc[ct] = 4 consecutive rows for column gn
    const int gmb = m0 + w*16 + quad*4;
    #pragma unroll
    for (int ct = 0; ct < 4; ++ct){
      int gn = n0 + ct*16 + m;
      float bv = ldw(bias, gn, wfl);
      float dl4[4], dx4[4];
      #pragma unroll
      for (int r = 0; r < 4; ++r){
        float dl = acc[ct][r] + bv + bv;     // dt + 2*dt_bias (ref's double add)
        float delta = (dl > 20.f) ? dl : __logf(1.f + __expf(dl));
        dl4[r] = delta;
        dx4[r] = delta * ldw(resid, (long)(gmb + r) * ldr + gn, rfl);
      }
      *(float4*)&Cf[(long)gn * ldc + gmb] = make_float4(dl4[0], dl4[1], dl4[2], dl4[3]);
      *(float4*)&C2[(long)gn * ldc2 + gmb] = make_float4(dx4[0], dx4[1], dx4[2], dx4[3]);
    }
    return;
  }

  #pragma unroll
  for (int r = 0; r < 4; ++r){
    int gm = m0 + w*16 + quad*4 + r;
    #pragma unroll
    for (int ct = 0; ct < 4; ++ct){
      int gn = n0 + ct*16 + m;
      float v = acc[ct][r];
      if (reg2){
        C2[(long)gm * ldc2 + (gn - nsplit)] = v;
      } else {
        if (bias) v += ldw(bias, gn, wfl);
        v *= oscale;
        if (resid) v += ldw(resid, (long)gm * ldr + gn, rfl);
        long off = (long)gm * ldc + gn;
        if (outmode == 2){
          if (fl) Cb[off] = f2bf(v); else Cf[off] = v;
        } else if (outmode == 3){
          Cb[off] = f2bf(v);
        } else {
          Cf[off] = v;
        }
        if (cdst) cdst[(long)gm * ldc + gn] = ldw(csrc, (long)gm * 256 + gn, cfl);
      }
    }
  }
}

// ---------------- z-batched MFMA GEMM (up to 8 independent problems) ----------------
// ldwq = weight row stride; wkoff = per-z weight k-offset (split-K).
// rfli[z] = flag index for resid dtype. aux[z] nonnull: A' = A + dvec[k]*aux (fused D*xc).
struct GB8 {
  const float* A[8]; const void* W[8]; const void* bias[8];
  float* Cf[8]; u16* Cb[8]; const void* resid[8];
  const void* csrc[8]; float* cdst[8]; float osc[8];
  int cfl[8]; int wkoff[8]; int rfli[8];
  const float* aux[8]; const void* dvec;
};

__global__ __launch_bounds__(256) void k_gemmb(
  GB8 gb, int lda, int K, int N, int ldc, int ldr, int ldwq,
  int act_gelu, int outmode, const int* __restrict__ flagp)
{
  const int fl = flagp[0];
  const int z = blockIdx.z;
  const float* A = gb.A[z]; const void* W = gb.W[z]; const void* bias = gb.bias[z];
  float* Cf = gb.Cf[z]; u16* Cb = gb.Cb[z]; const void* resid = gb.resid[z];
  const void* csrc = gb.csrc[z]; float* cdst = gb.cdst[z];
  const float osc = gb.osc[z];
  const int cfl = flagp[gb.cfl[z]];
  const int rfl = flagp[gb.rfli[z]];
  const int wkoff = gb.wkoff[z];
  const float* aux = gb.aux[z];

  __shared__ u16 As[64*72];
  __shared__ u16 Bs[64*72];
  const int tid = threadIdx.x;
  const int w = tid >> 6, lane = tid & 63, quad = lane >> 4, m = lane & 15;
  const int m0 = blockIdx.y << 6, n0 = blockIdx.x << 6;
  const int srow = tid >> 2, sc0 = (tid & 3) << 4;

  f32x4 acc[4];
  #pragma unroll
  for (int ct = 0; ct < 4; ++ct) acc[ct] = (f32x4){0.f,0.f,0.f,0.f};

  for (int k0 = 0; k0 < K; k0 += 64){
    {
      const float* ar = A + (long)(m0 + srow) * lda + k0 + sc0;
      #pragma unroll
      for (int g = 0; g < 2; ++g){
        float4 a0 = *(const float4*)(ar + g*8);
        float4 a1 = *(const float4*)(ar + g*8 + 4);
        if (aux){
          const float* xr = aux + (long)(m0 + srow) * lda + k0 + sc0;
          float4 x0 = *(const float4*)(xr + g*8);
          float4 x1 = *(const float4*)(xr + g*8 + 4);
          float4 d0 = ldw4(gb.dvec, k0 + sc0 + g*8, fl);
          float4 d1 = ldw4(gb.dvec, k0 + sc0 + g*8 + 4, fl);
          a0.x += d0.x*x0.x; a0.y += d0.y*x0.y; a0.z += d0.z*x0.z; a0.w += d0.w*x0.w;
          a1.x += d1.x*x1.x; a1.y += d1.y*x1.y; a1.z += d1.z*x1.z; a1.w += d1.w*x1.w;
        }
        if (act_gelu){
          a0.x=gelu_f(a0.x); a0.y=gelu_f(a0.y); a0.z=gelu_f(a0.z); a0.w=gelu_f(a0.w);
          a1.x=gelu_f(a1.x); a1.y=gelu_f(a1.y); a1.z=gelu_f(a1.z); a1.w=gelu_f(a1.w);
        }
        *(uint4*)&As[srow*72 + sc0 + g*8] = pack8(a0, a1);
      }
    }
    {
      long wb = (long)(n0 + srow) * ldwq + wkoff + k0 + sc0;
      if (fl){
        #pragma unroll
        for (int g = 0; g < 2; ++g)
          *(uint4*)&Bs[srow*72 + sc0 + g*8] = *(const uint4*)((const u16*)W + wb + g*8);
      } else {
        #pragma unroll
        for (int g = 0; g < 2; ++g){
          float4 b0 = *(const float4*)((const float*)W + wb + g*8);
          float4 b1 = *(const float4*)((const float*)W + wb + g*8 + 4);
          *(uint4*)&Bs[srow*72 + sc0 + g*8] = pack8(b0, b1);
        }
      }
    }
    __syncthreads();

    s16x8 av[2];
    #pragma unroll
    for (int s = 0; s < 2; ++s)
      av[s] = *(const s16x8*)&As[(w*16 + m)*72 + s*32 + quad*8];
    #pragma unroll
    for (int ct = 0; ct < 4; ++ct)
      #pragma unroll
      for (int s = 0; s < 2; ++s){
        s16x8 bv = *(const s16x8*)&Bs[(ct*16 + m)*72 + s*32 + quad*8];
        acc[ct] = __builtin_amdgcn_mfma_f32_16x16x32_bf16(av[s], bv, acc[ct], 0, 0, 0);
      }
    __syncthreads();
  }

  #pragma unroll
  for (int r = 0; r < 4; ++r){
    int gm = m0 + w*16 + quad*4 + r;
    #pragma unroll
    for (int ct = 0; ct < 4; ++ct){
      int gn = n0 + ct*16 + m;
      float v = acc[ct][r];
      if (bias) v += ldw(bias, gn, fl);
      v *= osc;
      if (resid) v += ldw(resid, (long)gm * ldr + gn, rfl);
      long off = (long)gm * ldc + gn;
      if (outmode == 2){
        if (fl) Cb[off] = f2bf(v); else Cf[off] = v;
      } else if (outmode == 3){
        Cb[off] = f2bf(v);
      } else {
        Cf[off] = v;
      }
      if (cdst) cdst[(long)gm * ldc + gn] = ldw(csrc, (long)gm * 256 + gn, cfl);
    }
  }
}

// ---------------- QKV extract + rotary, 2-descriptor batched --------------
// grid.y = 16: bh = dsc*8 + b*4 + h. Output bf16 head-major (bh,L,64).
__global__ __launch_bounds__(256) void k_rope(
  const float* __restrict__ qkv0, const float* __restrict__ qkv1,
  const void* __restrict__ pe0, const void* __restrict__ pe1,
  u16* __restrict__ q, u16* __restrict__ k, u16* __restrict__ v,
  int L, int B, int H, const int* __restrict__ flagp)
{
  int fl = *flagp;
  int tid = threadIdx.x;
  int lq = tid >> 6, d = tid & 63;
  int l = blockIdx.x * 4 + lq;
  int bh = blockIdx.y;
  int dsc = bh >> 3;
  int bh7 = bh & 7;
  int b = bh7 >> 2, h = bh7 & 3;
  const float* qkv = dsc ? qkv1 : qkv0;
  const void* pe = dsc ? pe1 : pe0;
  const float* row = qkv + ((long)b * L + l) * 768 + h * 192;
  float qv = row[d*3+0], kv = row[d*3+1], vv = row[d*3+2];
  int dn = (d & 1) ? (d - 1) : (d + 1);
  float qn = row[dn*3+0], kn = row[dn*3+1];
  float rq = (d & 1) ? qn : -qn;
  float rk = (d & 1) ? kn : -kn;
  long peo = ((long)b * L + l) * 64 + d;
  float p0 = ldw(pe, peo, fl);
  float p1 = ldw(pe, (long)B * L * 64 + peo, fl);
  long o = ((long)bh * L + l) * 64 + d;
  q[o] = f2bf((qv * p0 + rq * p1) * 0.125f);   // exact pow2 pre-scale
  k[o] = f2bf(kv * p0 + rk * p1);
  v[o] = f2bf(vv);
}

// ---------------- MFMA flash attention, bf16 in / fp32 partials out ------
// K-split via blockIdx.z (NZ=4). Pseudo-batch via blockIdx.y (incl. descriptor).
__global__ __launch_bounds__(256, 8) void k_attn_mfma(
  const u16* __restrict__ Q, long qsb, long qsh, long qsl,
  const u16* __restrict__ Kp, long ksb, long ksh, long ksl,
  const u16* __restrict__ Vp, long vsb, long vsh, long vsl,
  float* __restrict__ Opart, float* __restrict__ mpart, float* __restrict__ lpart,
  int L, int H, int kchunk)
{
  __shared__ u16 Kt[64*72];
  __shared__ u16 Vt[64*72];
  __shared__ u16 Ps[64*72];     // wave-private rows: no barrier needed around it
  const int tid  = threadIdx.x;
  const int w    = tid >> 6;
  const int lane = tid & 63;
  const int quad = lane >> 4;
  const int m    = lane & 15;
  const int bh = blockIdx.y, b = bh / H, h = bh % H;
  const int iq0 = blockIdx.x * 64;
  const int z = blockIdx.z;
  const long BHL = (long)gridDim.y * L;

  const u16* Qb = Q  + b*qsb + h*qsh;
  const u16* Kb = Kp + b*ksb + h*ksh;
  const u16* Vb = Vp + b*vsb + h*vsh;

  s16x8 aq[2];
  {
    const u16* qr = Qb + (long)(iq0 + w*16 + m) * qsl + quad*8;
    aq[0] = *(const s16x8*)(qr);
    aq[1] = *(const s16x8*)(qr + 32);
  }

  f32x4 o_acc[4];
  #pragma unroll
  for (int nt = 0; nt < 4; ++nt) o_acc[nt] = (f32x4){0.f,0.f,0.f,0.f};
  float mrow[4] = {-1e30f,-1e30f,-1e30f,-1e30f};
  float lrow[4] = {0.f,0.f,0.f,0.f};

  const int srow = tid >> 2, sc0 = (tid & 3) << 4;
  const int kg = tid & 15;
  const int dg = tid >> 4;
  const int vcb = ((((dg >> 2) * 2) + (kg >> 1)) & 7) * 8 + (kg & 1) * 4;
  const int modd = m & 1;
  const int pcolb = m & 6;
  const int jend = z * kchunk + kchunk;

  for (int j0 = z * kchunk; j0 < jend; j0 += 64){
    {
      const u16* kr = Kb + (long)(j0 + srow) * ksl + sc0;
      *(uint4*)&Kt[srow*72 + sc0]     = *(const uint4*)kr;
      *(uint4*)&Kt[srow*72 + sc0 + 8] = *(const uint4*)(kr + 8);
      const u16* vr = Vb + (long)(j0 + 4*kg) * vsl + 4*dg;
      ushort4 r0 = *(const ushort4*)(vr);
      ushort4 r1 = *(const ushort4*)(vr + vsl);
      ushort4 r2 = *(const ushort4*)(vr + 2*vsl);
      ushort4 r3 = *(const ushort4*)(vr + 3*vsl);
      u16* vt = &Vt[(4*dg)*72 + vcb];
      *(ushort4*)(vt)       = make_ushort4(r0.x, r1.x, r2.x, r3.x);
      *(ushort4*)(vt + 72)  = make_ushort4(r0.y, r1.y, r2.y, r3.y);
      *(ushort4*)(vt + 144) = make_ushort4(r0.z, r1.z, r2.z, r3.z);
      *(ushort4*)(vt + 216) = make_ushort4(r0.w, r1.w, r2.w, r3.w);
    }
    __syncthreads();

    float sv[4][4];
    #pragma unroll
    for (int ct = 0; ct < 4; ++ct){
      f32x4 acc = (f32x4){0.f,0.f,0.f,0.f};
      #pragma unroll
      for (int s = 0; s < 2; ++s){
        s16x8 bk = *(const s16x8*)&Kt[(ct*16 + m)*72 + s*32 + quad*8];
        acc = __builtin_amdgcn_mfma_f32_16x16x32_bf16(aq[s], bk, acc, 0, 0, 0);
      }
      #pragma unroll
      for (int r = 0; r < 4; ++r) sv[ct][r] = acc[r];
    }

    // tile max per row; defer-max: only rescale when growth > THR=8
    float v0s[4];
    int need = 0;
    #pragma unroll
    for (int r = 0; r < 4; ++r){
      float v0 = fmaxf(fmaxf(sv[0][r], sv[1][r]), fmaxf(sv[2][r], sv[3][r]));
      v0 = dppmax16(v0);
      v0s[r] = v0;
      need |= (v0 > mrow[r] + 8.f) ? 1 : 0;
    }
    if (__any(need)){
      float alpha[4];
      #pragma unroll
      for (int r = 0; r < 4; ++r){
        float mn = fmaxf(mrow[r], v0s[r]);
        alpha[r] = __expf(mrow[r] - mn);
        mrow[r] = mn;
        lrow[r] *= alpha[r];
      }
      #pragma unroll
      for (int nt = 0; nt < 4; ++nt)
        #pragma unroll
        for (int r = 0; r < 4; ++r) o_acc[nt][r] *= alpha[r];
    }
    float rsum[4] = {0.f,0.f,0.f,0.f};
    #pragma unroll
    for (int ct = 0; ct < 4; ++ct)
      #pragma unroll
      for (int r = 0; r < 4; ++r){
        float p = __expf(sv[ct][r] - mrow[r]);
        sv[ct][r] = p;
        rsum[r] += p;
      }
    #pragma unroll
    for (int r = 0; r < 4; ++r)
      lrow[r] += dppsum16(rsum[r]);

    // Ps packed b32 writes (DPP xor1 pair exchange + cvt_pk)
    #pragma unroll
    for (int ct = 0; ct < 4; ++ct){
      const int kb = (2*w + 2*ct + (m >> 3)) & 7;
      const int col = (kb << 3) | pcolb;
      #pragma unroll
      for (int rr = 0; rr < 2; ++rr){
        float nb_lo = dppf<0xB1>(sv[ct][rr]);
        float nb_hi = dppf<0xB1>(sv[ct][2+rr]);
        float lo = modd ? nb_hi       : sv[ct][rr];
        float hi = modd ? sv[ct][2+rr] : nb_lo;
        unsigned int pk = cvtpk(lo, hi);
        int row = w*16 + quad*4 + rr + 2*modd;
        *(unsigned int*)&Ps[row*72 + col] = pk;
      }
    }
    asm volatile("s_waitcnt lgkmcnt(0)" ::: "memory");  // own-wave rows RAW

    s16x8 ap[2];
    #pragma unroll
    for (int s = 0; s < 2; ++s)
      ap[s] = *(const s16x8*)&Ps[(w*16 + m)*72 + (((2*w + 4*s + quad) & 7) << 3)];
    #pragma unroll
    for (int nt = 0; nt < 4; ++nt)
      #pragma unroll
      for (int s = 0; s < 2; ++s){
        s16x8 bv = *(const s16x8*)&Vt[(nt*16 + m)*72 + (((2*nt + 4*s + quad) & 7) << 3)];
        o_acc[nt] = __builtin_amdgcn_mfma_f32_16x16x32_bf16(ap[s], bv, o_acc[nt], 0, 0, 0);
      }
    __syncthreads();
  }

  const long zOoff = (long)z * BHL * 64;
  #pragma unroll
  for (int r = 0; r < 4; ++r){
    int iq = iq0 + w*16 + quad*4 + r;
    long rowid = ((long)b*L + iq) * H + h;
    #pragma unroll
    for (int nt = 0; nt < 4; ++nt)
      Opart[zOoff + rowid*64 + nt*16 + m] = o_acc[nt][r];
    if (m == 0){
      mpart[(long)z*BHL + rowid] = mrow[r];
      lpart[(long)z*BHL + rowid] = lrow[r];
    }
  }
}

// ---------------- attention split combine (4-way, fp32 partials) --------
__global__ __launch_bounds__(256) void k_attn_comb(
  const float* Opart, const float* mpart, const float* lpart,
  float* O, long BHL)
{
  long i = (long)blockIdx.x * 256 + threadIdx.x;
  long row = i >> 6;
  float mv[4];
  float M = -1e30f;
  #pragma unroll
  for (int z = 0; z < 4; ++z){
    mv[z] = mpart[(long)z*BHL + row];
    M = fmaxf(M, mv[z]);
  }
  long N64 = BHL * 64;
  float T = 0.f, acc = 0.f;
  #pragma unroll
  for (int z = 0; z < 4; ++z){
    float wz = __expf(mv[z] - M);
    T   += lpart[(long)z*BHL + row] * wz;
    acc += Opart[(long)z*N64 + i] * wz;
  }
  O[i] = acc / T;
}

// ---------------- depthwise conv K=5 SAME + silu (batched pseudo-b) ------
__global__ __launch_bounds__(256) void k_conv2(
  const float* __restrict__ xz,
  const void* __restrict__ wx, const void* __restrict__ wz,
  float* __restrict__ outx, float* __restrict__ outz,
  int L, const int* __restrict__ flagp)
{
  int fl = *flagp;
  int c = threadIdx.x;
  int bl = blockIdx.x; int b = bl / L, l = bl % L;
  int choff = blockIdx.y ? 256 : 0;
  const void* w = blockIdx.y ? wz : wx;
  float* out = blockIdx.y ? outz : outx;
  const float* base = xz + ((long)b * L) * 512 + choff + c;
  float s = 0.f;
  #pragma unroll
  for (int kk = 0; kk < 5; ++kk){
    int ll = l + kk - 2;
    if (ll >= 0 && ll < L) s += base[(long)ll * 512] * ldw(w, c*5 + kk, fl);
  }
  out[((long)b * L + l) * 256 + c] = s / (1.f + __expf(-s));   // silu
}

// ---------------- chunk-parallel selective scan ----------------
// delta/dxc now TRANSPOSED (d-major, ld = ldt = 4*L): vectorized float4 loads.
#define SC_CS 64
#define SC_NC 32

__global__ __launch_bounds__(256) void k_scan1(
  const float* __restrict__ deltaT, const float* __restrict__ dxcT,
  const float* __restrict__ xdbl, const void* __restrict__ Alog,
  float* __restrict__ E_out, float* __restrict__ F_out,
  int L, int ldt, const int* __restrict__ flagp)
{
  int fl = *flagp;
  int tid = threadIdx.x;
  int g = tid >> 4, n = tid & 15;
  int gid = blockIdx.x * 16 + g;
  int chunk = gid & (SC_NC - 1);
  int p = gid >> 5;
  int b = p >> 8, d = p & 255;
  float A = -__expf(ldw(Alog, d*16 + n, fl));
  const float* dTp = deltaT + (long)d*ldt + (long)b*L;
  const float* dxp = dxcT  + (long)d*ldt + (long)b*L;
  const float* xdb = xdbl + (long)b*L*64;
  int l0 = chunk * SC_CS;
  float E = 1.f, F = 0.f;
  for (int i = 0; i < SC_CS; i += 4){
    int l = l0 + i;
    float4 dt4 = *(const float4*)(dTp + l);
    float4 dx4 = *(const float4*)(dxp + l);
    float e[4], u[4];
    e[0] = __expf(dt4.x * A); e[1] = __expf(dt4.y * A);
    e[2] = __expf(dt4.z * A); e[3] = __expf(dt4.w * A);
    u[0] = dx4.x * xdb[(l+0)*64 + 16 + n];
    u[1] = dx4.y * xdb[(l+1)*64 + 16 + n];
    u[2] = dx4.z * xdb[(l+2)*64 + 16 + n];
    u[3] = dx4.w * xdb[(l+3)*64 + 16 + n];
    F = e[0]*F + u[0]; F = e[1]*F + u[1];
    F = e[2]*F + u[2]; F = e[3]*F + u[3];
    E *= (e[0]*e[1]) * (e[2]*e[3]);
  }
  long idx = (long)(p*16 + n) * SC_NC + chunk;
  E_out[idx] = E; F_out[idx] = F;
}

__global__ __launch_bounds__(256) void k_scan2(
  const float* __restrict__ E, const float* __restrict__ F,
  float* __restrict__ Hin)
{
  int pn = blockIdx.x * 256 + threadIdx.x;
  const float* Ep = E + (long)pn * SC_NC;
  const float* Fp = F + (long)pn * SC_NC;
  float* Hp = Hin + (long)pn * SC_NC;
  float h = 0.f;
  #pragma unroll
  for (int c = 0; c < SC_NC; ++c){
    Hp[c] = h;
    h = Ep[c] * h + Fp[c];
  }
}

// y = scan partial only (D*xc folded into o-proj GEMM A-staging)
__global__ __launch_bounds__(256) void k_scan3(
  const float* __restrict__ deltaT, const float* __restrict__ dxcT,
  const float* __restrict__ xdbl, const void* __restrict__ Alog,
  const float* __restrict__ Hin, float* __restrict__ y,
  int L, int ldt, const int* __restrict__ flagp)
{
  int fl = *flagp;
  int tid = threadIdx.x;
  int g = tid >> 4, n = tid & 15;
  int gid = blockIdx.x * 16 + g;
  int chunk = gid & (SC_NC - 1);
  int p = gid >> 5;
  int b = p >> 8, d = p & 255;
  float A = -__expf(ldw(Alog, d*16 + n, fl));
  const float* dTp = deltaT + (long)d*ldt + (long)b*L;
  const float* dxp = dxcT  + (long)d*ldt + (long)b*L;
  const float* xdb = xdbl + (long)b*L*64;
  float* yb = y + (long)b*L*256 + d;
  long idx = (long)(p*16 + n) * SC_NC + chunk;
  float h = Hin[idx];
  int l0 = chunk * SC_CS;
  for (int i = 0; i < SC_CS; i += 4){
    int l = l0 + i;
    float4 dt4 = *(const float4*)(dTp + l);
    float4 dx4 = *(const float4*)(dxp + l);
    float e[4], u[4], cm[4];
    e[0] = __expf(dt4.x * A); e[1] = __expf(dt4.y * A);
    e[2] = __expf(dt4.z * A); e[3] = __expf(dt4.w * A);
    u[0] = dx4.x * xdb[(l+0)*64 + 16 + n];
    u[1] = dx4.y * xdb[(l+1)*64 + 16 + n];
    u[2] = dx4.z * xdb[(l+2)*64 + 16 + n];
    u[3] = dx4.w * xdb[(l+3)*64 + 16 + n];
    cm[0] = xdb[(l+0)*64 + 32 + n];
    cm[1] = xdb[(l+1)*64 + 32 + n];
    cm[2] = xdb[(l+2)*64 + 32 + n];
    cm[3] = xdb[(l+3)*64 + 32 + n];
    float s0, s1, s2, s3;
    h = e[0]*h + u[0]; s0 = h * cm[0];
    h = e[1]*h + u[1]; s1 = h * cm[1];
    h = e[2]*h + u[2]; s2 = h * cm[2];
    h = e[3]*h + u[3]; s3 = h * cm[3];
    s0 += __shfl_xor(s0, 1, 16); s1 += __shfl_xor(s1, 1, 16);
    s2 += __shfl_xor(s2, 1, 16); s3 += __shfl_xor(s3, 1, 16);
    s0 += __shfl_xor(s0, 2, 16); s1 += __shfl_xor(s1, 2, 16);
    s2 += __shfl_xor(s2, 2, 16); s3 += __shfl_xor(s3, 2, 16);
    s0 += __shfl_xor(s0, 4, 16); s1 += __shfl_xor(s1, 4, 16);
    s2 += __shfl_xor(s2, 4, 16); s3 += __shfl_xor(s3, 4, 16);
    s0 += __shfl_xor(s0, 8, 16); s1 += __shfl_xor(s1, 8, 16);
    s2 += __shfl_xor(s2, 8, 16); s3 += __shfl_xor(s3, 8, 16);
    if (n < 4){
      float out = (n == 0) ? s0 : (n == 1) ? s1 : (n == 2) ? s2 : s3;
      yb[(long)(l + n)*256] = out;
    }
  }
}

// two-buffer LN with split-K partial sum (both descriptors batched)
__global__ __launch_bounds__(256) void k_ln2(
  float* __restrict__ hA, const float* __restrict__ hA2,
  float* __restrict__ hB, const float* __restrict__ hB2,
  const void* __restrict__ g, const void* __restrict__ beta,
  const int* __restrict__ flagp)
{
  int fl = *flagp;
  int r = blockIdx.x * 4 + (threadIdx.x >> 6);
  float* hbase = (r < 4096) ? hA : hB;
  const float* h2base = (r < 4096) ? hA2 : hB2;
  int row = r & 4095;
  int lane = threadIdx.x & 63;
  float* hr = hbase + (long)row * 512;
  const float* h2r = h2base + (long)row * 512;
  float v[8]; float s = 0.f, ss = 0.f;
  #pragma unroll
  for (int i = 0; i < 8; ++i){
    v[i] = hr[lane + 64*i] + h2r[lane + 64*i];
    s += v[i]; ss += v[i]*v[i];
  }
  #pragma unroll
  for (int off = 1; off < 64; off <<= 1){ s += __shfl_xor(s, off); ss += __shfl_xor(ss, off); }
  float mean = s * (1.f/512.f);
  float var  = ss * (1.f/512.f) - mean * mean;
  float rs = rsqrtf(var + 1e-5f);
  #pragma unroll
  for (int i = 0; i < 8; ++i){
    int c = lane + 64*i;
    hr[c] = (v[i] - mean) * rs * ldw(g, c, fl) + ldw(beta, c, fl);
  }
}

extern "C" void kernel_launch(void* const* d_in, const int* in_sizes, int n_in,
                              void* d_out, int out_size, void* d_ws, size_t ws_size,
                              hipStream_t stream)
{
  const int B_ = 2, L_ = 2048, H_ = 4;
  const long BLE = (long)B_ * L_ * 256;       // 1,048,576 floats
  const long BHLb = 2L * B_ * H_ * L_;        // 32,768 (batched pseudo-heads)
  const long BHLc = (long)B_ * H_ * L_;       // 16,384 (cross)

  int* flagp = (int*)d_ws;
  float* base = (float*)d_ws + 64;

  // ---- generous descriptor-major workspace map (ws = 256 MiB = 64 BLE) ----
  float* cat0   = base + 0*BLE;    // 3 BLE, ld 768
  float* cat1   = base + 3*BLE;    // 3 BLE
  float* xz01   = base + 6*BLE;    // 4 BLE, pseudo-b ld 512
  u16*   q01    = (u16*)(base + 10*BLE);   // 1 BLE each (16 heads x L x 64 bf16)
  u16*   k01    = (u16*)(base + 11*BLE);
  u16*   v01    = (u16*)(base + 12*BLE);
  float* Opart  = base + 13*BLE;   // 8 BLE (4 z-planes x 2 BLE batched)
  float* ob01   = base + 21*BLE;   // 2 BLE
  float* mml    = base + 23*BLE;   // 4*32768
  float* mll    = mml + 4*32768;   // fits within 1 BLE slot
  float* xc01   = base + 24*BLE;   // 2 BLE
  float* zc01   = base + 26*BLE;   // 2 BLE
  float* xdbl01 = base + 28*BLE;   // 0.5 BLE
  float* delta01= base + 29*BLE;   // 2 BLE (TRANSPOSED 256 x 8192)
  float* dxc01  = base + 31*BLE;   // 2 BLE (TRANSPOSED 256 x 8192)
  float* scE    = base + 33*BLE;   // 0.5 BLE
  float* scF    = scE + 524288;
  float* scH    = scF + 524288;    // ends +34.5
  float* y01    = base + 35*BLE;   // 2 BLE
  float* catc0  = base + 37*BLE;   // 4 BLE, ld 1024
  float* catc1  = base + 41*BLE;   // 4 BLE
  float* h0     = base + 45*BLE;   // 2 BLE, ld 512
  float* part0  = base + 47*BLE;   // 2 BLE
  float* h1     = base + 49*BLE;   // 2 BLE
  float* part1  = base + 51*BLE;   // 2 BLE
  float* dbuf0  = base + 53*BLE;
  float* dbuf1  = base + 54*BLE;
  u16*   qc     = (u16*)(base + 55*BLE);   // cross q/k/v/o bf16, 0.5 BLE each
  u16*   kc     = qc + 1048576;
  u16*   vc     = kc + 1048576;
  u16*   oc     = vc + 1048576;            // ends +57
  float* catA   = base + 57*BLE;   // 2 BLE, ld 512
  float* catB   = base + 59*BLE;   // 2 BLE
  float* px     = base + 61*BLE;   // 16,384
  float* pd     = px + 16384;      // 16,384
  float* pb     = pd + 16384;      // 256

  const void* in[35];
  for (int i = 0; i < 35 && i < n_in; ++i) in[i] = d_in[i];

  k_sniff<<<1, 256, 0, stream>>>((const unsigned int*)in[0], 2048, flagp);
  k_pad<<<130, 256, 0, stream>>>(in[17], in[18], in[19], px, pd, pb, flagp);

  const int BIG = 1 << 30;
  const long sbP = (long)H_ * L_ * 64, shP = (long)L_ * 64, slP = 64;   // per pseudo-b
  const long sbF = (long)L_ * 256,     shF = 64,            slF = 256;  // (B,L,256)
  const int kchunk = L_ / 4;
  const int MROWS = 4 * L_;   // 8192 (transposed ld)

  // ---------------- batched mamba_attention (both descriptors) ----------------
  k_gemm_mfma<<<dim3(20, 64), 256, 0, stream>>>(
      in[0], 0, 256, 256, 1280, in[4], in[14], 768, 0, in[5],
      cat0, nullptr, 768, xz01, 512,
      nullptr, 1, 0, nullptr, 1, nullptr, 1.f, 0, 0, flagp);
  k_gemm_mfma<<<dim3(20, 64), 256, 0, stream>>>(
      in[1], 0, 256, 256, 1280, in[4], in[14], 768, 0, in[5],
      cat1, nullptr, 768, xz01 + 2*BLE, 512,
      nullptr, 1, 0, nullptr, 1, nullptr, 1.f, 0, 0, flagp);
  k_rope<<<dim3(L_/4, 16), 256, 0, stream>>>(cat0, cat1, in[2], in[3],
      q01, k01, v01, L_, B_, H_, flagp);
  k_attn_mfma<<<dim3(L_/64, 16, 4), 256, 0, stream>>>(
      q01, sbP, shP, slP, k01, sbP, shP, slP, v01, sbP, shP, slP,
      Opart, mml, mll, L_, H_, kchunk);
  k_attn_comb<<<8192, 256, 0, stream>>>(Opart, mml, mll, ob01, BHLb);
  k_conv2<<<dim3(2*B_*L_, 2), 256, 0, stream>>>(xz01, in[15], in[16], xc01, zc01, L_, flagp);
  // xproj (padded N=64, fp32 weights) into xdbl ld 64; M=8192 both descs
  k_gemm_mfma<<<dim3(1, 128), 256, 0, stream>>>(
      xc01, 1, 256, 256, 64, px, nullptr, BIG, 1, nullptr,
      xdbl01, nullptr, 64, nullptr, 0,
      nullptr, 1, 0, nullptr, 1, nullptr, 1.f, 0, 0, flagp);
  // dt (padded K=64) + fused softplus -> deltaT, dxcT (transposed ld=8192)
  k_gemm_mfma<<<dim3(4, 128), 256, 0, stream>>>(
      xdbl01, 1, 64, 64, 256, pd, nullptr, BIG, 1, pb,
      delta01, nullptr, MROWS, dxc01, MROWS,
      xc01, 1, 256, nullptr, 1, nullptr, 1.f, 0, 4, flagp);
  k_scan1<<<2048, 256, 0, stream>>>(delta01, dxc01, xdbl01, in[20], scE, scF, L_, MROWS, flagp);
  k_scan2<<<64, 256, 0, stream>>>(scE, scF, scH);
  k_scan3<<<2048, 256, 0, stream>>>(delta01, dxc01, xdbl01, in[20], scH, y01, L_, MROWS, flagp);
  // batched s_x / c_x / o-proj (+fused raw-input->cat copy), z=6
  // s_x slots (z0,z3) fuse A' = y + D*xc at staging.
  {
    GB8 gb = {};
    gb.dvec = in[21];
    gb.A[0] = y01;        gb.aux[0] = xc01;       gb.W[0] = in[22]; gb.Cf[0] = catc0 + 512; gb.osc[0] = 1.f; gb.cfl[0] = 1;
    gb.A[1] = zc01;       gb.W[1] = in[22]; gb.Cf[1] = catc0 + 768; gb.osc[1] = 1.f; gb.cfl[1] = 1;
    gb.A[2] = ob01;       gb.W[2] = in[6];  gb.bias[2] = in[7];     gb.Cf[2] = catc0 + 256;
    gb.csrc[2] = in[0];   gb.cdst[2] = catc0; gb.osc[2] = 1.f;      gb.cfl[2] = 0;
    gb.A[3] = y01 + BLE;  gb.aux[3] = xc01 + BLE; gb.W[3] = in[22]; gb.Cf[3] = catc1 + 512; gb.osc[3] = 1.f; gb.cfl[3] = 1;
    gb.A[4] = zc01 + BLE; gb.W[4] = in[22]; gb.Cf[4] = catc1 + 768; gb.osc[4] = 1.f; gb.cfl[4] = 1;
    gb.A[5] = ob01 + BLE; gb.W[5] = in[6];  gb.bias[5] = in[7];     gb.Cf[5] = catc1 + 256;
    gb.csrc[5] = in[1];   gb.cdst[5] = catc1; gb.osc[5] = 1.f;      gb.cfl[5] = 0;
    k_gemmb<<<dim3(4, 64, 6), 256, 0, stream>>>(gb, 256, 256, 256, 1024, 0, 256, 0, 0, flagp);
  }
  // ffn1 split-K=2 per descriptor (z=4)
  {
    GB8 gb = {};
    gb.cfl[0] = gb.cfl[1] = gb.cfl[2] = gb.cfl[3] = 1;
    gb.A[0] = catc0;       gb.W[0] = in[8]; gb.bias[0] = in[9]; gb.Cf[0] = h0;    gb.osc[0] = 1.f;
    gb.A[1] = catc0 + 512; gb.W[1] = in[8]; gb.wkoff[1] = 512;  gb.Cf[1] = part0; gb.osc[1] = 1.f;
    gb.A[2] = catc1;       gb.W[2] = in[8]; gb.bias[2] = in[9]; gb.Cf[2] = h1;    gb.osc[2] = 1.f;
    gb.A[3] = catc1 + 512; gb.W[3] = in[8]; gb.wkoff[3] = 512;  gb.Cf[3] = part1; gb.osc[3] = 1.f;
    k_gemmb<<<dim3(8, 64, 4), 256, 0, stream>>>(gb, 1024, 512, 512, 512, 0, 1024, 0, 0, flagp);
  }
  k_ln2<<<2048, 256, 0, stream>>>(h0, part0, h1, part1, in[10], in[11], flagp);
  // ffn2: gelu(h) @ W^T + bias + raw-input residual (dtype-aware), z=2
  {
    GB8 gb = {};
    gb.cfl[0] = gb.cfl[1] = 1;
    gb.A[0] = h0; gb.W[0] = in[12]; gb.bias[0] = in[13]; gb.resid[0] = in[0]; gb.rfli[0] = 0;
    gb.Cf[0] = dbuf0; gb.osc[0] = 1.f;
    gb.A[1] = h1; gb.W[1] = in[12]; gb.bias[1] = in[13]; gb.resid[1] = in[1]; gb.rfli[1] = 0;
    gb.Cf[1] = dbuf1; gb.osc[1] = 1.f;
    k_gemmb<<<dim3(4, 64, 2), 256, 0, stream>>>(gb, 512, 512, 256, 256, 256, 512, 1, 0, flagp);
  }

  // ---------------- cross attention ----------------
  const float s4 = 0.35355339059327373f;  // 64^-0.25
  float* cm0 = xc01;           // cross comb outputs reuse xc slots
  float* cm1 = xc01 + BLE;
  {
    GB8 gb = {};
    gb.cfl[0] = gb.cfl[1] = gb.cfl[2] = gb.cfl[3] = 1;
    gb.A[0] = dbuf0; gb.W[0] = in[23]; gb.bias[0] = in[24]; gb.Cb[0] = qc; gb.osc[0] = s4;
    gb.A[1] = dbuf1; gb.W[1] = in[23]; gb.bias[1] = in[24]; gb.Cb[1] = kc; gb.osc[1] = s4;
    gb.A[2] = dbuf0; gb.W[2] = in[25]; gb.bias[2] = in[26]; gb.Cb[2] = vc; gb.osc[2] = 1.f;
    gb.A[3] = dbuf1; gb.W[3] = in[25]; gb.bias[3] = in[26]; gb.Cb[3] = oc; gb.osc[3] = 1.f;
    k_gemmb<<<dim3(4, 64, 4), 256, 0, stream>>>(gb, 256, 256, 256, 256, 0, 256, 0, 3, flagp);
  }
  k_attn_mfma<<<dim3(L_/64, B_*H_, 4), 256, 0, stream>>>(
      qc, sbF, shF, slF, kc, sbF, shF, slF, oc, sbF, shF, slF,
      Opart, mml, mll, L_, H_, kchunk);
  k_attn_comb<<<4096, 256, 0, stream>>>(Opart, mml, mll, cm0, BHLc);
  k_attn_mfma<<<dim3(L_/64, B_*H_, 4), 256, 0, stream>>>(
      kc, sbF, shF, slF, qc, sbF, shF, slF, vc, sbF, shF, slF,
      Opart, mml, mll, L_, H_, kchunk);
  k_attn_comb<<<4096, 256, 0, stream>>>(Opart, mml, mll, cm1, BHLc);
  {
    GB8 gb = {};
    gb.cfl[0] = gb.cfl[1] = 1;
    gb.A[0] = cm0; gb.W[0] = in[27]; gb.bias[0] = in[28]; gb.Cf[0] = catA + 256;
    gb.csrc[0] = dbuf0; gb.cdst[0] = catA; gb.osc[0] = 1.f;
    gb.A[1] = cm1; gb.W[1] = in[27]; gb.bias[1] = in[28]; gb.Cf[1] = catB + 256;
    gb.csrc[1] = dbuf1; gb.cdst[1] = catB; gb.osc[1] = 1.f;
    k_gemmb<<<dim3(4, 64, 2), 256, 0, stream>>>(gb, 256, 256, 256, 512, 0, 256, 0, 0, flagp);
  }
  // ca-ffn1 split-K=2 per descriptor (z=4)
  {
    GB8 gb = {};
    gb.cfl[0] = gb.cfl[1] = gb.cfl[2] = gb.cfl[3] = 1;
    gb.A[0] = catA;       gb.W[0] = in[29]; gb.bias[0] = in[30]; gb.Cf[0] = h0;    gb.osc[0] = 1.f;
    gb.A[1] = catA + 256; gb.W[1] = in[29]; gb.wkoff[1] = 256;   gb.Cf[1] = part0; gb.osc[1] = 1.f;
    gb.A[2] = catB;       gb.W[2] = in[29]; gb.bias[2] = in[30]; gb.Cf[2] = h1;    gb.osc[2] = 1.f;
    gb.A[3] = catB + 256; gb.W[3] = in[29]; gb.wkoff[3] = 256;   gb.Cf[3] = part1; gb.osc[3] = 1.f;
    k_gemmb<<<dim3(8, 64, 4), 256, 0, stream>>>(gb, 512, 256, 512, 512, 0, 512, 0, 0, flagp);
  }
  k_ln2<<<2048, 256, 0, stream>>>(h0, part0, h1, part1, in[31], in[32], flagp);
  {
    GB8 gb = {};
    gb.cfl[0] = gb.cfl[1] = 1;
    gb.rfli[0] = gb.rfli[1] = 1;
    gb.A[0] = h0; gb.W[0] = in[33]; gb.bias[0] = in[34]; gb.resid[0] = dbuf0;
    gb.Cf[0] = (float*)d_out; gb.Cb[0] = (u16*)d_out; gb.osc[0] = 1.f;
    gb.A[1] = h1; gb.W[1] = in[33]; gb.bias[1] = in[34]; gb.resid[1] = dbuf1;
    gb.Cf[1] = (float*)d_out + BLE; gb.Cb[1] = (u16*)d_out + BLE; gb.osc[1] = 1.f;
    k_gemmb<<<dim3(4, 64, 2), 256, 0, stream>>>(gb, 512, 512, 256, 256, 256, 512, 1, 2, flagp);
  }
}

// Round 8
// 657.388 us; speedup vs baseline: 1.2476x; 1.0007x over previous
//
#include <hip/hip_runtime.h>

typedef unsigned short u16;
typedef short s16;
typedef s16 s16x8 __attribute__((ext_vector_type(8)));
typedef float f32x4 __attribute__((ext_vector_type(4)));

__device__ __forceinline__ float bf2f(u16 u){
  union { unsigned int i; float f; } v; v.i = ((unsigned int)u) << 16; return v.f;
}
__device__ __forceinline__ u16 f2bf(float f){
  union { float f; unsigned int u; } v; v.f = f;
  unsigned int r = (v.u + 0x7fffu + ((v.u >> 16) & 1u)) >> 16;
  return (u16)r;
}
// packed f32x2 -> bf16x2 (RNE, identical to f2bf) in ONE VALU op
__device__ __forceinline__ unsigned int cvtpk(float lo, float hi){
  unsigned int d;
  asm("v_cvt_pk_bf16_f32 %0, %1, %2" : "=v"(d) : "v"(lo), "v"(hi));
  return d;
}
__device__ __forceinline__ uint4 pack8(float4 a0, float4 a1){
  uint4 v;
  v.x = cvtpk(a0.x, a0.y); v.y = cvtpk(a0.z, a0.w);
  v.z = cvtpk(a1.x, a1.y); v.w = cvtpk(a1.z, a1.w);
  return v;
}
__device__ __forceinline__ float gelu_f(float x){
  return 0.5f * x * (1.f + erff(x * 0.70710678118654752440f));
}
__device__ __forceinline__ float ldw(const void* p, long i, int fl){
  return fl ? bf2f(((const u16*)p)[i]) : ((const float*)p)[i];
}
__device__ __forceinline__ float4 ldw4(const void* p, long i, int fl){
  if (fl){
    ushort4 w = *(const ushort4*)((const u16*)p + i);
    return make_float4(bf2f(w.x), bf2f(w.y), bf2f(w.z), bf2f(w.w));
  }
  return *(const float4*)((const float*)p + i);
}

// ---- DPP 16-lane butterfly reductions (VALU pipe, zero LDS traffic) ----
template<int C>
__device__ __forceinline__ float dppf(float x){
  return __int_as_float(__builtin_amdgcn_update_dpp(0, __float_as_int(x), C, 0xf, 0xf, true));
}
__device__ __forceinline__ float dppmax16(float v){
  v = fmaxf(v, dppf<0xB1>(v));
  v = fmaxf(v, dppf<0x4E>(v));
  v = fmaxf(v, dppf<0x141>(v));
  v = fmaxf(v, dppf<0x140>(v));
  return v;
}
__device__ __forceinline__ float dppsum16(float v){
  v += dppf<0xB1>(v);
  v += dppf<0x4E>(v);
  v += dppf<0x141>(v);
  v += dppf<0x140>(v);
  return v;
}

// ---------------- dtype sniffer (flag[0]=dtype, flag[1]=0 const) --------
__global__ __launch_bounds__(256) void k_sniff(const unsigned int* __restrict__ w,
                                               int n, int* __restrict__ flag){
  __shared__ int cnt[256];
  int c = 0;
  for (int i = threadIdx.x; i < n; i += 256){
    unsigned e = (w[i] >> 7) & 0xFFu;
    c += (e >= 120u && e <= 127u) ? 1 : 0;
  }
  cnt[threadIdx.x] = c; __syncthreads();
  for (int s = 128; s > 0; s >>= 1){
    if (threadIdx.x < s) cnt[threadIdx.x] += cnt[threadIdx.x + s];
    __syncthreads();
  }
  if (threadIdx.x == 0) flag[0] = (2 * cnt[0] > n) ? 1 : 0;
  if (threadIdx.x == 1) flag[1] = 0;
}

// ---- zero-pad xproj (48x256 -> 64x256) / dt_w (256x16 -> 256x64) / dt_b ----
__global__ __launch_bounds__(256) void k_pad(
  const void* __restrict__ wx, const void* __restrict__ wd,
  const void* __restrict__ bd,
  float* __restrict__ px, float* __restrict__ pd, float* __restrict__ pb,
  const int* __restrict__ flagp)
{
  int fl = *flagp;
  int i = blockIdx.x * 256 + threadIdx.x;
  if (i < 16384){
    int r = i >> 8, c = i & 255;
    px[i] = (r < 48) ? ldw(wx, r*256 + c, fl) : 0.f;
  } else if (i < 32768){
    int j = i - 16384;
    int n = j >> 6, k = j & 63;
    pd[j] = (k < 16) ? ldw(wd, n*16 + k, fl) : 0.f;
  } else if (i < 33024){
    pb[i - 32768] = ldw(bd, i - 32768, fl);
  }
}

// ---------------- MFMA GEMM (staged 64x64 tile) ----------------
// outmode: 0 fp32, 2 dynamic, 3 bf16,
//          4 softplus(dt+2*bias) -> Cf TRANSPOSED (d-major), delta*resid -> C2 TRANSPOSED.
// A1/coff1/c2off1: optional z-batch (blockIdx.z==1 uses A1, Cf+coff1, C2+c2off1).
__global__ __launch_bounds__(256) void k_gemm_mfma(
  const void* __restrict__ A0, int aflidx, int lda, int K, int N,
  const void* __restrict__ W, const void* __restrict__ W2, int nsplit, int wflidx,
  const void* __restrict__ bias,
  float* __restrict__ Cf0, u16* __restrict__ Cb, int ldc,
  float* __restrict__ C20, int ldc2,
  const void* __restrict__ resid, int rflidx, int ldr,
  const void* __restrict__ csrc, int cflidx, float* __restrict__ cdst,
  float oscale, int act_gelu, int outmode,
  const void* __restrict__ A1, long coff1, long c2off1,
  const int* __restrict__ flagp)
{
  const int fl  = flagp[0];
  const int afl = flagp[aflidx];
  const int wfl = flagp[wflidx];
  const int rfl = flagp[rflidx];
  const int cfl = flagp[cflidx];
  const void* A = A0;
  float* Cf = Cf0;
  float* C2 = C20;
  if (blockIdx.z){ A = A1; Cf += coff1; C2 += c2off1; }
  __shared__ u16 As[64*72];
  __shared__ u16 Bs[64*72];
  const int tid = threadIdx.x;
  const int w = tid >> 6, lane = tid & 63, quad = lane >> 4, m = lane & 15;
  const int m0 = blockIdx.y << 6, n0 = blockIdx.x << 6;
  const int srow = tid >> 2, sc0 = (tid & 3) << 4;
  const int reg2 = (n0 >= nsplit);
  const void* Wp = reg2 ? W2 : W;
  const int nbase = reg2 ? nsplit : 0;

  f32x4 acc[4];
  #pragma unroll
  for (int ct = 0; ct < 4; ++ct) acc[ct] = (f32x4){0.f,0.f,0.f,0.f};

  for (int k0 = 0; k0 < K; k0 += 64){
    {
      long ab = (long)(m0 + srow) * lda + k0 + sc0;
      if (afl && !act_gelu){
        #pragma unroll
        for (int g = 0; g < 2; ++g)
          *(uint4*)&As[srow*72 + sc0 + g*8] = *(const uint4*)((const u16*)A + ab + g*8);
      } else {
        #pragma unroll
        for (int g = 0; g < 2; ++g){
          float4 a0 = ldw4(A, ab + g*8, afl);
          float4 a1 = ldw4(A, ab + g*8 + 4, afl);
          if (act_gelu){
            a0.x=gelu_f(a0.x); a0.y=gelu_f(a0.y); a0.z=gelu_f(a0.z); a0.w=gelu_f(a0.w);
            a1.x=gelu_f(a1.x); a1.y=gelu_f(a1.y); a1.z=gelu_f(a1.z); a1.w=gelu_f(a1.w);
          }
          *(uint4*)&As[srow*72 + sc0 + g*8] = pack8(a0, a1);
        }
      }
    }
    {
      long wb = (long)(n0 + srow - nbase) * K + k0 + sc0;
      if (wfl){
        #pragma unroll
        for (int g = 0; g < 2; ++g)
          *(uint4*)&Bs[srow*72 + sc0 + g*8] = *(const uint4*)((const u16*)Wp + wb + g*8);
      } else {
        #pragma unroll
        for (int g = 0; g < 2; ++g){
          float4 b0 = *(const float4*)((const float*)Wp + wb + g*8);
          float4 b1 = *(const float4*)((const float*)Wp + wb + g*8 + 4);
          *(uint4*)&Bs[srow*72 + sc0 + g*8] = pack8(b0, b1);
        }
      }
    }
    __syncthreads();

    s16x8 av[2];
    #pragma unroll
    for (int s = 0; s < 2; ++s)
      av[s] = *(const s16x8*)&As[(w*16 + m)*72 + s*32 + quad*8];
    #pragma unroll
    for (int ct = 0; ct < 4; ++ct)
      #pragma unroll
      for (int s = 0; s < 2; ++s){
        s16x8 bv = *(const s16x8*)&Bs[(ct*16 + m)*72 + s*32 + quad*8];
        acc[ct] = __builtin_amdgcn_mfma_f32_16x16x32_bf16(av[s], bv, acc[ct], 0, 0, 0);
      }
    __syncthreads();
  }

  if (outmode == 4){
    // transposed float4 stores: acc[ct] = 4 consecutive rows for column gn
    const int gmb = m0 + w*16 + quad*4;
    #pragma unroll
    for (int ct = 0; ct < 4; ++ct){
      int gn = n0 + ct*16 + m;
      float bv = ldw(bias, gn, wfl);
      float dl4[4], dx4[4];
      #pragma unroll
      for (int r = 0; r < 4; ++r){
        float dl = acc[ct][r] + bv + bv;     // dt + 2*dt_bias (ref's double add)
        float delta = (dl > 20.f) ? dl : __logf(1.f + __expf(dl));
        dl4[r] = delta;
        dx4[r] = delta * ldw(resid, (long)(gmb + r) * ldr + gn, rfl);
      }
      *(float4*)&Cf[(long)gn * ldc + gmb] = make_float4(dl4[0], dl4[1], dl4[2], dl4[3]);
      *(float4*)&C2[(long)gn * ldc2 + gmb] = make_float4(dx4[0], dx4[1], dx4[2], dx4[3]);
    }
    return;
  }

  #pragma unroll
  for (int r = 0; r < 4; ++r){
    int gm = m0 + w*16 + quad*4 + r;
    #pragma unroll
    for (int ct = 0; ct < 4; ++ct){
      int gn = n0 + ct*16 + m;
      float v = acc[ct][r];
      if (reg2){
        C2[(long)gm * ldc2 + (gn - nsplit)] = v;
      } else {
        if (bias) v += ldw(bias, gn, wfl);
        v *= oscale;
        if (resid) v += ldw(resid, (long)gm * ldr + gn, rfl);
        long off = (long)gm * ldc + gn;
        if (outmode == 2){
          if (fl) Cb[off] = f2bf(v); else Cf[off] = v;
        } else if (outmode == 3){
          Cb[off] = f2bf(v);
        } else {
          Cf[off] = v;
        }
        if (cdst) cdst[(long)gm * ldc + gn] = ldw(csrc, (long)gm * 256 + gn, cfl);
      }
    }
  }
}

// ---------------- z-batched MFMA GEMM (up to 8 independent problems) ----------------
struct GB8 {
  const float* A[8]; const void* W[8]; const void* bias[8];
  float* Cf[8]; u16* Cb[8]; const void* resid[8];
  const void* csrc[8]; float* cdst[8]; float osc[8];
  int cfl[8]; int wkoff[8]; int rfli[8];
  const float* aux[8]; const void* dvec;
};

__global__ __launch_bounds__(256) void k_gemmb(
  GB8 gb, int lda, int K, int N, int ldc, int ldr, int ldwq,
  int act_gelu, int outmode, const int* __restrict__ flagp)
{
  const int fl = flagp[0];
  const int z = blockIdx.z;
  const float* A = gb.A[z]; const void* W = gb.W[z]; const void* bias = gb.bias[z];
  float* Cf = gb.Cf[z]; u16* Cb = gb.Cb[z]; const void* resid = gb.resid[z];
  const void* csrc = gb.csrc[z]; float* cdst = gb.cdst[z];
  const float osc = gb.osc[z];
  const int cfl = flagp[gb.cfl[z]];
  const int rfl = flagp[gb.rfli[z]];
  const int wkoff = gb.wkoff[z];
  const float* aux = gb.aux[z];

  __shared__ u16 As[64*72];
  __shared__ u16 Bs[64*72];
  const int tid = threadIdx.x;
  const int w = tid >> 6, lane = tid & 63, quad = lane >> 4, m = lane & 15;
  const int m0 = blockIdx.y << 6, n0 = blockIdx.x << 6;
  const int srow = tid >> 2, sc0 = (tid & 3) << 4;

  f32x4 acc[4];
  #pragma unroll
  for (int ct = 0; ct < 4; ++ct) acc[ct] = (f32x4){0.f,0.f,0.f,0.f};

  for (int k0 = 0; k0 < K; k0 += 64){
    {
      const float* ar = A + (long)(m0 + srow) * lda + k0 + sc0;
      #pragma unroll
      for (int g = 0; g < 2; ++g){
        float4 a0 = *(const float4*)(ar + g*8);
        float4 a1 = *(const float4*)(ar + g*8 + 4);
        if (aux){
          const float* xr = aux + (long)(m0 + srow) * lda + k0 + sc0;
          float4 x0 = *(const float4*)(xr + g*8);
          float4 x1 = *(const float4*)(xr + g*8 + 4);
          float4 d0 = ldw4(gb.dvec, k0 + sc0 + g*8, fl);
          float4 d1 = ldw4(gb.dvec, k0 + sc0 + g*8 + 4, fl);
          a0.x += d0.x*x0.x; a0.y += d0.y*x0.y; a0.z += d0.z*x0.z; a0.w += d0.w*x0.w;
          a1.x += d1.x*x1.x; a1.y += d1.y*x1.y; a1.z += d1.z*x1.z; a1.w += d1.w*x1.w;
        }
        if (act_gelu){
          a0.x=gelu_f(a0.x); a0.y=gelu_f(a0.y); a0.z=gelu_f(a0.z); a0.w=gelu_f(a0.w);
          a1.x=gelu_f(a1.x); a1.y=gelu_f(a1.y); a1.z=gelu_f(a1.z); a1.w=gelu_f(a1.w);
        }
        *(uint4*)&As[srow*72 + sc0 + g*8] = pack8(a0, a1);
      }
    }
    {
      long wb = (long)(n0 + srow) * ldwq + wkoff + k0 + sc0;
      if (fl){
        #pragma unroll
        for (int g = 0; g < 2; ++g)
          *(uint4*)&Bs[srow*72 + sc0 + g*8] = *(const uint4*)((const u16*)W + wb + g*8);
      } else {
        #pragma unroll
        for (int g = 0; g < 2; ++g){
          float4 b0 = *(const float4*)((const float*)W + wb + g*8);
          float4 b1 = *(const float4*)((const float*)W + wb + g*8 + 4);
          *(uint4*)&Bs[srow*72 + sc0 + g*8] = pack8(b0, b1);
        }
      }
    }
    __syncthreads();

    s16x8 av[2];
    #pragma unroll
    for (int s = 0; s < 2; ++s)
      av[s] = *(const s16x8*)&As[(w*16 + m)*72 + s*32 + quad*8];
    #pragma unroll
    for (int ct = 0; ct < 4; ++ct)
      #pragma unroll
      for (int s = 0; s < 2; ++s){
        s16x8 bv = *(const s16x8*)&Bs[(ct*16 + m)*72 + s*32 + quad*8];
        acc[ct] = __builtin_amdgcn_mfma_f32_16x16x32_bf16(av[s], bv, acc[ct], 0, 0, 0);
      }
    __syncthreads();
  }

  #pragma unroll
  for (int r = 0; r < 4; ++r){
    int gm = m0 + w*16 + quad*4 + r;
    #pragma unroll
    for (int ct = 0; ct < 4; ++ct){
      int gn = n0 + ct*16 + m;
      float v = acc[ct][r];
      if (bias) v += ldw(bias, gn, fl);
      v *= osc;
      if (resid) v += ldw(resid, (long)gm * ldr + gn, rfl);
      long off = (long)gm * ldc + gn;
      if (outmode == 2){
        if (fl) Cb[off] = f2bf(v); else Cf[off] = v;
      } else if (outmode == 3){
        Cb[off] = f2bf(v);
      } else {
        Cf[off] = v;
      }
      if (cdst) cdst[(long)gm * ldc + gn] = ldw(csrc, (long)gm * 256 + gn, cfl);
    }
  }
}

// ---------------- QKV extract + rotary, 2-descriptor batched --------------
// grid.y = 16: bh = dsc*8 + b*4 + h. Output bf16 head-major (bh,L,64).
// q pre-scaled by 0.125*log2(e): scores land in log2 domain (exp2 softmax).
__global__ __launch_bounds__(256) void k_rope(
  const float* __restrict__ qkv0, const float* __restrict__ qkv1,
  const void* __restrict__ pe0, const void* __restrict__ pe1,
  u16* __restrict__ q, u16* __restrict__ k, u16* __restrict__ v,
  int L, int B, int H, const int* __restrict__ flagp)
{
  int fl = *flagp;
  int tid = threadIdx.x;
  int lq = tid >> 6, d = tid & 63;
  int l = blockIdx.x * 4 + lq;
  int bh = blockIdx.y;
  int dsc = bh >> 3;
  int bh7 = bh & 7;
  int b = bh7 >> 2, h = bh7 & 3;
  const float* qkv = dsc ? qkv1 : qkv0;
  const void* pe = dsc ? pe1 : pe0;
  const float* row = qkv + ((long)b * L + l) * 768 + h * 192;
  float qv = row[d*3+0], kv = row[d*3+1], vv = row[d*3+2];
  int dn = (d & 1) ? (d - 1) : (d + 1);
  float qn = row[dn*3+0], kn = row[dn*3+1];
  float rq = (d & 1) ? qn : -qn;
  float rk = (d & 1) ? kn : -kn;
  long peo = ((long)b * L + l) * 64 + d;
  float p0 = ldw(pe, peo, fl);
  float p1 = ldw(pe, (long)B * L * 64 + peo, fl);
  long o = ((long)bh * L + l) * 64 + d;
  q[o] = f2bf((qv * p0 + rq * p1) * 0.18033688011112042f);  // 0.125 * log2(e)
  k[o] = f2bf(kv * p0 + rk * p1);
  v[o] = f2bf(vv);
}

// ---------------- MFMA flash attention, bf16 in / fp32 partials out ------
// Scores in log2 domain (exp2 softmax). K-split via blockIdx.z (NZ=2).
// bxor: K/V batch index = b^bxor (enables batching both cross directions).
__global__ __launch_bounds__(256, 8) void k_attn_mfma(
  const u16* __restrict__ Q, long qsb, long qsh, long qsl,
  const u16* __restrict__ Kp, long ksb, long ksh, long ksl,
  const u16* __restrict__ Vp, long vsb, long vsh, long vsl,
  float* __restrict__ Opart, float* __restrict__ mpart, float* __restrict__ lpart,
  int L, int H, int kchunk, int bxor)
{
  __shared__ u16 Kt[64*72];
  __shared__ u16 Vt[64*72];
  __shared__ u16 Ps[64*72];     // wave-private rows: no barrier needed around it
  const int tid  = threadIdx.x;
  const int w    = tid >> 6;
  const int lane = tid & 63;
  const int quad = lane >> 4;
  const int m    = lane & 15;
  const int bh = blockIdx.y, b = bh / H, h = bh % H;
  const int iq0 = blockIdx.x * 64;
  const int z = blockIdx.z;
  const long BHL = (long)gridDim.y * L;

  const u16* Qb = Q  + (long)b*qsb + h*qsh;
  const u16* Kb = Kp + (long)(b^bxor)*ksb + h*ksh;
  const u16* Vb = Vp + (long)(b^bxor)*vsb + h*vsh;

  s16x8 aq[2];
  {
    const u16* qr = Qb + (long)(iq0 + w*16 + m) * qsl + quad*8;
    aq[0] = *(const s16x8*)(qr);
    aq[1] = *(const s16x8*)(qr + 32);
  }

  f32x4 o_acc[4];
  #pragma unroll
  for (int nt = 0; nt < 4; ++nt) o_acc[nt] = (f32x4){0.f,0.f,0.f,0.f};
  float mrow[4] = {-1e30f,-1e30f,-1e30f,-1e30f};
  float lrow[4] = {0.f,0.f,0.f,0.f};

  const int srow = tid >> 2, sc0 = (tid & 3) << 4;
  const int kg = tid & 15;
  const int dg = tid >> 4;
  const int vcb = ((((dg >> 2) * 2) + (kg >> 1)) & 7) * 8 + (kg & 1) * 4;
  const int modd = m & 1;
  const int pcolb = m & 6;
  const int jend = z * kchunk + kchunk;

  for (int j0 = z * kchunk; j0 < jend; j0 += 64){
    {
      const u16* kr = Kb + (long)(j0 + srow) * ksl + sc0;
      *(uint4*)&Kt[srow*72 + sc0]     = *(const uint4*)kr;
      *(uint4*)&Kt[srow*72 + sc0 + 8] = *(const uint4*)(kr + 8);
      const u16* vr = Vb + (long)(j0 + 4*kg) * vsl + 4*dg;
      ushort4 r0 = *(const ushort4*)(vr);
      ushort4 r1 = *(const ushort4*)(vr + vsl);
      ushort4 r2 = *(const ushort4*)(vr + 2*vsl);
      ushort4 r3 = *(const ushort4*)(vr + 3*vsl);
      u16* vt = &Vt[(4*dg)*72 + vcb];
      *(ushort4*)(vt)       = make_ushort4(r0.x, r1.x, r2.x, r3.x);
      *(ushort4*)(vt + 72)  = make_ushort4(r0.y, r1.y, r2.y, r3.y);
      *(ushort4*)(vt + 144) = make_ushort4(r0.z, r1.z, r2.z, r3.z);
      *(ushort4*)(vt + 216) = make_ushort4(r0.w, r1.w, r2.w, r3.w);
    }
    __syncthreads();

    float sv[4][4];
    #pragma unroll
    for (int ct = 0; ct < 4; ++ct){
      f32x4 acc = (f32x4){0.f,0.f,0.f,0.f};
      #pragma unroll
      for (int s = 0; s < 2; ++s){
        s16x8 bk = *(const s16x8*)&Kt[(ct*16 + m)*72 + s*32 + quad*8];
        acc = __builtin_amdgcn_mfma_f32_16x16x32_bf16(aq[s], bk, acc, 0, 0, 0);
      }
      #pragma unroll
      for (int r = 0; r < 4; ++r) sv[ct][r] = acc[r];
    }

    // tile max per row; defer-max: only rescale when growth > THR=8 (log2 units)
    float v0s[4];
    int need = 0;
    #pragma unroll
    for (int r = 0; r < 4; ++r){
      float v0 = fmaxf(fmaxf(sv[0][r], sv[1][r]), fmaxf(sv[2][r], sv[3][r]));
      v0 = dppmax16(v0);
      v0s[r] = v0;
      need |= (v0 > mrow[r] + 8.f) ? 1 : 0;
    }
    if (__any(need)){
      float alpha[4];
      #pragma unroll
      for (int r = 0; r < 4; ++r){
        float mn = fmaxf(mrow[r], v0s[r]);
        alpha[r] = exp2f(mrow[r] - mn);
        mrow[r] = mn;
        lrow[r] *= alpha[r];
      }
      #pragma unroll
      for (int nt = 0; nt < 4; ++nt)
        #pragma unroll
        for (int r = 0; r < 4; ++r) o_acc[nt][r] *= alpha[r];
    }
    float rsum[4] = {0.f,0.f,0.f,0.f};
    #pragma unroll
    for (int ct = 0; ct < 4; ++ct)
      #pragma unroll
      for (int r = 0; r < 4; ++r){
        float p = exp2f(sv[ct][r] - mrow[r]);
        sv[ct][r] = p;
        rsum[r] += p;
      }
    #pragma unroll
    for (int r = 0; r < 4; ++r)
      lrow[r] += dppsum16(rsum[r]);

    // Ps packed b32 writes (DPP xor1 pair exchange + cvt_pk)
    #pragma unroll
    for (int ct = 0; ct < 4; ++ct){
      const int kb = (2*w + 2*ct + (m >> 3)) & 7;
      const int col = (kb << 3) | pcolb;
      #pragma unroll
      for (int rr = 0; rr < 2; ++rr){
        float nb_lo = dppf<0xB1>(sv[ct][rr]);
        float nb_hi = dppf<0xB1>(sv[ct][2+rr]);
        float lo = modd ? nb_hi       : sv[ct][rr];
        float hi = modd ? sv[ct][2+rr] : nb_lo;
        unsigned int pk = cvtpk(lo, hi);
        int row = w*16 + quad*4 + rr + 2*modd;
        *(unsigned int*)&Ps[row*72 + col] = pk;
      }
    }
    asm volatile("s_waitcnt lgkmcnt(0)" ::: "memory");  // own-wave rows RAW

    s16x8 ap[2];
    #pragma unroll
    for (int s = 0; s < 2; ++s)
      ap[s] = *(const s16x8*)&Ps[(w*16 + m)*72 + (((2*w + 4*s + quad) & 7) << 3)];
    #pragma unroll
    for (int nt = 0; nt < 4; ++nt)
      #pragma unroll
      for (int s = 0; s < 2; ++s){
        s16x8 bv = *(const s16x8*)&Vt[(nt*16 + m)*72 + (((2*nt + 4*s + quad) & 7) << 3)];
        o_acc[nt] = __builtin_amdgcn_mfma_f32_16x16x32_bf16(ap[s], bv, o_acc[nt], 0, 0, 0);
      }
    __syncthreads();
  }

  const long zOoff = (long)z * BHL * 64;
  #pragma unroll
  for (int r = 0; r < 4; ++r){
    int iq = iq0 + w*16 + quad*4 + r;
    long rowid = ((long)b*L + iq) * H + h;
    #pragma unroll
    for (int nt = 0; nt < 4; ++nt)
      Opart[zOoff + rowid*64 + nt*16 + m] = o_acc[nt][r];
    if (m == 0){
      mpart[(long)z*BHL + rowid] = mrow[r];
      lpart[(long)z*BHL + rowid] = lrow[r];
    }
  }
}

// ---------------- attention split combine (nz-way, log2-domain m) --------
__global__ __launch_bounds__(256) void k_attn_comb(
  const float* Opart, const float* mpart, const float* lpart,
  float* O, long BHL, int nz)
{
  long i = (long)blockIdx.x * 256 + threadIdx.x;
  long row = i >> 6;
  float mv[4];
  float M = -1e30f;
  for (int z = 0; z < nz; ++z){
    mv[z] = mpart[(long)z*BHL + row];
    M = fmaxf(M, mv[z]);
  }
  long N64 = BHL * 64;
  float T = 0.f, acc = 0.f;
  for (int z = 0; z < nz; ++z){
    float wz = exp2f(mv[z] - M);
    T   += lpart[(long)z*BHL + row] * wz;
    acc += Opart[(long)z*N64 + i] * wz;
  }
  O[i] = acc / T;
}

// ---------------- depthwise conv K=5 SAME + silu (batched pseudo-b) ------
__global__ __launch_bounds__(256) void k_conv2(
  const float* __restrict__ xz,
  const void* __restrict__ wx, const void* __restrict__ wz,
  float* __restrict__ outx, float* __restrict__ outz,
  int L, const int* __restrict__ flagp)
{
  int fl = *flagp;
  int c = threadIdx.x;
  int bl = blockIdx.x; int b = bl / L, l = bl % L;
  int choff = blockIdx.y ? 256 : 0;
  const void* w = blockIdx.y ? wz : wx;
  float* out = blockIdx.y ? outz : outx;
  const float* base = xz + ((long)b * L) * 512 + choff + c;
  float s = 0.f;
  #pragma unroll
  for (int kk = 0; kk < 5; ++kk){
    int ll = l + kk - 2;
    if (ll >= 0 && ll < L) s += base[(long)ll * 512] * ldw(w, c*5 + kk, fl);
  }
  out[((long)b * L + l) * 256 + c] = s / (1.f + __expf(-s));   // silu
}

// ---------------- chunk-parallel selective scan ----------------
#define SC_CS 64
#define SC_NC 32

__global__ __launch_bounds__(256) void k_scan1(
  const float* __restrict__ deltaT, const float* __restrict__ dxcT,
  const float* __restrict__ xdbl, const void* __restrict__ Alog,
  float* __restrict__ E_out, float* __restrict__ F_out,
  int L, int ldt, const int* __restrict__ flagp)
{
  int fl = *flagp;
  int tid = threadIdx.x;
  int g = tid >> 4, n = tid & 15;
  int gid = blockIdx.x * 16 + g;
  int chunk = gid & (SC_NC - 1);
  int p = gid >> 5;
  int b = p >> 8, d = p & 255;
  float A = -__expf(ldw(Alog, d*16 + n, fl));
  const float* dTp = deltaT + (long)d*ldt + (long)b*L;
  const float* dxp = dxcT  + (long)d*ldt + (long)b*L;
  const float* xdb = xdbl + (long)b*L*64;
  int l0 = chunk * SC_CS;
  float E = 1.f, F = 0.f;
  for (int i = 0; i < SC_CS; i += 4){
    int l = l0 + i;
    float4 dt4 = *(const float4*)(dTp + l);
    float4 dx4 = *(const float4*)(dxp + l);
    float e[4], u[4];
    e[0] = __expf(dt4.x * A); e[1] = __expf(dt4.y * A);
    e[2] = __expf(dt4.z * A); e[3] = __expf(dt4.w * A);
    u[0] = dx4.x * xdb[(l+0)*64 + 16 + n];
    u[1] = dx4.y * xdb[(l+1)*64 + 16 + n];
    u[2] = dx4.z * xdb[(l+2)*64 + 16 + n];
    u[3] = dx4.w * xdb[(l+3)*64 + 16 + n];
    F = e[0]*F + u[0]; F = e[1]*F + u[1];
    F = e[2]*F + u[2]; F = e[3]*F + u[3];
    E *= (e[0]*e[1]) * (e[2]*e[3]);
  }
  long idx = (long)(p*16 + n) * SC_NC + chunk;
  E_out[idx] = E; F_out[idx] = F;
}

__global__ __launch_bounds__(256) void k_scan2(
  const float* __restrict__ E, const float* __restrict__ F,
  float* __restrict__ Hin)
{
  int pn = blockIdx.x * 256 + threadIdx.x;
  const float* Ep = E + (long)pn * SC_NC;
  const float* Fp = F + (long)pn * SC_NC;
  float* Hp = Hin + (long)pn * SC_NC;
  float h = 0.f;
  #pragma unroll
  for (int c = 0; c < SC_NC; ++c){
    Hp[c] = h;
    h = Ep[c] * h + Fp[c];
  }
}

// y = scan partial only (D*xc folded into o-proj GEMM A-staging)
__global__ __launch_bounds__(256) void k_scan3(
  const float* __restrict__ deltaT, const float* __restrict__ dxcT,
  const float* __restrict__ xdbl, const void* __restrict__ Alog,
  const float* __restrict__ Hin, float* __restrict__ y,
  int L, int ldt, const int* __restrict__ flagp)
{
  int fl = *flagp;
  int tid = threadIdx.x;
  int g = tid >> 4, n = tid & 15;
  int gid = blockIdx.x * 16 + g;
  int chunk = gid & (SC_NC - 1);
  int p = gid >> 5;
  int b = p >> 8, d = p & 255;
  float A = -__expf(ldw(Alog, d*16 + n, fl));
  const float* dTp = deltaT + (long)d*ldt + (long)b*L;
  const float* dxp = dxcT  + (long)d*ldt + (long)b*L;
  const float* xdb = xdbl + (long)b*L*64;
  float* yb = y + (long)b*L*256 + d;
  long idx = (long)(p*16 + n) * SC_NC + chunk;
  float h = Hin[idx];
  int l0 = chunk * SC_CS;
  for (int i = 0; i < SC_CS; i += 4){
    int l = l0 + i;
    float4 dt4 = *(const float4*)(dTp + l);
    float4 dx4 = *(const float4*)(dxp + l);
    float e[4], u[4], cm[4];
    e[0] = __expf(dt4.x * A); e[1] = __expf(dt4.y * A);
    e[2] = __expf(dt4.z * A); e[3] = __expf(dt4.w * A);
    u[0] = dx4.x * xdb[(l+0)*64 + 16 + n];
    u[1] = dx4.y * xdb[(l+1)*64 + 16 + n];
    u[2] = dx4.z * xdb[(l+2)*64 + 16 + n];
    u[3] = dx4.w * xdb[(l+3)*64 + 16 + n];
    cm[0] = xdb[(l+0)*64 + 32 + n];
    cm[1] = xdb[(l+1)*64 + 32 + n];
    cm[2] = xdb[(l+2)*64 + 32 + n];
    cm[3] = xdb[(l+3)*64 + 32 + n];
    float s0, s1, s2, s3;
    h = e[0]*h + u[0]; s0 = h * cm[0];
    h = e[1]*h + u[1]; s1 = h * cm[1];
    h = e[2]*h + u[2]; s2 = h * cm[2];
    h = e[3]*h + u[3]; s3 = h * cm[3];
    s0 += __shfl_xor(s0, 1, 16); s1 += __shfl_xor(s1, 1, 16);
    s2 += __shfl_xor(s2, 1, 16); s3 += __shfl_xor(s3, 1, 16);
    s0 += __shfl_xor(s0, 2, 16); s1 += __shfl_xor(s1, 2, 16);
    s2 += __shfl_xor(s2, 2, 16); s3 += __shfl_xor(s3, 2, 16);
    s0 += __shfl_xor(s0, 4, 16); s1 += __shfl_xor(s1, 4, 16);
    s2 += __shfl_xor(s2, 4, 16); s3 += __shfl_xor(s3, 4, 16);
    s0 += __shfl_xor(s0, 8, 16); s1 += __shfl_xor(s1, 8, 16);
    s2 += __shfl_xor(s2, 8, 16); s3 += __shfl_xor(s3, 8, 16);
    if (n < 4){
      float out = (n == 0) ? s0 : (n == 1) ? s1 : (n == 2) ? s2 : s3;
      yb[(long)(l + n)*256] = out;
    }
  }
}

// two-buffer LN with split-K partial sum (both descriptors batched)
__global__ __launch_bounds__(256) void k_ln2(
  float* __restrict__ hA, const float* __restrict__ hA2,
  float* __restrict__ hB, const float* __restrict__ hB2,
  const void* __restrict__ g, const void* __restrict__ beta,
  const int* __restrict__ flagp)
{
  int fl = *flagp;
  int r = blockIdx.x * 4 + (threadIdx.x >> 6);
  float* hbase = (r < 4096) ? hA : hB;
  const float* h2base = (r < 4096) ? hA2 : hB2;
  int row = r & 4095;
  int lane = threadIdx.x & 63;
  float* hr = hbase + (long)row * 512;
  const float* h2r = h2base + (long)row * 512;
  float v[8]; float s = 0.f, ss = 0.f;
  #pragma unroll
  for (int i = 0; i < 8; ++i){
    v[i] = hr[lane + 64*i] + h2r[lane + 64*i];
    s += v[i]; ss += v[i]*v[i];
  }
  #pragma unroll
  for (int off = 1; off < 64; off <<= 1){ s += __shfl_xor(s, off); ss += __shfl_xor(ss, off); }
  float mean = s * (1.f/512.f);
  float var  = ss * (1.f/512.f) - mean * mean;
  float rs = rsqrtf(var + 1e-5f);
  #pragma unroll
  for (int i = 0; i < 8; ++i){
    int c = lane + 64*i;
    hr[c] = (v[i] - mean) * rs * ldw(g, c, fl) + ldw(beta, c, fl);
  }
}

extern "C" void kernel_launch(void* const* d_in, const int* in_sizes, int n_in,
                              void* d_out, int out_size, void* d_ws, size_t ws_size,
                              hipStream_t stream)
{
  const int B_ = 2, L_ = 2048, H_ = 4;
  const long BLE = (long)B_ * L_ * 256;       // 1,048,576 floats
  const long BHLb = 2L * B_ * H_ * L_;        // 32,768 (batched pseudo-heads)

  int* flagp = (int*)d_ws;
  float* base = (float*)d_ws + 64;

  // ---- workspace map (units of BLE fp32) ----
  float* cat0   = base + 0*BLE;    // 3 BLE, ld 768
  float* cat1   = base + 3*BLE;    // 3 BLE
  float* xz01   = base + 6*BLE;    // 4 BLE, pseudo-b ld 512
  u16*   q01    = (u16*)(base + 10*BLE);
  u16*   k01    = (u16*)(base + 11*BLE);
  u16*   v01    = (u16*)(base + 12*BLE);
  float* Opart  = base + 13*BLE;   // 4 BLE (2 z-planes x 2 BLE batched)
  float* ob01   = base + 21*BLE;   // 2 BLE
  float* mml    = base + 23*BLE;   // 2*32768
  float* mll    = mml + 2*32768;
  float* xc01   = base + 24*BLE;   // 2 BLE
  float* zc01   = base + 26*BLE;   // 2 BLE
  float* xdbl01 = base + 28*BLE;   // 0.5 BLE
  float* delta01= base + 29*BLE;   // 2 BLE (TRANSPOSED 256 x 8192)
  float* dxc01  = base + 31*BLE;   // 2 BLE (TRANSPOSED 256 x 8192)
  float* scE    = base + 33*BLE;
  float* scF    = scE + 524288;
  float* scH    = scF + 524288;
  float* y01    = base + 35*BLE;   // 2 BLE
  float* catc0  = base + 37*BLE;   // 4 BLE, ld 1024
  float* catc1  = base + 41*BLE;   // 4 BLE
  float* h0     = base + 45*BLE;   // 2 BLE, ld 512
  float* part0  = base + 47*BLE;   // 2 BLE
  float* h1     = base + 49*BLE;   // 2 BLE
  float* part1  = base + 51*BLE;   // 2 BLE
  float* dbuf0  = base + 53*BLE;
  float* dbuf1  = base + 54*BLE;
  u16*   qc     = (u16*)(base + 55*BLE);   // cross q/k/v/o bf16, contiguous
  u16*   kc     = qc + 1048576;
  u16*   vc     = kc + 1048576;
  u16*   oc     = vc + 1048576;
  float* catA   = base + 57*BLE;   // 2 BLE, ld 512
  float* catB   = base + 59*BLE;   // 2 BLE
  float* px     = base + 61*BLE;
  float* pd     = px + 16384;
  float* pb     = pd + 16384;

  const void* in[35];
  for (int i = 0; i < 35 && i < n_in; ++i) in[i] = d_in[i];

  k_sniff<<<1, 256, 0, stream>>>((const unsigned int*)in[0], 2048, flagp);
  k_pad<<<130, 256, 0, stream>>>(in[17], in[18], in[19], px, pd, pb, flagp);

  const int BIG = 1 << 30;
  const long sbP = (long)H_ * L_ * 64, shP = (long)L_ * 64, slP = 64;
  const long sbF = (long)L_ * 256,     shF = 64,            slF = 256;
  const int NZ = 2;
  const int kchunk = L_ / NZ;          // 1024
  const int MROWS = 4 * L_;            // 8192 (transposed ld)
  const float LOG2E = 1.4426950408889634f;

  // ---------------- batched mamba_attention (both descriptors) ----------------
  // merged qkv + xz; z-batched over descriptors
  k_gemm_mfma<<<dim3(20, 64, 2), 256, 0, stream>>>(
      in[0], 0, 256, 256, 1280, in[4], in[14], 768, 0, in[5],
      cat0, nullptr, 768, xz01, 512,
      nullptr, 1, 0, nullptr, 1, nullptr, 1.f, 0, 0,
      in[1], 3*BLE, 2*BLE, flagp);
  k_rope<<<dim3(L_/4, 16), 256, 0, stream>>>(cat0, cat1, in[2], in[3],
      q01, k01, v01, L_, B_, H_, flagp);
  k_attn_mfma<<<dim3(L_/64, 16, NZ), 256, 0, stream>>>(
      q01, sbP, shP, slP, k01, sbP, shP, slP, v01, sbP, shP, slP,
      Opart, mml, mll, L_, H_, kchunk, 0);
  k_attn_comb<<<8192, 256, 0, stream>>>(Opart, mml, mll, ob01, BHLb, NZ);
  k_conv2<<<dim3(2*B_*L_, 2), 256, 0, stream>>>(xz01, in[15], in[16], xc01, zc01, L_, flagp);
  // xproj (padded N=64, fp32 weights) into xdbl ld 64; M=8192 both descs
  k_gemm_mfma<<<dim3(1, 128), 256, 0, stream>>>(
      xc01, 1, 256, 256, 64, px, nullptr, BIG, 1, nullptr,
      xdbl01, nullptr, 64, nullptr, 0,
      nullptr, 1, 0, nullptr, 1, nullptr, 1.f, 0, 0,
      nullptr, 0, 0, flagp);
  // dt (padded K=64) + fused softplus -> deltaT, dxcT (transposed ld=8192)
  k_gemm_mfma<<<dim3(4, 128), 256, 0, stream>>>(
      xdbl01, 1, 64, 64, 256, pd, nullptr, BIG, 1, pb,
      delta01, nullptr, MROWS, dxc01, MROWS,
      xc01, 1, 256, nullptr, 1, nullptr, 1.f, 0, 4,
      nullptr, 0, 0, flagp);
  k_scan1<<<2048, 256, 0, stream>>>(delta01, dxc01, xdbl01, in[20], scE, scF, L_, MROWS, flagp);
  k_scan2<<<64, 256, 0, stream>>>(scE, scF, scH);
  k_scan3<<<2048, 256, 0, stream>>>(delta01, dxc01, xdbl01, in[20], scH, y01, L_, MROWS, flagp);
  // batched s_x / c_x / o-proj (+fused raw-input->cat copy), z=6
  {
    GB8 gb = {};
    gb.dvec = in[21];
    gb.A[0] = y01;        gb.aux[0] = xc01;       gb.W[0] = in[22]; gb.Cf[0] = catc0 + 512; gb.osc[0] = 1.f; gb.cfl[0] = 1;
    gb.A[1] = zc01;       gb.W[1] = in[22]; gb.Cf[1] = catc0 + 768; gb.osc[1] = 1.f; gb.cfl[1] = 1;
    gb.A[2] = ob01;       gb.W[2] = in[6];  gb.bias[2] = in[7];     gb.Cf[2] = catc0 + 256;
    gb.csrc[2] = in[0];   gb.cdst[2] = catc0; gb.osc[2] = 1.f;      gb.cfl[2] = 0;
    gb.A[3] = y01 + BLE;  gb.aux[3] = xc01 + BLE; gb.W[3] = in[22]; gb.Cf[3] = catc1 + 512; gb.osc[3] = 1.f; gb.cfl[3] = 1;
    gb.A[4] = zc01 + BLE; gb.W[4] = in[22]; gb.Cf[4] = catc1 + 768; gb.osc[4] = 1.f; gb.cfl[4] = 1;
    gb.A[5] = ob01 + BLE; gb.W[5] = in[6];  gb.bias[5] = in[7];     gb.Cf[5] = catc1 + 256;
    gb.csrc[5] = in[1];   gb.cdst[5] = catc1; gb.osc[5] = 1.f;      gb.cfl[5] = 0;
    k_gemmb<<<dim3(4, 64, 6), 256, 0, stream>>>(gb, 256, 256, 256, 1024, 0, 256, 0, 0, flagp);
  }
  // ffn1 split-K=2 per descriptor (z=4)
  {
    GB8 gb = {};
    gb.cfl[0] = gb.cfl[1] = gb.cfl[2] = gb.cfl[3] = 1;
    gb.A[0] = catc0;       gb.W[0] = in[8]; gb.bias[0] = in[9]; gb.Cf[0] = h0;    gb.osc[0] = 1.f;
    gb.A[1] = catc0 + 512; gb.W[1] = in[8]; gb.wkoff[1] = 512;  gb.Cf[1] = part0; gb.osc[1] = 1.f;
    gb.A[2] = catc1;       gb.W[2] = in[8]; gb.bias[2] = in[9]; gb.Cf[2] = h1;    gb.osc[2] = 1.f;
    gb.A[3] = catc1 + 512; gb.W[3] = in[8]; gb.wkoff[3] = 512;  gb.Cf[3] = part1; gb.osc[3] = 1.f;
    k_gemmb<<<dim3(8, 64, 4), 256, 0, stream>>>(gb, 1024, 512, 512, 512, 0, 1024, 0, 0, flagp);
  }
  k_ln2<<<2048, 256, 0, stream>>>(h0, part0, h1, part1, in[10], in[11], flagp);
  // ffn2: gelu(h) @ W^T + bias + raw-input residual (dtype-aware), z=2
  {
    GB8 gb = {};
    gb.cfl[0] = gb.cfl[1] = 1;
    gb.A[0] = h0; gb.W[0] = in[12]; gb.bias[0] = in[13]; gb.resid[0] = in[0]; gb.rfli[0] = 0;
    gb.Cf[0] = dbuf0; gb.osc[0] = 1.f;
    gb.A[1] = h1; gb.W[1] = in[12]; gb.bias[1] = in[13]; gb.resid[1] = in[1]; gb.rfli[1] = 0;
    gb.Cf[1] = dbuf1; gb.osc[1] = 1.f;
    k_gemmb<<<dim3(4, 64, 2), 256, 0, stream>>>(gb, 512, 512, 256, 256, 256, 512, 1, 0, flagp);
  }

  // ---------------- cross attention (both directions in ONE launch) ----------------
  const float s4 = 0.35355339059327373f;  // 64^-0.25
  float* cm0 = xc01;           // cross comb outputs reuse xc slots (contiguous 2 BLE)
  {
    GB8 gb = {};
    gb.cfl[0] = gb.cfl[1] = gb.cfl[2] = gb.cfl[3] = 1;
    gb.A[0] = dbuf0; gb.W[0] = in[23]; gb.bias[0] = in[24]; gb.Cb[0] = qc; gb.osc[0] = s4 * LOG2E;
    gb.A[1] = dbuf1; gb.W[1] = in[23]; gb.bias[1] = in[24]; gb.Cb[1] = kc; gb.osc[1] = s4;
    gb.A[2] = dbuf0; gb.W[2] = in[25]; gb.bias[2] = in[26]; gb.Cb[2] = vc; gb.osc[2] = 1.f;
    gb.A[3] = dbuf1; gb.W[3] = in[25]; gb.bias[3] = in[26]; gb.Cb[3] = oc; gb.osc[3] = 1.f;
    k_gemmb<<<dim3(4, 64, 4), 256, 0, stream>>>(gb, 256, 256, 256, 256, 0, 256, 0, 3, flagp);
  }
  // pseudo-b 0..3 over contiguous {qc,kc}: Q = qc+b*sbF, K/V index b^2
  //   bh<8 (b=0,1): Q=qc, K=kc, V=oc  -> m0 rows
  //   bh>=8 (b=2,3): Q=kc, K=qc, V=vc -> m1 rows
  k_attn_mfma<<<dim3(L_/64, 16, NZ), 256, 0, stream>>>(
      qc, sbF, shF, slF, qc, sbF, shF, slF, vc, sbF, shF, slF,
      Opart, mml, mll, L_, H_, kchunk, 2);
  k_attn_comb<<<8192, 256, 0, stream>>>(Opart, mml, mll, cm0, BHLb, NZ);
  {
    GB8 gb = {};
    gb.cfl[0] = gb.cfl[1] = 1;
    gb.A[0] = cm0;       gb.W[0] = in[27]; gb.bias[0] = in[28]; gb.Cf[0] = catA + 256;
    gb.csrc[0] = dbuf0;  gb.cdst[0] = catA; gb.osc[0] = 1.f;
    gb.A[1] = cm0 + BLE; gb.W[1] = in[27]; gb.bias[1] = in[28]; gb.Cf[1] = catB + 256;
    gb.csrc[1] = dbuf1;  gb.cdst[1] = catB; gb.osc[1] = 1.f;
    k_gemmb<<<dim3(4, 64, 2), 256, 0, stream>>>(gb, 256, 256, 256, 512, 0, 256, 0, 0, flagp);
  }
  // ca-ffn1 split-K=2 per descriptor (z=4)
  {
    GB8 gb = {};
    gb.cfl[0] = gb.cfl[1] = gb.cfl[2] = gb.cfl[3] = 1;
    gb.A[0] = catA;       gb.W[0] = in[29]; gb.bias[0] = in[30]; gb.Cf[0] = h0;    gb.osc[0] = 1.f;
    gb.A[1] = catA + 256; gb.W[1] = in[29]; gb.wkoff[1] = 256;   gb.Cf[1] = part0; gb.osc[1] = 1.f;
    gb.A[2] = catB;       gb.W[2] = in[29]; gb.bias[2] = in[30]; gb.Cf[2] = h1;    gb.osc[2] = 1.f;
    gb.A[3] = catB + 256; gb.W[3] = in[29]; gb.wkoff[3] = 256;   gb.Cf[3] = part1; gb.osc[3] = 1.f;
    k_gemmb<<<dim3(8, 64, 4), 256, 0, stream>>>(gb, 512, 256, 512, 512, 0, 512, 0, 0, flagp);
  }
  k_ln2<<<2048, 256, 0, stream>>>(h0, part0, h1, part1, in[31], in[32], flagp);
  {
    GB8 gb = {};
    gb.cfl[0] = gb.cfl[1] = 1;
    gb.rfli[0] = gb.rfli[1] = 1;
    gb.A[0] = h0; gb.W[0] = in[33]; gb.bias[0] = in[34]; gb.resid[0] = dbuf0;
    gb.Cf[0] = (float*)d_out; gb.Cb[0] = (u16*)d_out; gb.osc[0] = 1.f;
    gb.A[1] = h1; gb.W[1] = in[33]; gb.bias[1] = in[34]; gb.resid[1] = dbuf1;
    gb.Cf[1] = (float*)d_out + BLE; gb.Cb[1] = (u16*)d_out + BLE; gb.osc[1] = 1.f;
    k_gemmb<<<dim3(4, 64, 2), 256, 0, stream>>>(gb, 512, 512, 256, 256, 256, 512, 1, 2, flagp);
  }
}

// Round 9
// 649.311 us; speedup vs baseline: 1.2631x; 1.0124x over previous
//
#include <hip/hip_runtime.h>

typedef unsigned short u16;
typedef short s16;
typedef s16 s16x8 __attribute__((ext_vector_type(8)));
typedef float f32x4 __attribute__((ext_vector_type(4)));

__device__ __forceinline__ float bf2f(u16 u){
  union { unsigned int i; float f; } v; v.i = ((unsigned int)u) << 16; return v.f;
}
__device__ __forceinline__ u16 f2bf(float f){
  union { float f; unsigned int u; } v; v.f = f;
  unsigned int r = (v.u + 0x7fffu + ((v.u >> 16) & 1u)) >> 16;
  return (u16)r;
}
// packed f32x2 -> bf16x2 (RNE, identical to f2bf) in ONE VALU op
__device__ __forceinline__ unsigned int cvtpk(float lo, float hi){
  unsigned int d;
  asm("v_cvt_pk_bf16_f32 %0, %1, %2" : "=v"(d) : "v"(lo), "v"(hi));
  return d;
}
__device__ __forceinline__ uint4 pack8(float4 a0, float4 a1){
  uint4 v;
  v.x = cvtpk(a0.x, a0.y); v.y = cvtpk(a0.z, a0.w);
  v.z = cvtpk(a1.x, a1.y); v.w = cvtpk(a1.z, a1.w);
  return v;
}
__device__ __forceinline__ float gelu_f(float x){
  return 0.5f * x * (1.f + erff(x * 0.70710678118654752440f));
}
__device__ __forceinline__ float ldw(const void* p, long i, int fl){
  return fl ? bf2f(((const u16*)p)[i]) : ((const float*)p)[i];
}
__device__ __forceinline__ float4 ldw4(const void* p, long i, int fl){
  if (fl){
    ushort4 w = *(const ushort4*)((const u16*)p + i);
    return make_float4(bf2f(w.x), bf2f(w.y), bf2f(w.z), bf2f(w.w));
  }
  return *(const float4*)((const float*)p + i);
}

// ---- DPP 16-lane butterfly reductions (VALU pipe, zero LDS traffic) ----
template<int C>
__device__ __forceinline__ float dppf(float x){
  return __int_as_float(__builtin_amdgcn_update_dpp(0, __float_as_int(x), C, 0xf, 0xf, true));
}
__device__ __forceinline__ float dppmax16(float v){
  v = fmaxf(v, dppf<0xB1>(v));
  v = fmaxf(v, dppf<0x4E>(v));
  v = fmaxf(v, dppf<0x141>(v));
  v = fmaxf(v, dppf<0x140>(v));
  return v;
}
__device__ __forceinline__ float dppsum16(float v){
  v += dppf<0xB1>(v);
  v += dppf<0x4E>(v);
  v += dppf<0x141>(v);
  v += dppf<0x140>(v);
  return v;
}

// ---------------- dtype sniffer (flag[0]=dtype, flag[1]=0 const) --------
__global__ __launch_bounds__(256) void k_sniff(const unsigned int* __restrict__ w,
                                               int n, int* __restrict__ flag){
  __shared__ int cnt[256];
  int c = 0;
  for (int i = threadIdx.x; i < n; i += 256){
    unsigned e = (w[i] >> 7) & 0xFFu;
    c += (e >= 120u && e <= 127u) ? 1 : 0;
  }
  cnt[threadIdx.x] = c; __syncthreads();
  for (int s = 128; s > 0; s >>= 1){
    if (threadIdx.x < s) cnt[threadIdx.x] += cnt[threadIdx.x + s];
    __syncthreads();
  }
  if (threadIdx.x == 0) flag[0] = (2 * cnt[0] > n) ? 1 : 0;
  if (threadIdx.x == 1) flag[1] = 0;
}

// ---- weight pre-conversion: 11 static matrices -> contiguous bf16 buffer ----
struct WC { const void* src[11]; int off[12]; };
__global__ __launch_bounds__(256) void k_wconv(WC wc, u16* __restrict__ dst,
                                               const int* __restrict__ flagp){
  int fl = *flagp;
  int i = blockIdx.x * 256 + threadIdx.x;
  if (i >= wc.off[11]) return;
  int s = 0;
  #pragma unroll
  for (int t = 1; t < 11; ++t) s += (i >= wc.off[t]) ? 1 : 0;
  dst[i] = f2bf(ldw(wc.src[s], i - wc.off[s], fl));
}

// ---- zero-pad xproj (48x256 -> 64x256) / dt_w (256x16 -> 256x64) -> bf16; dt_b fp32 ----
__global__ __launch_bounds__(256) void k_pad(
  const void* __restrict__ wx, const void* __restrict__ wd,
  const void* __restrict__ bd,
  u16* __restrict__ px, u16* __restrict__ pd, float* __restrict__ pb,
  const int* __restrict__ flagp)
{
  int fl = *flagp;
  int i = blockIdx.x * 256 + threadIdx.x;
  if (i < 16384){
    int r = i >> 8, c = i & 255;
    px[i] = f2bf((r < 48) ? ldw(wx, r*256 + c, fl) : 0.f);
  } else if (i < 32768){
    int j = i - 16384;
    int n = j >> 6, k = j & 63;
    pd[j] = f2bf((k < 16) ? ldw(wd, n*16 + k, fl) : 0.f);
  } else if (i < 33024){
    pb[i - 32768] = ldw(bd, i - 32768, fl);
  }
}

// ---------------- MFMA GEMM (staged 64x64 tile; weights always bf16) ----------------
// outmode: 0 fp32, 2 dynamic, 3 bf16,
//          4 softplus(dt+2*bias) -> Cf TRANSPOSED (d-major), delta*resid -> C2 TRANSPOSED.
// A1/coff1/c2off1: optional z-batch (blockIdx.z==1 uses A1, Cf+coff1, C2+c2off1).
__global__ __launch_bounds__(256) void k_gemm_mfma(
  const void* __restrict__ A0, int aflidx, int lda, int K, int N,
  const u16* __restrict__ W, const u16* __restrict__ W2, int nsplit, int wflidx,
  const void* __restrict__ bias,
  float* __restrict__ Cf0, u16* __restrict__ Cb, int ldc,
  float* __restrict__ C20, int ldc2,
  const void* __restrict__ resid, int rflidx, int ldr,
  const void* __restrict__ csrc, int cflidx, float* __restrict__ cdst,
  float oscale, int act_gelu, int outmode,
  const void* __restrict__ A1, long coff1, long c2off1,
  const int* __restrict__ flagp)
{
  const int fl  = flagp[0];
  const int afl = flagp[aflidx];
  const int wfl = flagp[wflidx];     // bias dtype only
  const int rfl = flagp[rflidx];
  const int cfl = flagp[cflidx];
  const void* A = A0;
  float* Cf = Cf0;
  float* C2 = C20;
  if (blockIdx.z){ A = A1; Cf += coff1; C2 += c2off1; }
  __shared__ u16 As[64*72];
  __shared__ u16 Bs[64*72];
  const int tid = threadIdx.x;
  const int w = tid >> 6, lane = tid & 63, quad = lane >> 4, m = lane & 15;
  const int m0 = blockIdx.y << 6, n0 = blockIdx.x << 6;
  const int srow = tid >> 2, sc0 = (tid & 3) << 4;
  const int reg2 = (n0 >= nsplit);
  const u16* Wp = reg2 ? W2 : W;
  const int nbase = reg2 ? nsplit : 0;

  f32x4 acc[4];
  #pragma unroll
  for (int ct = 0; ct < 4; ++ct) acc[ct] = (f32x4){0.f,0.f,0.f,0.f};

  for (int k0 = 0; k0 < K; k0 += 64){
    {
      long ab = (long)(m0 + srow) * lda + k0 + sc0;
      if (afl && !act_gelu){
        #pragma unroll
        for (int g = 0; g < 2; ++g)
          *(uint4*)&As[srow*72 + sc0 + g*8] = *(const uint4*)((const u16*)A + ab + g*8);
      } else {
        #pragma unroll
        for (int g = 0; g < 2; ++g){
          float4 a0 = ldw4(A, ab + g*8, afl);
          float4 a1 = ldw4(A, ab + g*8 + 4, afl);
          if (act_gelu){
            a0.x=gelu_f(a0.x); a0.y=gelu_f(a0.y); a0.z=gelu_f(a0.z); a0.w=gelu_f(a0.w);
            a1.x=gelu_f(a1.x); a1.y=gelu_f(a1.y); a1.z=gelu_f(a1.z); a1.w=gelu_f(a1.w);
          }
          *(uint4*)&As[srow*72 + sc0 + g*8] = pack8(a0, a1);
        }
      }
    }
    {
      long wb = (long)(n0 + srow - nbase) * K + k0 + sc0;
      #pragma unroll
      for (int g = 0; g < 2; ++g)
        *(uint4*)&Bs[srow*72 + sc0 + g*8] = *(const uint4*)(Wp + wb + g*8);
    }
    __syncthreads();

    s16x8 av[2];
    #pragma unroll
    for (int s = 0; s < 2; ++s)
      av[s] = *(const s16x8*)&As[(w*16 + m)*72 + s*32 + quad*8];
    #pragma unroll
    for (int ct = 0; ct < 4; ++ct)
      #pragma unroll
      for (int s = 0; s < 2; ++s){
        s16x8 bv = *(const s16x8*)&Bs[(ct*16 + m)*72 + s*32 + quad*8];
        acc[ct] = __builtin_amdgcn_mfma_f32_16x16x32_bf16(av[s], bv, acc[ct], 0, 0, 0);
      }
    __syncthreads();
  }

  if (outmode == 4){
    // transposed float4 stores: acc[ct] = 4 consecutive rows for column gn
    const int gmb = m0 + w*16 + quad*4;
    #pragma unroll
    for (int ct = 0; ct < 4; ++ct){
      int gn = n0 + ct*16 + m;
      float bv = ldw(bias, gn, wfl);
      float dl4[4], dx4[4];
      #pragma unroll
      for (int r = 0; r < 4; ++r){
        float dl = acc[ct][r] + bv + bv;     // dt + 2*dt_bias (ref's double add)
        float delta = (dl > 20.f) ? dl : __logf(1.f + __expf(dl));
        dl4[r] = delta;
        dx4[r] = delta * ldw(resid, (long)(gmb + r) * ldr + gn, rfl);
      }
      *(float4*)&Cf[(long)gn * ldc + gmb] = make_float4(dl4[0], dl4[1], dl4[2], dl4[3]);
      *(float4*)&C2[(long)gn * ldc2 + gmb] = make_float4(dx4[0], dx4[1], dx4[2], dx4[3]);
    }
    return;
  }

  #pragma unroll
  for (int r = 0; r < 4; ++r){
    int gm = m0 + w*16 + quad*4 + r;
    #pragma unroll
    for (int ct = 0; ct < 4; ++ct){
      int gn = n0 + ct*16 + m;
      float v = acc[ct][r];
      if (reg2){
        C2[(long)gm * ldc2 + (gn - nsplit)] = v;
      } else {
        if (bias) v += ldw(bias, gn, wfl);
        v *= oscale;
        if (resid) v += ldw(resid, (long)gm * ldr + gn, rfl);
        long off = (long)gm * ldc + gn;
        if (outmode == 2){
          if (fl) Cb[off] = f2bf(v); else Cf[off] = v;
        } else if (outmode == 3){
          Cb[off] = f2bf(v);
        } else {
          Cf[off] = v;
        }
        if (cdst) cdst[(long)gm * ldc + gn] = ldw(csrc, (long)gm * 256 + gn, cfl);
      }
    }
  }
}

// ---------------- z-batched MFMA GEMM (up to 8 independent problems) ----------------
// Weights always bf16 (pre-converted). ldwq/wkoff in elements.
struct GB8 {
  const float* A[8]; const u16* W[8]; const void* bias[8];
  float* Cf[8]; u16* Cb[8]; const void* resid[8];
  const void* csrc[8]; float* cdst[8]; float osc[8];
  int cfl[8]; int wkoff[8]; int rfli[8];
  const float* aux[8]; const void* dvec;
};

__global__ __launch_bounds__(256) void k_gemmb(
  GB8 gb, int lda, int K, int N, int ldc, int ldr, int ldwq,
  int act_gelu, int outmode, const int* __restrict__ flagp)
{
  const int fl = flagp[0];
  const int z = blockIdx.z;
  const float* A = gb.A[z]; const u16* W = gb.W[z]; const void* bias = gb.bias[z];
  float* Cf = gb.Cf[z]; u16* Cb = gb.Cb[z]; const void* resid = gb.resid[z];
  const void* csrc = gb.csrc[z]; float* cdst = gb.cdst[z];
  const float osc = gb.osc[z];
  const int cfl = flagp[gb.cfl[z]];
  const int rfl = flagp[gb.rfli[z]];
  const int wkoff = gb.wkoff[z];
  const float* aux = gb.aux[z];

  __shared__ u16 As[64*72];
  __shared__ u16 Bs[64*72];
  const int tid = threadIdx.x;
  const int w = tid >> 6, lane = tid & 63, quad = lane >> 4, m = lane & 15;
  const int m0 = blockIdx.y << 6, n0 = blockIdx.x << 6;
  const int srow = tid >> 2, sc0 = (tid & 3) << 4;

  f32x4 acc[4];
  #pragma unroll
  for (int ct = 0; ct < 4; ++ct) acc[ct] = (f32x4){0.f,0.f,0.f,0.f};

  for (int k0 = 0; k0 < K; k0 += 64){
    {
      const float* ar = A + (long)(m0 + srow) * lda + k0 + sc0;
      #pragma unroll
      for (int g = 0; g < 2; ++g){
        float4 a0 = *(const float4*)(ar + g*8);
        float4 a1 = *(const float4*)(ar + g*8 + 4);
        if (aux){
          const float* xr = aux + (long)(m0 + srow) * lda + k0 + sc0;
          float4 x0 = *(const float4*)(xr + g*8);
          float4 x1 = *(const float4*)(xr + g*8 + 4);
          float4 d0 = ldw4(gb.dvec, k0 + sc0 + g*8, fl);
          float4 d1 = ldw4(gb.dvec, k0 + sc0 + g*8 + 4, fl);
          a0.x += d0.x*x0.x; a0.y += d0.y*x0.y; a0.z += d0.z*x0.z; a0.w += d0.w*x0.w;
          a1.x += d1.x*x1.x; a1.y += d1.y*x1.y; a1.z += d1.z*x1.z; a1.w += d1.w*x1.w;
        }
        if (act_gelu){
          a0.x=gelu_f(a0.x); a0.y=gelu_f(a0.y); a0.z=gelu_f(a0.z); a0.w=gelu_f(a0.w);
          a1.x=gelu_f(a1.x); a1.y=gelu_f(a1.y); a1.z=gelu_f(a1.z); a1.w=gelu_f(a1.w);
        }
        *(uint4*)&As[srow*72 + sc0 + g*8] = pack8(a0, a1);
      }
    }
    {
      long wb = (long)(n0 + srow) * ldwq + wkoff + k0 + sc0;
      #pragma unroll
      for (int g = 0; g < 2; ++g)
        *(uint4*)&Bs[srow*72 + sc0 + g*8] = *(const uint4*)(W + wb + g*8);
    }
    __syncthreads();

    s16x8 av[2];
    #pragma unroll
    for (int s = 0; s < 2; ++s)
      av[s] = *(const s16x8*)&As[(w*16 + m)*72 + s*32 + quad*8];
    #pragma unroll
    for (int ct = 0; ct < 4; ++ct)
      #pragma unroll
      for (int s = 0; s < 2; ++s){
        s16x8 bv = *(const s16x8*)&Bs[(ct*16 + m)*72 + s*32 + quad*8];
        acc[ct] = __builtin_amdgcn_mfma_f32_16x16x32_bf16(av[s], bv, acc[ct], 0, 0, 0);
      }
    __syncthreads();
  }

  #pragma unroll
  for (int r = 0; r < 4; ++r){
    int gm = m0 + w*16 + quad*4 + r;
    #pragma unroll
    for (int ct = 0; ct < 4; ++ct){
      int gn = n0 + ct*16 + m;
      float v = acc[ct][r];
      if (bias) v += ldw(bias, gn, fl);
      v *= osc;
      if (resid) v += ldw(resid, (long)gm * ldr + gn, rfl);
      long off = (long)gm * ldc + gn;
      if (outmode == 2){
        if (fl) Cb[off] = f2bf(v); else Cf[off] = v;
      } else if (outmode == 3){
        Cb[off] = f2bf(v);
      } else {
        Cf[off] = v;
      }
      if (cdst) cdst[(long)gm * ldc + gn] = ldw(csrc, (long)gm * 256 + gn, cfl);
    }
  }
}

// ---------------- QKV extract + rotary, 2-descriptor batched --------------
// grid.y = 16: bh = dsc*8 + b*4 + h. Output bf16 head-major (bh,L,64).
// q pre-scaled by 0.125*log2(e): scores land in log2 domain (exp2 softmax).
__global__ __launch_bounds__(256) void k_rope(
  const float* __restrict__ qkv0, const float* __restrict__ qkv1,
  const void* __restrict__ pe0, const void* __restrict__ pe1,
  u16* __restrict__ q, u16* __restrict__ k, u16* __restrict__ v,
  int L, int B, int H, const int* __restrict__ flagp)
{
  int fl = *flagp;
  int tid = threadIdx.x;
  int lq = tid >> 6, d = tid & 63;
  int l = blockIdx.x * 4 + lq;
  int bh = blockIdx.y;
  int dsc = bh >> 3;
  int bh7 = bh & 7;
  int b = bh7 >> 2, h = bh7 & 3;
  const float* qkv = dsc ? qkv1 : qkv0;
  const void* pe = dsc ? pe1 : pe0;
  const float* row = qkv + ((long)b * L + l) * 768 + h * 192;
  float qv = row[d*3+0], kv = row[d*3+1], vv = row[d*3+2];
  int dn = (d & 1) ? (d - 1) : (d + 1);
  float qn = row[dn*3+0], kn = row[dn*3+1];
  float rq = (d & 1) ? qn : -qn;
  float rk = (d & 1) ? kn : -kn;
  long peo = ((long)b * L + l) * 64 + d;
  float p0 = ldw(pe, peo, fl);
  float p1 = ldw(pe, (long)B * L * 64 + peo, fl);
  long o = ((long)bh * L + l) * 64 + d;
  q[o] = f2bf((qv * p0 + rq * p1) * 0.18033688011112042f);  // 0.125 * log2(e)
  k[o] = f2bf(kv * p0 + rk * p1);
  v[o] = f2bf(vv);
}

// ---------------- MFMA flash attention, bf16 in / fp32 partials out ------
// Scores in log2 domain (exp2 softmax). K-split via blockIdx.z (NZ=2).
// bxor: K/V batch index = b^bxor (enables batching both cross directions).
__global__ __launch_bounds__(256, 8) void k_attn_mfma(
  const u16* __restrict__ Q, long qsb, long qsh, long qsl,
  const u16* __restrict__ Kp, long ksb, long ksh, long ksl,
  const u16* __restrict__ Vp, long vsb, long vsh, long vsl,
  float* __restrict__ Opart, float* __restrict__ mpart, float* __restrict__ lpart,
  int L, int H, int kchunk, int bxor)
{
  __shared__ u16 Kt[64*72];
  __shared__ u16 Vt[64*72];
  __shared__ u16 Ps[64*72];     // wave-private rows: no barrier needed around it
  const int tid  = threadIdx.x;
  const int w    = tid >> 6;
  const int lane = tid & 63;
  const int quad = lane >> 4;
  const int m    = lane & 15;
  const int bh = blockIdx.y, b = bh / H, h = bh % H;
  const int iq0 = blockIdx.x * 64;
  const int z = blockIdx.z;
  const long BHL = (long)gridDim.y * L;

  const u16* Qb = Q  + (long)b*qsb + h*qsh;
  const u16* Kb = Kp + (long)(b^bxor)*ksb + h*ksh;
  const u16* Vb = Vp + (long)(b^bxor)*vsb + h*vsh;

  s16x8 aq[2];
  {
    const u16* qr = Qb + (long)(iq0 + w*16 + m) * qsl + quad*8;
    aq[0] = *(const s16x8*)(qr);
    aq[1] = *(const s16x8*)(qr + 32);
  }

  f32x4 o_acc[4];
  #pragma unroll
  for (int nt = 0; nt < 4; ++nt) o_acc[nt] = (f32x4){0.f,0.f,0.f,0.f};
  float mrow[4] = {-1e30f,-1e30f,-1e30f,-1e30f};
  float lrow[4] = {0.f,0.f,0.f,0.f};

  const int srow = tid >> 2, sc0 = (tid & 3) << 4;
  const int kg = tid & 15;
  const int dg = tid >> 4;
  const int vcb = ((((dg >> 2) * 2) + (kg >> 1)) & 7) * 8 + (kg & 1) * 4;
  const int modd = m & 1;
  const int pcolb = m & 6;
  const int jend = z * kchunk + kchunk;

  for (int j0 = z * kchunk; j0 < jend; j0 += 64){
    {
      const u16* kr = Kb + (long)(j0 + srow) * ksl + sc0;
      *(uint4*)&Kt[srow*72 + sc0]     = *(const uint4*)kr;
      *(uint4*)&Kt[srow*72 + sc0 + 8] = *(const uint4*)(kr + 8);
      const u16* vr = Vb + (long)(j0 + 4*kg) * vsl + 4*dg;
      ushort4 r0 = *(const ushort4*)(vr);
      ushort4 r1 = *(const ushort4*)(vr + vsl);
      ushort4 r2 = *(const ushort4*)(vr + 2*vsl);
      ushort4 r3 = *(const ushort4*)(vr + 3*vsl);
      u16* vt = &Vt[(4*dg)*72 + vcb];
      *(ushort4*)(vt)       = make_ushort4(r0.x, r1.x, r2.x, r3.x);
      *(ushort4*)(vt + 72)  = make_ushort4(r0.y, r1.y, r2.y, r3.y);
      *(ushort4*)(vt + 144) = make_ushort4(r0.z, r1.z, r2.z, r3.z);
      *(ushort4*)(vt + 216) = make_ushort4(r0.w, r1.w, r2.w, r3.w);
    }
    __syncthreads();

    float sv[4][4];
    #pragma unroll
    for (int ct = 0; ct < 4; ++ct){
      f32x4 acc = (f32x4){0.f,0.f,0.f,0.f};
      #pragma unroll
      for (int s = 0; s < 2; ++s){
        s16x8 bk = *(const s16x8*)&Kt[(ct*16 + m)*72 + s*32 + quad*8];
        acc = __builtin_amdgcn_mfma_f32_16x16x32_bf16(aq[s], bk, acc, 0, 0, 0);
      }
      #pragma unroll
      for (int r = 0; r < 4; ++r) sv[ct][r] = acc[r];
    }

    // tile max per row; defer-max: only rescale when growth > THR=8 (log2 units)
    float v0s[4];
    int need = 0;
    #pragma unroll
    for (int r = 0; r < 4; ++r){
      float v0 = fmaxf(fmaxf(sv[0][r], sv[1][r]), fmaxf(sv[2][r], sv[3][r]));
      v0 = dppmax16(v0);
      v0s[r] = v0;
      need |= (v0 > mrow[r] + 8.f) ? 1 : 0;
    }
    if (__any(need)){
      float alpha[4];
      #pragma unroll
      for (int r = 0; r < 4; ++r){
        float mn = fmaxf(mrow[r], v0s[r]);
        alpha[r] = exp2f(mrow[r] - mn);
        mrow[r] = mn;
        lrow[r] *= alpha[r];
      }
      #pragma unroll
      for (int nt = 0; nt < 4; ++nt)
        #pragma unroll
        for (int r = 0; r < 4; ++r) o_acc[nt][r] *= alpha[r];
    }
    float rsum[4] = {0.f,0.f,0.f,0.f};
    #pragma unroll
    for (int ct = 0; ct < 4; ++ct)
      #pragma unroll
      for (int r = 0; r < 4; ++r){
        float p = exp2f(sv[ct][r] - mrow[r]);
        sv[ct][r] = p;
        rsum[r] += p;
      }
    #pragma unroll
    for (int r = 0; r < 4; ++r)
      lrow[r] += dppsum16(rsum[r]);

    // Ps packed b32 writes (DPP xor1 pair exchange + cvt_pk)
    #pragma unroll
    for (int ct = 0; ct < 4; ++ct){
      const int kb = (2*w + 2*ct + (m >> 3)) & 7;
      const int col = (kb << 3) | pcolb;
      #pragma unroll
      for (int rr = 0; rr < 2; ++rr){
        float nb_lo = dppf<0xB1>(sv[ct][rr]);
        float nb_hi = dppf<0xB1>(sv[ct][2+rr]);
        float lo = modd ? nb_hi       : sv[ct][rr];
        float hi = modd ? sv[ct][2+rr] : nb_lo;
        unsigned int pk = cvtpk(lo, hi);
        int row = w*16 + quad*4 + rr + 2*modd;
        *(unsigned int*)&Ps[row*72 + col] = pk;
      }
    }
    asm volatile("s_waitcnt lgkmcnt(0)" ::: "memory");  // own-wave rows RAW

    s16x8 ap[2];
    #pragma unroll
    for (int s = 0; s < 2; ++s)
      ap[s] = *(const s16x8*)&Ps[(w*16 + m)*72 + (((2*w + 4*s + quad) & 7) << 3)];
    #pragma unroll
    for (int nt = 0; nt < 4; ++nt)
      #pragma unroll
      for (int s = 0; s < 2; ++s){
        s16x8 bv = *(const s16x8*)&Vt[(nt*16 + m)*72 + (((2*nt + 4*s + quad) & 7) << 3)];
        o_acc[nt] = __builtin_amdgcn_mfma_f32_16x16x32_bf16(ap[s], bv, o_acc[nt], 0, 0, 0);
      }
    __syncthreads();
  }

  const long zOoff = (long)z * BHL * 64;
  #pragma unroll
  for (int r = 0; r < 4; ++r){
    int iq = iq0 + w*16 + quad*4 + r;
    long rowid = ((long)b*L + iq) * H + h;
    #pragma unroll
    for (int nt = 0; nt < 4; ++nt)
      Opart[zOoff + rowid*64 + nt*16 + m] = o_acc[nt][r];
    if (m == 0){
      mpart[(long)z*BHL + rowid] = mrow[r];
      lpart[(long)z*BHL + rowid] = lrow[r];
    }
  }
}

// ---------------- attention split combine (nz-way, log2-domain m) --------
__global__ __launch_bounds__(256) void k_attn_comb(
  const float* Opart, const float* mpart, const float* lpart,
  float* O, long BHL, int nz)
{
  long i = (long)blockIdx.x * 256 + threadIdx.x;
  long row = i >> 6;
  float mv[4];
  float M = -1e30f;
  for (int z = 0; z < nz; ++z){
    mv[z] = mpart[(long)z*BHL + row];
    M = fmaxf(M, mv[z]);
  }
  long N64 = BHL * 64;
  float T = 0.f, acc = 0.f;
  for (int z = 0; z < nz; ++z){
    float wz = exp2f(mv[z] - M);
    T   += lpart[(long)z*BHL + row] * wz;
    acc += Opart[(long)z*N64 + i] * wz;
  }
  O[i] = acc / T;
}

// ---------------- depthwise conv K=5 SAME + silu (batched pseudo-b) ------
__global__ __launch_bounds__(256) void k_conv2(
  const float* __restrict__ xz,
  const void* __restrict__ wx, const void* __restrict__ wz,
  float* __restrict__ outx, float* __restrict__ outz,
  int L, const int* __restrict__ flagp)
{
  int fl = *flagp;
  int c = threadIdx.x;
  int bl = blockIdx.x; int b = bl / L, l = bl % L;
  int choff = blockIdx.y ? 256 : 0;
  const void* w = blockIdx.y ? wz : wx;
  float* out = blockIdx.y ? outz : outx;
  const float* base = xz + ((long)b * L) * 512 + choff + c;
  float s = 0.f;
  #pragma unroll
  for (int kk = 0; kk < 5; ++kk){
    int ll = l + kk - 2;
    if (ll >= 0 && ll < L) s += base[(long)ll * 512] * ldw(w, c*5 + kk, fl);
  }
  out[((long)b * L + l) * 256 + c] = s / (1.f + __expf(-s));   // silu
}

// ---------------- chunk-parallel selective scan ----------------
#define SC_CS 64
#define SC_NC 32

__global__ __launch_bounds__(256) void k_scan1(
  const float* __restrict__ deltaT, const float* __restrict__ dxcT,
  const float* __restrict__ xdbl, const void* __restrict__ Alog,
  float* __restrict__ E_out, float* __restrict__ F_out,
  int L, int ldt, const int* __restrict__ flagp)
{
  int fl = *flagp;
  int tid = threadIdx.x;
  int g = tid >> 4, n = tid & 15;
  int gid = blockIdx.x * 16 + g;
  int chunk = gid & (SC_NC - 1);
  int p = gid >> 5;
  int b = p >> 8, d = p & 255;
  float A = -__expf(ldw(Alog, d*16 + n, fl));
  const float* dTp = deltaT + (long)d*ldt + (long)b*L;
  const float* dxp = dxcT  + (long)d*ldt + (long)b*L;
  const float* xdb = xdbl + (long)b*L*64;
  int l0 = chunk * SC_CS;
  float E = 1.f, F = 0.f;
  for (int i = 0; i < SC_CS; i += 4){
    int l = l0 + i;
    float4 dt4 = *(const float4*)(dTp + l);
    float4 dx4 = *(const float4*)(dxp + l);
    float e[4], u[4];
    e[0] = __expf(dt4.x * A); e[1] = __expf(dt4.y * A);
    e[2] = __expf(dt4.z * A); e[3] = __expf(dt4.w * A);
    u[0] = dx4.x * xdb[(l+0)*64 + 16 + n];
    u[1] = dx4.y * xdb[(l+1)*64 + 16 + n];
    u[2] = dx4.z * xdb[(l+2)*64 + 16 + n];
    u[3] = dx4.w * xdb[(l+3)*64 + 16 + n];
    F = e[0]*F + u[0]; F = e[1]*F + u[1];
    F = e[2]*F + u[2]; F = e[3]*F + u[3];
    E *= (e[0]*e[1]) * (e[2]*e[3]);
  }
  long idx = (long)(p*16 + n) * SC_NC + chunk;
  E_out[idx] = E; F_out[idx] = F;
}

__global__ __launch_bounds__(256) void k_scan2(
  const float* __restrict__ E, const float* __restrict__ F,
  float* __restrict__ Hin)
{
  int pn = blockIdx.x * 256 + threadIdx.x;
  const float* Ep = E + (long)pn * SC_NC;
  const float* Fp = F + (long)pn * SC_NC;
  float* Hp = Hin + (long)pn * SC_NC;
  float h = 0.f;
  #pragma unroll
  for (int c = 0; c < SC_NC; ++c){
    Hp[c] = h;
    h = Ep[c] * h + Fp[c];
  }
}

// y = scan partial only (D*xc folded into o-proj GEMM A-staging)
__global__ __launch_bounds__(256) void k_scan3(
  const float* __restrict__ deltaT, const float* __restrict__ dxcT,
  const float* __restrict__ xdbl, const void* __restrict__ Alog,
  const float* __restrict__ Hin, float* __restrict__ y,
  int L, int ldt, const int* __restrict__ flagp)
{
  int fl = *flagp;
  int tid = threadIdx.x;
  int g = tid >> 4, n = tid & 15;
  int gid = blockIdx.x * 16 + g;
  int chunk = gid & (SC_NC - 1);
  int p = gid >> 5;
  int b = p >> 8, d = p & 255;
  float A = -__expf(ldw(Alog, d*16 + n, fl));
  const float* dTp = deltaT + (long)d*ldt + (long)b*L;
  const float* dxp = dxcT  + (long)d*ldt + (long)b*L;
  const float* xdb = xdbl + (long)b*L*64;
  float* yb = y + (long)b*L*256 + d;
  long idx = (long)(p*16 + n) * SC_NC + chunk;
  float h = Hin[idx];
  int l0 = chunk * SC_CS;
  for (int i = 0; i < SC_CS; i += 4){
    int l = l0 + i;
    float4 dt4 = *(const float4*)(dTp + l);
    float4 dx4 = *(const float4*)(dxp + l);
    float e[4], u[4], cm[4];
    e[0] = __expf(dt4.x * A); e[1] = __expf(dt4.y * A);
    e[2] = __expf(dt4.z * A); e[3] = __expf(dt4.w * A);
    u[0] = dx4.x * xdb[(l+0)*64 + 16 + n];
    u[1] = dx4.y * xdb[(l+1)*64 + 16 + n];
    u[2] = dx4.z * xdb[(l+2)*64 + 16 + n];
    u[3] = dx4.w * xdb[(l+3)*64 + 16 + n];
    cm[0] = xdb[(l+0)*64 + 32 + n];
    cm[1] = xdb[(l+1)*64 + 32 + n];
    cm[2] = xdb[(l+2)*64 + 32 + n];
    cm[3] = xdb[(l+3)*64 + 32 + n];
    float s0, s1, s2, s3;
    h = e[0]*h + u[0]; s0 = h * cm[0];
    h = e[1]*h + u[1]; s1 = h * cm[1];
    h = e[2]*h + u[2]; s2 = h * cm[2];
    h = e[3]*h + u[3]; s3 = h * cm[3];
    s0 += __shfl_xor(s0, 1, 16); s1 += __shfl_xor(s1, 1, 16);
    s2 += __shfl_xor(s2, 1, 16); s3 += __shfl_xor(s3, 1, 16);
    s0 += __shfl_xor(s0, 2, 16); s1 += __shfl_xor(s1, 2, 16);
    s2 += __shfl_xor(s2, 2, 16); s3 += __shfl_xor(s3, 2, 16);
    s0 += __shfl_xor(s0, 4, 16); s1 += __shfl_xor(s1, 4, 16);
    s2 += __shfl_xor(s2, 4, 16); s3 += __shfl_xor(s3, 4, 16);
    s0 += __shfl_xor(s0, 8, 16); s1 += __shfl_xor(s1, 8, 16);
    s2 += __shfl_xor(s2, 8, 16); s3 += __shfl_xor(s3, 8, 16);
    if (n < 4){
      float out = (n == 0) ? s0 : (n == 1) ? s1 : (n == 2) ? s2 : s3;
      yb[(long)(l + n)*256] = out;
    }
  }
}

// two-buffer LN with split-K partial sum (both descriptors batched)
__global__ __launch_bounds__(256) void k_ln2(
  float* __restrict__ hA, const float* __restrict__ hA2,
  float* __restrict__ hB, const float* __restrict__ hB2,
  const void* __restrict__ g, const void* __restrict__ beta,
  const int* __restrict__ flagp)
{
  int fl = *flagp;
  int r = blockIdx.x * 4 + (threadIdx.x >> 6);
  float* hbase = (r < 4096) ? hA : hB;
  const float* h2base = (r < 4096) ? hA2 : hB2;
  int row = r & 4095;
  int lane = threadIdx.x & 63;
  float* hr = hbase + (long)row * 512;
  const float* h2r = h2base + (long)row * 512;
  float v[8]; float s = 0.f, ss = 0.f;
  #pragma unroll
  for (int i = 0; i < 8; ++i){
    v[i] = hr[lane + 64*i] + h2r[lane + 64*i];
    s += v[i]; ss += v[i]*v[i];
  }
  #pragma unroll
  for (int off = 1; off < 64; off <<= 1){ s += __shfl_xor(s, off); ss += __shfl_xor(ss, off); }
  float mean = s * (1.f/512.f);
  float var  = ss * (1.f/512.f) - mean * mean;
  float rs = rsqrtf(var + 1e-5f);
  #pragma unroll
  for (int i = 0; i < 8; ++i){
    int c = lane + 64*i;
    hr[c] = (v[i] - mean) * rs * ldw(g, c, fl) + ldw(beta, c, fl);
  }
}

extern "C" void kernel_launch(void* const* d_in, const int* in_sizes, int n_in,
                              void* d_out, int out_size, void* d_ws, size_t ws_size,
                              hipStream_t stream)
{
  const int B_ = 2, L_ = 2048, H_ = 4;
  const long BLE = (long)B_ * L_ * 256;       // 1,048,576 floats
  const long BHLb = 2L * B_ * H_ * L_;        // 32,768 (batched pseudo-heads)

  int* flagp = (int*)d_ws;
  float* base = (float*)d_ws + 64;

  // ---- workspace map (units of BLE fp32) ----
  float* cat0   = base + 0*BLE;    // 3 BLE, ld 768
  float* cat1   = base + 3*BLE;    // 3 BLE
  float* xz01   = base + 6*BLE;    // 4 BLE, pseudo-b ld 512
  u16*   q01    = (u16*)(base + 10*BLE);
  u16*   k01    = (u16*)(base + 11*BLE);
  u16*   v01    = (u16*)(base + 12*BLE);
  float* Opart  = base + 13*BLE;   // 4 BLE (2 z-planes x 2 BLE batched)
  float* ob01   = base + 21*BLE;   // 2 BLE
  float* mml    = base + 23*BLE;   // 2*32768
  float* mll    = mml + 2*32768;
  float* xc01   = base + 24*BLE;   // 2 BLE
  float* zc01   = base + 26*BLE;   // 2 BLE
  float* xdbl01 = base + 28*BLE;   // 0.5 BLE
  float* delta01= base + 29*BLE;   // 2 BLE (TRANSPOSED 256 x 8192)
  float* dxc01  = base + 31*BLE;   // 2 BLE (TRANSPOSED 256 x 8192)
  float* scE    = base + 33*BLE;
  float* scF    = scE + 524288;
  float* scH    = scF + 524288;
  float* y01    = base + 35*BLE;   // 2 BLE
  float* catc0  = base + 37*BLE;   // 4 BLE, ld 1024
  float* catc1  = base + 41*BLE;   // 4 BLE
  float* h0     = base + 45*BLE;   // 2 BLE, ld 512
  float* part0  = base + 47*BLE;   // 2 BLE
  float* h1     = base + 49*BLE;   // 2 BLE
  float* part1  = base + 51*BLE;   // 2 BLE
  float* dbuf0  = base + 53*BLE;
  float* dbuf1  = base + 54*BLE;
  u16*   qc     = (u16*)(base + 55*BLE);   // cross q/k/v/o bf16, contiguous
  u16*   kc     = qc + 1048576;
  u16*   vc     = kc + 1048576;
  u16*   oc     = vc + 1048576;
  float* catA   = base + 57*BLE;   // 2 BLE, ld 512
  float* catB   = base + 59*BLE;   // 2 BLE
  u16*   px     = (u16*)(base + 61*BLE);   // bf16 padded xproj (64x256)
  u16*   pd     = px + 16384;              // bf16 padded dt_w (256x64)
  float* pb     = (float*)(pd + 16384);    // fp32 dt_b
  u16*   wbuf   = (u16*)(base + 62*BLE);   // pre-converted bf16 weights

  const void* in[35];
  for (int i = 0; i < 35 && i < n_in; ++i) in[i] = d_in[i];

  // ---- bf16 weight buffer layout (element offsets) ----
  const int woff[12] = {
    0,                 // in[4]  qkv_w       768*256
    196608,            // in[14] m_in_w      512*256
    327680,            // in[6]  attn_out_w  256*256
    393216,            // in[8]  ma_ffn_w1   512*1024
    917504,            // in[12] ma_ffn_w2   256*512
    1048576,           // in[22] m_out_w     256*256
    1114112,           // in[23] ca_qk_w     256*256
    1179648,           // in[25] ca_v_w      256*256
    1245184,           // in[27] ca_out_w    256*256
    1310720,           // in[29] ca_ffn_w1   512*512
    1572864,           // in[33] ca_ffn_w2   256*512
    1703936 };
  const u16* wqkv  = wbuf + woff[0];
  const u16* wxz   = wbuf + woff[1];
  const u16* wattn = wbuf + woff[2];
  const u16* wffn1 = wbuf + woff[3];
  const u16* wffn2 = wbuf + woff[4];
  const u16* wout  = wbuf + woff[5];
  const u16* wcqk  = wbuf + woff[6];
  const u16* wcv   = wbuf + woff[7];
  const u16* wcout = wbuf + woff[8];
  const u16* wcf1  = wbuf + woff[9];
  const u16* wcf2  = wbuf + woff[10];

  k_sniff<<<1, 256, 0, stream>>>((const unsigned int*)in[0], 2048, flagp);
  {
    WC wc = {};
    wc.src[0]=in[4]; wc.src[1]=in[14]; wc.src[2]=in[6]; wc.src[3]=in[8];
    wc.src[4]=in[12]; wc.src[5]=in[22]; wc.src[6]=in[23]; wc.src[7]=in[25];
    wc.src[8]=in[27]; wc.src[9]=in[29]; wc.src[10]=in[33];
    for (int t = 0; t < 12; ++t) wc.off[t] = woff[t];
    k_wconv<<<(woff[11] + 255)/256, 256, 0, stream>>>(wc, wbuf, flagp);
  }
  k_pad<<<130, 256, 0, stream>>>(in[17], in[18], in[19], px, pd, pb, flagp);

  const int BIG = 1 << 30;
  const long sbP = (long)H_ * L_ * 64, shP = (long)L_ * 64, slP = 64;
  const long sbF = (long)L_ * 256,     shF = 64,            slF = 256;
  const int NZ = 2;
  const int kchunk = L_ / NZ;          // 1024
  const int MROWS = 4 * L_;            // 8192 (transposed ld)
  const float LOG2E = 1.4426950408889634f;

  // ---------------- batched mamba_attention (both descriptors) ----------------
  // merged qkv + xz; z-batched over descriptors
  k_gemm_mfma<<<dim3(20, 64, 2), 256, 0, stream>>>(
      in[0], 0, 256, 256, 1280, wqkv, wxz, 768, 0, in[5],
      cat0, nullptr, 768, xz01, 512,
      nullptr, 1, 0, nullptr, 1, nullptr, 1.f, 0, 0,
      in[1], 3*BLE, 2*BLE, flagp);
  k_rope<<<dim3(L_/4, 16), 256, 0, stream>>>(cat0, cat1, in[2], in[3],
      q01, k01, v01, L_, B_, H_, flagp);
  k_attn_mfma<<<dim3(L_/64, 16, NZ), 256, 0, stream>>>(
      q01, sbP, shP, slP, k01, sbP, shP, slP, v01, sbP, shP, slP,
      Opart, mml, mll, L_, H_, kchunk, 0);
  k_attn_comb<<<8192, 256, 0, stream>>>(Opart, mml, mll, ob01, BHLb, NZ);
  k_conv2<<<dim3(2*B_*L_, 2), 256, 0, stream>>>(xz01, in[15], in[16], xc01, zc01, L_, flagp);
  // xproj (padded N=64, bf16 weights) into xdbl ld 64; M=8192 both descs
  k_gemm_mfma<<<dim3(1, 128), 256, 0, stream>>>(
      xc01, 1, 256, 256, 64, px, nullptr, BIG, 1, nullptr,
      xdbl01, nullptr, 64, nullptr, 0,
      nullptr, 1, 0, nullptr, 1, nullptr, 1.f, 0, 0,
      nullptr, 0, 0, flagp);
  // dt (padded K=64, bf16 weights, fp32 bias) + fused softplus -> deltaT, dxcT
  k_gemm_mfma<<<dim3(4, 128), 256, 0, stream>>>(
      xdbl01, 1, 64, 64, 256, pd, nullptr, BIG, 1, pb,
      delta01, nullptr, MROWS, dxc01, MROWS,
      xc01, 1, 256, nullptr, 1, nullptr, 1.f, 0, 4,
      nullptr, 0, 0, flagp);
  k_scan1<<<2048, 256, 0, stream>>>(delta01, dxc01, xdbl01, in[20], scE, scF, L_, MROWS, flagp);
  k_scan2<<<64, 256, 0, stream>>>(scE, scF, scH);
  k_scan3<<<2048, 256, 0, stream>>>(delta01, dxc01, xdbl01, in[20], scH, y01, L_, MROWS, flagp);
  // batched s_x / c_x / o-proj (+fused raw-input->cat copy), z=6
  {
    GB8 gb = {};
    gb.dvec = in[21];
    gb.A[0] = y01;        gb.aux[0] = xc01;       gb.W[0] = wout; gb.Cf[0] = catc0 + 512; gb.osc[0] = 1.f; gb.cfl[0] = 1;
    gb.A[1] = zc01;       gb.W[1] = wout; gb.Cf[1] = catc0 + 768; gb.osc[1] = 1.f; gb.cfl[1] = 1;
    gb.A[2] = ob01;       gb.W[2] = wattn; gb.bias[2] = in[7];    gb.Cf[2] = catc0 + 256;
    gb.csrc[2] = in[0];   gb.cdst[2] = catc0; gb.osc[2] = 1.f;    gb.cfl[2] = 0;
    gb.A[3] = y01 + BLE;  gb.aux[3] = xc01 + BLE; gb.W[3] = wout; gb.Cf[3] = catc1 + 512; gb.osc[3] = 1.f; gb.cfl[3] = 1;
    gb.A[4] = zc01 + BLE; gb.W[4] = wout; gb.Cf[4] = catc1 + 768; gb.osc[4] = 1.f; gb.cfl[4] = 1;
    gb.A[5] = ob01 + BLE; gb.W[5] = wattn; gb.bias[5] = in[7];    gb.Cf[5] = catc1 + 256;
    gb.csrc[5] = in[1];   gb.cdst[5] = catc1; gb.osc[5] = 1.f;    gb.cfl[5] = 0;
    k_gemmb<<<dim3(4, 64, 6), 256, 0, stream>>>(gb, 256, 256, 256, 1024, 0, 256, 0, 0, flagp);
  }
  // ffn1 split-K=2 per descriptor (z=4)
  {
    GB8 gb = {};
    gb.cfl[0] = gb.cfl[1] = gb.cfl[2] = gb.cfl[3] = 1;
    gb.A[0] = catc0;       gb.W[0] = wffn1; gb.bias[0] = in[9]; gb.Cf[0] = h0;    gb.osc[0] = 1.f;
    gb.A[1] = catc0 + 512; gb.W[1] = wffn1; gb.wkoff[1] = 512;  gb.Cf[1] = part0; gb.osc[1] = 1.f;
    gb.A[2] = catc1;       gb.W[2] = wffn1; gb.bias[2] = in[9]; gb.Cf[2] = h1;    gb.osc[2] = 1.f;
    gb.A[3] = catc1 + 512; gb.W[3] = wffn1; gb.wkoff[3] = 512;  gb.Cf[3] = part1; gb.osc[3] = 1.f;
    k_gemmb<<<dim3(8, 64, 4), 256, 0, stream>>>(gb, 1024, 512, 512, 512, 0, 1024, 0, 0, flagp);
  }
  k_ln2<<<2048, 256, 0, stream>>>(h0, part0, h1, part1, in[10], in[11], flagp);
  // ffn2: gelu(h) @ W^T + bias + raw-input residual (dtype-aware), z=2
  {
    GB8 gb = {};
    gb.cfl[0] = gb.cfl[1] = 1;
    gb.A[0] = h0; gb.W[0] = wffn2; gb.bias[0] = in[13]; gb.resid[0] = in[0]; gb.rfli[0] = 0;
    gb.Cf[0] = dbuf0; gb.osc[0] = 1.f;
    gb.A[1] = h1; gb.W[1] = wffn2; gb.bias[1] = in[13]; gb.resid[1] = in[1]; gb.rfli[1] = 0;
    gb.Cf[1] = dbuf1; gb.osc[1] = 1.f;
    k_gemmb<<<dim3(4, 64, 2), 256, 0, stream>>>(gb, 512, 512, 256, 256, 256, 512, 1, 0, flagp);
  }

  // ---------------- cross attention (both directions in ONE launch) ----------------
  const float s4 = 0.35355339059327373f;  // 64^-0.25
  float* cm0 = xc01;           // cross comb outputs reuse xc slots (contiguous 2 BLE)
  {
    GB8 gb = {};
    gb.cfl[0] = gb.cfl[1] = gb.cfl[2] = gb.cfl[3] = 1;
    gb.A[0] = dbuf0; gb.W[0] = wcqk; gb.bias[0] = in[24]; gb.Cb[0] = qc; gb.osc[0] = s4 * LOG2E;
    gb.A[1] = dbuf1; gb.W[1] = wcqk; gb.bias[1] = in[24]; gb.Cb[1] = kc; gb.osc[1] = s4;
    gb.A[2] = dbuf0; gb.W[2] = wcv;  gb.bias[2] = in[26]; gb.Cb[2] = vc; gb.osc[2] = 1.f;
    gb.A[3] = dbuf1; gb.W[3] = wcv;  gb.bias[3] = in[26]; gb.Cb[3] = oc; gb.osc[3] = 1.f;
    k_gemmb<<<dim3(4, 64, 4), 256, 0, stream>>>(gb, 256, 256, 256, 256, 0, 256, 0, 3, flagp);
  }
  // pseudo-b 0..3 over contiguous {qc,kc}: Q = qc+b*sbF, K/V index b^2
  k_attn_mfma<<<dim3(L_/64, 16, NZ), 256, 0, stream>>>(
      qc, sbF, shF, slF, qc, sbF, shF, slF, vc, sbF, shF, slF,
      Opart, mml, mll, L_, H_, kchunk, 2);
  k_attn_comb<<<8192, 256, 0, stream>>>(Opart, mml, mll, cm0, BHLb, NZ);
  {
    GB8 gb = {};
    gb.cfl[0] = gb.cfl[1] = 1;
    gb.A[0] = cm0;       gb.W[0] = wcout; gb.bias[0] = in[28]; gb.Cf[0] = catA + 256;
    gb.csrc[0] = dbuf0;  gb.cdst[0] = catA; gb.osc[0] = 1.f;
    gb.A[1] = cm0 + BLE; gb.W[1] = wcout; gb.bias[1] = in[28]; gb.Cf[1] = catB + 256;
    gb.csrc[1] = dbuf1;  gb.cdst[1] = catB; gb.osc[1] = 1.f;
    k_gemmb<<<dim3(4, 64, 2), 256, 0, stream>>>(gb, 256, 256, 256, 512, 0, 256, 0, 0, flagp);
  }
  // ca-ffn1 split-K=2 per descriptor (z=4)
  {
    GB8 gb = {};
    gb.cfl[0] = gb.cfl[1] = gb.cfl[2] = gb.cfl[3] = 1;
    gb.A[0] = catA;       gb.W[0] = wcf1; gb.bias[0] = in[30]; gb.Cf[0] = h0;    gb.osc[0] = 1.f;
    gb.A[1] = catA + 256; gb.W[1] = wcf1; gb.wkoff[1] = 256;   gb.Cf[1] = part0; gb.osc[1] = 1.f;
    gb.A[2] = catB;       gb.W[2] = wcf1; gb.bias[2] = in[30]; gb.Cf[2] = h1;    gb.osc[2] = 1.f;
    gb.A[3] = catB + 256; gb.W[3] = wcf1; gb.wkoff[3] = 256;   gb.Cf[3] = part1; gb.osc[3] = 1.f;
    k_gemmb<<<dim3(8, 64, 4), 256, 0, stream>>>(gb, 512, 256, 512, 512, 0, 512, 0, 0, flagp);
  }
  k_ln2<<<2048, 256, 0, stream>>>(h0, part0, h1, part1, in[31], in[32], flagp);
  {
    GB8 gb = {};
    gb.cfl[0] = gb.cfl[1] = 1;
    gb.rfli[0] = gb.rfli[1] = 1;
    gb.A[0] = h0; gb.W[0] = wcf2; gb.bias[0] = in[34]; gb.resid[0] = dbuf0;
    gb.Cf[0] = (float*)d_out; gb.Cb[0] = (u16*)d_out; gb.osc[0] = 1.f;
    gb.A[1] = h1; gb.W[1] = wcf2; gb.bias[1] = in[34]; gb.resid[1] = dbuf1;
    gb.Cf[1] = (float*)d_out + BLE; gb.Cb[1] = (u16*)d_out + BLE; gb.osc[1] = 1.f;
    k_gemmb<<<dim3(4, 64, 2), 256, 0, stream>>>(gb, 512, 512, 256, 256, 256, 512, 1, 2, flagp);
  }
}

// Round 10
// 606.519 us; speedup vs baseline: 1.3522x; 1.0706x over previous
//
#include <hip/hip_runtime.h>

typedef unsigned short u16;
typedef short s16;
typedef s16 s16x8 __attribute__((ext_vector_type(8)));
typedef float f32x4 __attribute__((ext_vector_type(4)));

__device__ __forceinline__ float bf2f(u16 u){
  union { unsigned int i; float f; } v; v.i = ((unsigned int)u) << 16; return v.f;
}
__device__ __forceinline__ u16 f2bf(float f){
  union { float f; unsigned int u; } v; v.f = f;
  unsigned int r = (v.u + 0x7fffu + ((v.u >> 16) & 1u)) >> 16;
  return (u16)r;
}
// packed f32x2 -> bf16x2 (RNE, identical to f2bf) in ONE VALU op
__device__ __forceinline__ unsigned int cvtpk(float lo, float hi){
  unsigned int d;
  asm("v_cvt_pk_bf16_f32 %0, %1, %2" : "=v"(d) : "v"(lo), "v"(hi));
  return d;
}
__device__ __forceinline__ uint4 pack8(float4 a0, float4 a1){
  uint4 v;
  v.x = cvtpk(a0.x, a0.y); v.y = cvtpk(a0.z, a0.w);
  v.z = cvtpk(a1.x, a1.y); v.w = cvtpk(a1.z, a1.w);
  return v;
}
__device__ __forceinline__ float gelu_f(float x){
  return 0.5f * x * (1.f + erff(x * 0.70710678118654752440f));
}
__device__ __forceinline__ float ldw(const void* p, long i, int fl){
  return fl ? bf2f(((const u16*)p)[i]) : ((const float*)p)[i];
}
__device__ __forceinline__ float4 ldw4(const void* p, long i, int fl){
  if (fl){
    ushort4 w = *(const ushort4*)((const u16*)p + i);
    return make_float4(bf2f(w.x), bf2f(w.y), bf2f(w.z), bf2f(w.w));
  }
  return *(const float4*)((const float*)p + i);
}

// ---- DPP 16-lane butterfly reductions (VALU pipe, zero LDS traffic) ----
template<int C>
__device__ __forceinline__ float dppf(float x){
  return __int_as_float(__builtin_amdgcn_update_dpp(0, __float_as_int(x), C, 0xf, 0xf, true));
}
__device__ __forceinline__ float dppmax16(float v){
  v = fmaxf(v, dppf<0xB1>(v));
  v = fmaxf(v, dppf<0x4E>(v));
  v = fmaxf(v, dppf<0x141>(v));
  v = fmaxf(v, dppf<0x140>(v));
  return v;
}
__device__ __forceinline__ float dppsum16(float v){
  v += dppf<0xB1>(v);
  v += dppf<0x4E>(v);
  v += dppf<0x141>(v);
  v += dppf<0x140>(v);
  return v;
}

// ---------------- dtype sniffer (flag[0]=dtype, flag[1]=0, flag[2]=1) --------
__global__ __launch_bounds__(256) void k_sniff(const unsigned int* __restrict__ w,
                                               int n, int* __restrict__ flag){
  __shared__ int cnt[256];
  int c = 0;
  for (int i = threadIdx.x; i < n; i += 256){
    unsigned e = (w[i] >> 7) & 0xFFu;
    c += (e >= 120u && e <= 127u) ? 1 : 0;
  }
  cnt[threadIdx.x] = c; __syncthreads();
  for (int s = 128; s > 0; s >>= 1){
    if (threadIdx.x < s) cnt[threadIdx.x] += cnt[threadIdx.x + s];
    __syncthreads();
  }
  if (threadIdx.x == 0) flag[0] = (2 * cnt[0] > n) ? 1 : 0;
  if (threadIdx.x == 1) flag[1] = 0;
  if (threadIdx.x == 2) flag[2] = 1;
}

// ---- conversion: 11 weights + 2 inputs -> contiguous bf16 buffer ----
struct WC { const void* src[13]; int off[14]; };
__global__ __launch_bounds__(256) void k_wconv(WC wc, u16* __restrict__ dst,
                                               const int* __restrict__ flagp){
  int fl = *flagp;
  int i = blockIdx.x * 256 + threadIdx.x;
  if (i >= wc.off[13]) return;
  int s = 0;
  #pragma unroll
  for (int t = 1; t < 13; ++t) s += (i >= wc.off[t]) ? 1 : 0;
  dst[i] = f2bf(ldw(wc.src[s], i - wc.off[s], fl));
}

// ---- zero-pad xproj (48x256 -> 64x256) / dt_w (256x16 -> 256x64) -> bf16; dt_b fp32 ----
__global__ __launch_bounds__(256) void k_pad(
  const void* __restrict__ wx, const void* __restrict__ wd,
  const void* __restrict__ bd,
  u16* __restrict__ px, u16* __restrict__ pd, float* __restrict__ pb,
  const int* __restrict__ flagp)
{
  int fl = *flagp;
  int i = blockIdx.x * 256 + threadIdx.x;
  if (i < 16384){
    int r = i >> 8, c = i & 255;
    px[i] = f2bf((r < 48) ? ldw(wx, r*256 + c, fl) : 0.f);
  } else if (i < 32768){
    int j = i - 16384;
    int n = j >> 6, k = j & 63;
    pd[j] = f2bf((k < 16) ? ldw(wd, n*16 + k, fl) : 0.f);
  } else if (i < 33024){
    pb[i - 32768] = ldw(bd, i - 32768, fl);
  }
}

// ---------------- MFMA GEMM (staged 64x64 tile; weights always bf16) ----------------
// outmode: 0 fp32, 2 dynamic, 3 bf16,
//          4 softplus(dt+2*bias) -> Cf TRANSPOSED (d-major), delta*resid -> C2 TRANSPOSED.
// A1/coff1/c2off1: optional z-batch (blockIdx.z==1 uses A1, Cf+coff1, C2+c2off1).
__global__ __launch_bounds__(256) void k_gemm_mfma(
  const void* __restrict__ A0, int aflidx, int lda, int K, int N,
  const u16* __restrict__ W, const u16* __restrict__ W2, int nsplit, int wflidx,
  const void* __restrict__ bias,
  float* __restrict__ Cf0, u16* __restrict__ Cb, int ldc,
  float* __restrict__ C20, int ldc2,
  const void* __restrict__ resid, int rflidx, int ldr,
  float oscale, int act_gelu, int outmode,
  const void* __restrict__ A1, long coff1, long c2off1,
  const int* __restrict__ flagp)
{
  const int fl  = flagp[0];
  const int afl = flagp[aflidx];
  const int wfl = flagp[wflidx];     // bias dtype only
  const int rfl = flagp[rflidx];
  const void* A = A0;
  float* Cf = Cf0;
  float* C2 = C20;
  if (blockIdx.z){ A = A1; Cf += coff1; C2 += c2off1; }
  __shared__ u16 As[64*72];
  __shared__ u16 Bs[64*72];
  const int tid = threadIdx.x;
  const int w = tid >> 6, lane = tid & 63, quad = lane >> 4, m = lane & 15;
  const int m0 = blockIdx.y << 6, n0 = blockIdx.x << 6;
  const int srow = tid >> 2, sc0 = (tid & 3) << 4;
  const int reg2 = (n0 >= nsplit);
  const u16* Wp = reg2 ? W2 : W;
  const int nbase = reg2 ? nsplit : 0;

  f32x4 acc[4];
  #pragma unroll
  for (int ct = 0; ct < 4; ++ct) acc[ct] = (f32x4){0.f,0.f,0.f,0.f};

  for (int k0 = 0; k0 < K; k0 += 64){
    {
      long ab = (long)(m0 + srow) * lda + k0 + sc0;
      if (afl && !act_gelu){
        #pragma unroll
        for (int g = 0; g < 2; ++g)
          *(uint4*)&As[srow*72 + sc0 + g*8] = *(const uint4*)((const u16*)A + ab + g*8);
      } else {
        #pragma unroll
        for (int g = 0; g < 2; ++g){
          float4 a0 = ldw4(A, ab + g*8, afl);
          float4 a1 = ldw4(A, ab + g*8 + 4, afl);
          if (act_gelu){
            a0.x=gelu_f(a0.x); a0.y=gelu_f(a0.y); a0.z=gelu_f(a0.z); a0.w=gelu_f(a0.w);
            a1.x=gelu_f(a1.x); a1.y=gelu_f(a1.y); a1.z=gelu_f(a1.z); a1.w=gelu_f(a1.w);
          }
          *(uint4*)&As[srow*72 + sc0 + g*8] = pack8(a0, a1);
        }
      }
    }
    {
      long wb = (long)(n0 + srow - nbase) * K + k0 + sc0;
      #pragma unroll
      for (int g = 0; g < 2; ++g)
        *(uint4*)&Bs[srow*72 + sc0 + g*8] = *(const uint4*)(Wp + wb + g*8);
    }
    __syncthreads();

    s16x8 av[2];
    #pragma unroll
    for (int s = 0; s < 2; ++s)
      av[s] = *(const s16x8*)&As[(w*16 + m)*72 + s*32 + quad*8];
    #pragma unroll
    for (int ct = 0; ct < 4; ++ct)
      #pragma unroll
      for (int s = 0; s < 2; ++s){
        s16x8 bv = *(const s16x8*)&Bs[(ct*16 + m)*72 + s*32 + quad*8];
        acc[ct] = __builtin_amdgcn_mfma_f32_16x16x32_bf16(av[s], bv, acc[ct], 0, 0, 0);
      }
    __syncthreads();
  }

  if (outmode == 4){
    // transposed float4 stores: acc[ct] = 4 consecutive rows for column gn
    const int gmb = m0 + w*16 + quad*4;
    #pragma unroll
    for (int ct = 0; ct < 4; ++ct){
      int gn = n0 + ct*16 + m;
      float bv = ldw(bias, gn, wfl);
      float dl4[4], dx4[4];
      #pragma unroll
      for (int r = 0; r < 4; ++r){
        float dl = acc[ct][r] + bv + bv;     // dt + 2*dt_bias (ref's double add)
        float delta = (dl > 20.f) ? dl : __logf(1.f + __expf(dl));
        dl4[r] = delta;
        dx4[r] = delta * ldw(resid, (long)(gmb + r) * ldr + gn, rfl);
      }
      *(float4*)&Cf[(long)gn * ldc + gmb] = make_float4(dl4[0], dl4[1], dl4[2], dl4[3]);
      *(float4*)&C2[(long)gn * ldc2 + gmb] = make_float4(dx4[0], dx4[1], dx4[2], dx4[3]);
    }
    return;
  }

  #pragma unroll
  for (int r = 0; r < 4; ++r){
    int gm = m0 + w*16 + quad*4 + r;
    #pragma unroll
    for (int ct = 0; ct < 4; ++ct){
      int gn = n0 + ct*16 + m;
      float v = acc[ct][r];
      if (reg2){
        C2[(long)gm * ldc2 + (gn - nsplit)] = v;
      } else {
        if (bias) v += ldw(bias, gn, wfl);
        v *= oscale;
        if (resid) v += ldw(resid, (long)gm * ldr + gn, rfl);
        long off = (long)gm * ldc + gn;
        if (outmode == 2){
          if (fl) Cb[off] = f2bf(v); else Cf[off] = v;
        } else if (outmode == 3){
          Cb[off] = f2bf(v);
        } else {
          Cf[off] = v;
        }
      }
    }
  }
}

// ---------------- z-batched MFMA GEMM (up to 8 independent problems) ----------------
// Weights always bf16. afli[z]=1: A is bf16 (plain copy path, no aux/gelu).
// outmode: 0 fp32 Cf, 2 dynamic, 3 bf16 Cb, 5 both Cf+Cb. cdst (bf16) copy from csrc.
struct GB8 {
  const void* A[8]; const u16* W[8]; const void* bias[8];
  float* Cf[8]; u16* Cb[8]; const void* resid[8];
  const void* csrc[8]; u16* cdst[8]; float osc[8];
  int cfl[8]; int wkoff[8]; int rfli[8]; int afli[8];
  const float* aux[8]; const void* dvec;
};

__global__ __launch_bounds__(256) void k_gemmb(
  GB8 gb, int lda, int K, int N, int ldc, int ldr, int ldwq,
  int act_gelu, int outmode, const int* __restrict__ flagp)
{
  const int fl = flagp[0];
  const int z = blockIdx.z;
  const void* A = gb.A[z]; const u16* W = gb.W[z]; const void* bias = gb.bias[z];
  float* Cf = gb.Cf[z]; u16* Cb = gb.Cb[z]; const void* resid = gb.resid[z];
  const void* csrc = gb.csrc[z]; u16* cdst = gb.cdst[z];
  const float osc = gb.osc[z];
  const int cfl = flagp[gb.cfl[z]];
  const int rfl = flagp[gb.rfli[z]];
  const int wkoff = gb.wkoff[z];
  const int abf = gb.afli[z];
  const float* aux = gb.aux[z];

  __shared__ u16 As[64*72];
  __shared__ u16 Bs[64*72];
  const int tid = threadIdx.x;
  const int w = tid >> 6, lane = tid & 63, quad = lane >> 4, m = lane & 15;
  const int m0 = blockIdx.y << 6, n0 = blockIdx.x << 6;
  const int srow = tid >> 2, sc0 = (tid & 3) << 4;

  f32x4 acc[4];
  #pragma unroll
  for (int ct = 0; ct < 4; ++ct) acc[ct] = (f32x4){0.f,0.f,0.f,0.f};

  for (int k0 = 0; k0 < K; k0 += 64){
    if (abf){
      const u16* ar = (const u16*)A + (long)(m0 + srow) * lda + k0 + sc0;
      #pragma unroll
      for (int g = 0; g < 2; ++g)
        *(uint4*)&As[srow*72 + sc0 + g*8] = *(const uint4*)(ar + g*8);
    } else {
      const float* ar = (const float*)A + (long)(m0 + srow) * lda + k0 + sc0;
      #pragma unroll
      for (int g = 0; g < 2; ++g){
        float4 a0 = *(const float4*)(ar + g*8);
        float4 a1 = *(const float4*)(ar + g*8 + 4);
        if (aux){
          const float* xr = aux + (long)(m0 + srow) * lda + k0 + sc0;
          float4 x0 = *(const float4*)(xr + g*8);
          float4 x1 = *(const float4*)(xr + g*8 + 4);
          float4 d0 = ldw4(gb.dvec, k0 + sc0 + g*8, fl);
          float4 d1 = ldw4(gb.dvec, k0 + sc0 + g*8 + 4, fl);
          a0.x += d0.x*x0.x; a0.y += d0.y*x0.y; a0.z += d0.z*x0.z; a0.w += d0.w*x0.w;
          a1.x += d1.x*x1.x; a1.y += d1.y*x1.y; a1.z += d1.z*x1.z; a1.w += d1.w*x1.w;
        }
        if (act_gelu){
          a0.x=gelu_f(a0.x); a0.y=gelu_f(a0.y); a0.z=gelu_f(a0.z); a0.w=gelu_f(a0.w);
          a1.x=gelu_f(a1.x); a1.y=gelu_f(a1.y); a1.z=gelu_f(a1.z); a1.w=gelu_f(a1.w);
        }
        *(uint4*)&As[srow*72 + sc0 + g*8] = pack8(a0, a1);
      }
    }
    {
      long wb = (long)(n0 + srow) * ldwq + wkoff + k0 + sc0;
      #pragma unroll
      for (int g = 0; g < 2; ++g)
        *(uint4*)&Bs[srow*72 + sc0 + g*8] = *(const uint4*)(W + wb + g*8);
    }
    __syncthreads();

    s16x8 av[2];
    #pragma unroll
    for (int s = 0; s < 2; ++s)
      av[s] = *(const s16x8*)&As[(w*16 + m)*72 + s*32 + quad*8];
    #pragma unroll
    for (int ct = 0; ct < 4; ++ct)
      #pragma unroll
      for (int s = 0; s < 2; ++s){
        s16x8 bv = *(const s16x8*)&Bs[(ct*16 + m)*72 + s*32 + quad*8];
        acc[ct] = __builtin_amdgcn_mfma_f32_16x16x32_bf16(av[s], bv, acc[ct], 0, 0, 0);
      }
    __syncthreads();
  }

  #pragma unroll
  for (int r = 0; r < 4; ++r){
    int gm = m0 + w*16 + quad*4 + r;
    #pragma unroll
    for (int ct = 0; ct < 4; ++ct){
      int gn = n0 + ct*16 + m;
      float v = acc[ct][r];
      if (bias) v += ldw(bias, gn, fl);
      v *= osc;
      if (resid) v += ldw(resid, (long)gm * ldr + gn, rfl);
      long off = (long)gm * ldc + gn;
      if (outmode == 2){
        if (fl) Cb[off] = f2bf(v); else Cf[off] = v;
      } else if (outmode == 3){
        Cb[off] = f2bf(v);
      } else if (outmode == 5){
        Cf[off] = v; Cb[off] = f2bf(v);
      } else {
        Cf[off] = v;
      }
      if (cdst) cdst[(long)gm * ldc + gn] = f2bf(ldw(csrc, (long)gm * 256 + gn, cfl));
    }
  }
}

// ---------------- QKV extract + rotary, 2-descriptor batched --------------
// grid.y = 16: bh = dsc*8 + b*4 + h. Output bf16 head-major (bh,L,64).
// q pre-scaled by 0.125*log2(e): scores land in log2 domain (exp2 softmax).
__global__ __launch_bounds__(256) void k_rope(
  const float* __restrict__ qkv0, const float* __restrict__ qkv1,
  const void* __restrict__ pe0, const void* __restrict__ pe1,
  u16* __restrict__ q, u16* __restrict__ k, u16* __restrict__ v,
  int L, int B, int H, const int* __restrict__ flagp)
{
  int fl = *flagp;
  int tid = threadIdx.x;
  int lq = tid >> 6, d = tid & 63;
  int l = blockIdx.x * 4 + lq;
  int bh = blockIdx.y;
  int dsc = bh >> 3;
  int bh7 = bh & 7;
  int b = bh7 >> 2, h = bh7 & 3;
  const float* qkv = dsc ? qkv1 : qkv0;
  const void* pe = dsc ? pe1 : pe0;
  const float* row = qkv + ((long)b * L + l) * 768 + h * 192;
  float qv = row[d*3+0], kv = row[d*3+1], vv = row[d*3+2];
  int dn = (d & 1) ? (d - 1) : (d + 1);
  float qn = row[dn*3+0], kn = row[dn*3+1];
  float rq = (d & 1) ? qn : -qn;
  float rk = (d & 1) ? kn : -kn;
  long peo = ((long)b * L + l) * 64 + d;
  float p0 = ldw(pe, peo, fl);
  float p1 = ldw(pe, (long)B * L * 64 + peo, fl);
  long o = ((long)bh * L + l) * 64 + d;
  q[o] = f2bf((qv * p0 + rq * p1) * 0.18033688011112042f);  // 0.125 * log2(e)
  k[o] = f2bf(kv * p0 + rk * p1);
  v[o] = f2bf(vv);
}

// ---------------- MFMA flash attention, bf16 in / fp32 partials out ------
// Scores in log2 domain (exp2 softmax). K-split via blockIdx.z (NZ=2).
// bxor: K/V batch index = b^bxor (enables batching both cross directions).
__global__ __launch_bounds__(256, 8) void k_attn_mfma(
  const u16* __restrict__ Q, long qsb, long qsh, long qsl,
  const u16* __restrict__ Kp, long ksb, long ksh, long ksl,
  const u16* __restrict__ Vp, long vsb, long vsh, long vsl,
  float* __restrict__ Opart, float* __restrict__ mpart, float* __restrict__ lpart,
  int L, int H, int kchunk, int bxor)
{
  __shared__ u16 Kt[64*72];
  __shared__ u16 Vt[64*72];
  __shared__ u16 Ps[64*72];     // wave-private rows: no barrier needed around it
  const int tid  = threadIdx.x;
  const int w    = tid >> 6;
  const int lane = tid & 63;
  const int quad = lane >> 4;
  const int m    = lane & 15;
  const int bh = blockIdx.y, b = bh / H, h = bh % H;
  const int iq0 = blockIdx.x * 64;
  const int z = blockIdx.z;
  const long BHL = (long)gridDim.y * L;

  const u16* Qb = Q  + (long)b*qsb + h*qsh;
  const u16* Kb = Kp + (long)(b^bxor)*ksb + h*ksh;
  const u16* Vb = Vp + (long)(b^bxor)*vsb + h*vsh;

  s16x8 aq[2];
  {
    const u16* qr = Qb + (long)(iq0 + w*16 + m) * qsl + quad*8;
    aq[0] = *(const s16x8*)(qr);
    aq[1] = *(const s16x8*)(qr + 32);
  }

  f32x4 o_acc[4];
  #pragma unroll
  for (int nt = 0; nt < 4; ++nt) o_acc[nt] = (f32x4){0.f,0.f,0.f,0.f};
  float mrow[4] = {-1e30f,-1e30f,-1e30f,-1e30f};
  float lrow[4] = {0.f,0.f,0.f,0.f};

  const int srow = tid >> 2, sc0 = (tid & 3) << 4;
  const int kg = tid & 15;
  const int dg = tid >> 4;
  const int vcb = ((((dg >> 2) * 2) + (kg >> 1)) & 7) * 8 + (kg & 1) * 4;
  const int modd = m & 1;
  const int pcolb = m & 6;
  const int jend = z * kchunk + kchunk;

  for (int j0 = z * kchunk; j0 < jend; j0 += 64){
    {
      const u16* kr = Kb + (long)(j0 + srow) * ksl + sc0;
      *(uint4*)&Kt[srow*72 + sc0]     = *(const uint4*)kr;
      *(uint4*)&Kt[srow*72 + sc0 + 8] = *(const uint4*)(kr + 8);
      const u16* vr = Vb + (long)(j0 + 4*kg) * vsl + 4*dg;
      ushort4 r0 = *(const ushort4*)(vr);
      ushort4 r1 = *(const ushort4*)(vr + vsl);
      ushort4 r2 = *(const ushort4*)(vr + 2*vsl);
      ushort4 r3 = *(const ushort4*)(vr + 3*vsl);
      u16* vt = &Vt[(4*dg)*72 + vcb];
      *(ushort4*)(vt)       = make_ushort4(r0.x, r1.x, r2.x, r3.x);
      *(ushort4*)(vt + 72)  = make_ushort4(r0.y, r1.y, r2.y, r3.y);
      *(ushort4*)(vt + 144) = make_ushort4(r0.z, r1.z, r2.z, r3.z);
      *(ushort4*)(vt + 216) = make_ushort4(r0.w, r1.w, r2.w, r3.w);
    }
    __syncthreads();

    float sv[4][4];
    #pragma unroll
    for (int ct = 0; ct < 4; ++ct){
      f32x4 acc = (f32x4){0.f,0.f,0.f,0.f};
      #pragma unroll
      for (int s = 0; s < 2; ++s){
        s16x8 bk = *(const s16x8*)&Kt[(ct*16 + m)*72 + s*32 + quad*8];
        acc = __builtin_amdgcn_mfma_f32_16x16x32_bf16(aq[s], bk, acc, 0, 0, 0);
      }
      #pragma unroll
      for (int r = 0; r < 4; ++r) sv[ct][r] = acc[r];
    }

    // tile max per row; defer-max: only rescale when growth > THR=8 (log2 units)
    float v0s[4];
    int need = 0;
    #pragma unroll
    for (int r = 0; r < 4; ++r){
      float v0 = fmaxf(fmaxf(sv[0][r], sv[1][r]), fmaxf(sv[2][r], sv[3][r]));
      v0 = dppmax16(v0);
      v0s[r] = v0;
      need |= (v0 > mrow[r] + 8.f) ? 1 : 0;
    }
    if (__any(need)){
      float alpha[4];
      #pragma unroll
      for (int r = 0; r < 4; ++r){
        float mn = fmaxf(mrow[r], v0s[r]);
        alpha[r] = exp2f(mrow[r] - mn);
        mrow[r] = mn;
        lrow[r] *= alpha[r];
      }
      #pragma unroll
      for (int nt = 0; nt < 4; ++nt)
        #pragma unroll
        for (int r = 0; r < 4; ++r) o_acc[nt][r] *= alpha[r];
    }
    float rsum[4] = {0.f,0.f,0.f,0.f};
    #pragma unroll
    for (int ct = 0; ct < 4; ++ct)
      #pragma unroll
      for (int r = 0; r < 4; ++r){
        float p = exp2f(sv[ct][r] - mrow[r]);
        sv[ct][r] = p;
        rsum[r] += p;
      }
    #pragma unroll
    for (int r = 0; r < 4; ++r)
      lrow[r] += dppsum16(rsum[r]);

    // Ps packed b32 writes (DPP xor1 pair exchange + cvt_pk)
    #pragma unroll
    for (int ct = 0; ct < 4; ++ct){
      const int kb = (2*w + 2*ct + (m >> 3)) & 7;
      const int col = (kb << 3) | pcolb;
      #pragma unroll
      for (int rr = 0; rr < 2; ++rr){
        float nb_lo = dppf<0xB1>(sv[ct][rr]);
        float nb_hi = dppf<0xB1>(sv[ct][2+rr]);
        float lo = modd ? nb_hi       : sv[ct][rr];
        float hi = modd ? sv[ct][2+rr] : nb_lo;
        unsigned int pk = cvtpk(lo, hi);
        int row = w*16 + quad*4 + rr + 2*modd;
        *(unsigned int*)&Ps[row*72 + col] = pk;
      }
    }
    asm volatile("s_waitcnt lgkmcnt(0)" ::: "memory");  // own-wave rows RAW

    s16x8 ap[2];
    #pragma unroll
    for (int s = 0; s < 2; ++s)
      ap[s] = *(const s16x8*)&Ps[(w*16 + m)*72 + (((2*w + 4*s + quad) & 7) << 3)];
    #pragma unroll
    for (int nt = 0; nt < 4; ++nt)
      #pragma unroll
      for (int s = 0; s < 2; ++s){
        s16x8 bv = *(const s16x8*)&Vt[(nt*16 + m)*72 + (((2*nt + 4*s + quad) & 7) << 3)];
        o_acc[nt] = __builtin_amdgcn_mfma_f32_16x16x32_bf16(ap[s], bv, o_acc[nt], 0, 0, 0);
      }
    __syncthreads();
  }

  const long zOoff = (long)z * BHL * 64;
  #pragma unroll
  for (int r = 0; r < 4; ++r){
    int iq = iq0 + w*16 + quad*4 + r;
    long rowid = ((long)b*L + iq) * H + h;
    #pragma unroll
    for (int nt = 0; nt < 4; ++nt)
      Opart[zOoff + rowid*64 + nt*16 + m] = o_acc[nt][r];
    if (m == 0){
      mpart[(long)z*BHL + rowid] = mrow[r];
      lpart[(long)z*BHL + rowid] = lrow[r];
    }
  }
}

// ---------------- attention split combine (nz-way, log2-domain m; bf16 out) --------
__global__ __launch_bounds__(256) void k_attn_comb(
  const float* Opart, const float* mpart, const float* lpart,
  u16* O, long BHL, int nz)
{
  long i = (long)blockIdx.x * 256 + threadIdx.x;
  long row = i >> 6;
  float mv[4];
  float M = -1e30f;
  for (int z = 0; z < nz; ++z){
    mv[z] = mpart[(long)z*BHL + row];
    M = fmaxf(M, mv[z]);
  }
  long N64 = BHL * 64;
  float T = 0.f, acc = 0.f;
  for (int z = 0; z < nz; ++z){
    float wz = exp2f(mv[z] - M);
    T   += lpart[(long)z*BHL + row] * wz;
    acc += Opart[(long)z*N64 + i] * wz;
  }
  O[i] = f2bf(acc / T);
}

// ---------------- depthwise conv K=5 SAME + silu (batched pseudo-b) ------
// x path: fp32 + bf16 outputs; z path: bf16 only.
__global__ __launch_bounds__(256) void k_conv2(
  const float* __restrict__ xz,
  const void* __restrict__ wx, const void* __restrict__ wz,
  float* __restrict__ outxf, u16* __restrict__ outxb, u16* __restrict__ outzb,
  int L, const int* __restrict__ flagp)
{
  int fl = *flagp;
  int c = threadIdx.x;
  int bl = blockIdx.x; int b = bl / L, l = bl % L;
  int choff = blockIdx.y ? 256 : 0;
  const void* w = blockIdx.y ? wz : wx;
  const float* base = xz + ((long)b * L) * 512 + choff + c;
  float s = 0.f;
  #pragma unroll
  for (int kk = 0; kk < 5; ++kk){
    int ll = l + kk - 2;
    if (ll >= 0 && ll < L) s += base[(long)ll * 512] * ldw(w, c*5 + kk, fl);
  }
  s = s / (1.f + __expf(-s));   // silu
  long idx = ((long)b * L + l) * 256 + c;
  if (blockIdx.y){
    outzb[idx] = f2bf(s);
  } else {
    outxf[idx] = s;
    outxb[idx] = f2bf(s);
  }
}

// ---------------- chunk-parallel selective scan ----------------
#define SC_CS 64
#define SC_NC 32

__global__ __launch_bounds__(256) void k_scan1(
  const float* __restrict__ deltaT, const float* __restrict__ dxcT,
  const float* __restrict__ xdbl, const void* __restrict__ Alog,
  float* __restrict__ E_out, float* __restrict__ F_out,
  int L, int ldt, const int* __restrict__ flagp)
{
  int fl = *flagp;
  int tid = threadIdx.x;
  int g = tid >> 4, n = tid & 15;
  int gid = blockIdx.x * 16 + g;
  int chunk = gid & (SC_NC - 1);
  int p = gid >> 5;
  int b = p >> 8, d = p & 255;
  float A = -__expf(ldw(Alog, d*16 + n, fl));
  const float* dTp = deltaT + (long)d*ldt + (long)b*L;
  const float* dxp = dxcT  + (long)d*ldt + (long)b*L;
  const float* xdb = xdbl + (long)b*L*64;
  int l0 = chunk * SC_CS;
  float E = 1.f, F = 0.f;
  for (int i = 0; i < SC_CS; i += 4){
    int l = l0 + i;
    float4 dt4 = *(const float4*)(dTp + l);
    float4 dx4 = *(const float4*)(dxp + l);
    float e[4], u[4];
    e[0] = __expf(dt4.x * A); e[1] = __expf(dt4.y * A);
    e[2] = __expf(dt4.z * A); e[3] = __expf(dt4.w * A);
    u[0] = dx4.x * xdb[(l+0)*64 + 16 + n];
    u[1] = dx4.y * xdb[(l+1)*64 + 16 + n];
    u[2] = dx4.z * xdb[(l+2)*64 + 16 + n];
    u[3] = dx4.w * xdb[(l+3)*64 + 16 + n];
    F = e[0]*F + u[0]; F = e[1]*F + u[1];
    F = e[2]*F + u[2]; F = e[3]*F + u[3];
    E *= (e[0]*e[1]) * (e[2]*e[3]);
  }
  long idx = (long)(p*16 + n) * SC_NC + chunk;
  E_out[idx] = E; F_out[idx] = F;
}

__global__ __launch_bounds__(256) void k_scan2(
  const float* __restrict__ E, const float* __restrict__ F,
  float* __restrict__ Hin)
{
  int pn = blockIdx.x * 256 + threadIdx.x;
  const float* Ep = E + (long)pn * SC_NC;
  const float* Fp = F + (long)pn * SC_NC;
  float* Hp = Hin + (long)pn * SC_NC;
  float h = 0.f;
  #pragma unroll
  for (int c = 0; c < SC_NC; ++c){
    Hp[c] = h;
    h = Ep[c] * h + Fp[c];
  }
}

// y = scan partial only (D*xc folded into o-proj GEMM A-staging)
__global__ __launch_bounds__(256) void k_scan3(
  const float* __restrict__ deltaT, const float* __restrict__ dxcT,
  const float* __restrict__ xdbl, const void* __restrict__ Alog,
  const float* __restrict__ Hin, float* __restrict__ y,
  int L, int ldt, const int* __restrict__ flagp)
{
  int fl = *flagp;
  int tid = threadIdx.x;
  int g = tid >> 4, n = tid & 15;
  int gid = blockIdx.x * 16 + g;
  int chunk = gid & (SC_NC - 1);
  int p = gid >> 5;
  int b = p >> 8, d = p & 255;
  float A = -__expf(ldw(Alog, d*16 + n, fl));
  const float* dTp = deltaT + (long)d*ldt + (long)b*L;
  const float* dxp = dxcT  + (long)d*ldt + (long)b*L;
  const float* xdb = xdbl + (long)b*L*64;
  float* yb = y + (long)b*L*256 + d;
  long idx = (long)(p*16 + n) * SC_NC + chunk;
  float h = Hin[idx];
  int l0 = chunk * SC_CS;
  for (int i = 0; i < SC_CS; i += 4){
    int l = l0 + i;
    float4 dt4 = *(const float4*)(dTp + l);
    float4 dx4 = *(const float4*)(dxp + l);
    float e[4], u[4], cm[4];
    e[0] = __expf(dt4.x * A); e[1] = __expf(dt4.y * A);
    e[2] = __expf(dt4.z * A); e[3] = __expf(dt4.w * A);
    u[0] = dx4.x * xdb[(l+0)*64 + 16 + n];
    u[1] = dx4.y * xdb[(l+1)*64 + 16 + n];
    u[2] = dx4.z * xdb[(l+2)*64 + 16 + n];
    u[3] = dx4.w * xdb[(l+3)*64 + 16 + n];
    cm[0] = xdb[(l+0)*64 + 32 + n];
    cm[1] = xdb[(l+1)*64 + 32 + n];
    cm[2] = xdb[(l+2)*64 + 32 + n];
    cm[3] = xdb[(l+3)*64 + 32 + n];
    float s0, s1, s2, s3;
    h = e[0]*h + u[0]; s0 = h * cm[0];
    h = e[1]*h + u[1]; s1 = h * cm[1];
    h = e[2]*h + u[2]; s2 = h * cm[2];
    h = e[3]*h + u[3]; s3 = h * cm[3];
    s0 += __shfl_xor(s0, 1, 16); s1 += __shfl_xor(s1, 1, 16);
    s2 += __shfl_xor(s2, 1, 16); s3 += __shfl_xor(s3, 1, 16);
    s0 += __shfl_xor(s0, 2, 16); s1 += __shfl_xor(s1, 2, 16);
    s2 += __shfl_xor(s2, 2, 16); s3 += __shfl_xor(s3, 2, 16);
    s0 += __shfl_xor(s0, 4, 16); s1 += __shfl_xor(s1, 4, 16);
    s2 += __shfl_xor(s2, 4, 16); s3 += __shfl_xor(s3, 4, 16);
    s0 += __shfl_xor(s0, 8, 16); s1 += __shfl_xor(s1, 8, 16);
    s2 += __shfl_xor(s2, 8, 16); s3 += __shfl_xor(s3, 8, 16);
    if (n < 4){
      float out = (n == 0) ? s0 : (n == 1) ? s1 : (n == 2) ? s2 : s3;
      yb[(long)(l + n)*256] = out;
    }
  }
}

// two-buffer LN with split-K partial sum (both descriptors batched)
__global__ __launch_bounds__(256) void k_ln2(
  float* __restrict__ hA, const float* __restrict__ hA2,
  float* __restrict__ hB, const float* __restrict__ hB2,
  const void* __restrict__ g, const void* __restrict__ beta,
  const int* __restrict__ flagp)
{
  int fl = *flagp;
  int r = blockIdx.x * 4 + (threadIdx.x >> 6);
  float* hbase = (r < 4096) ? hA : hB;
  const float* h2base = (r < 4096) ? hA2 : hB2;
  int row = r & 4095;
  int lane = threadIdx.x & 63;
  float* hr = hbase + (long)row * 512;
  const float* h2r = h2base + (long)row * 512;
  float v[8]; float s = 0.f, ss = 0.f;
  #pragma unroll
  for (int i = 0; i < 8; ++i){
    v[i] = hr[lane + 64*i] + h2r[lane + 64*i];
    s += v[i]; ss += v[i]*v[i];
  }
  #pragma unroll
  for (int off = 1; off < 64; off <<= 1){ s += __shfl_xor(s, off); ss += __shfl_xor(ss, off); }
  float mean = s * (1.f/512.f);
  float var  = ss * (1.f/512.f) - mean * mean;
  float rs = rsqrtf(var + 1e-5f);
  #pragma unroll
  for (int i = 0; i < 8; ++i){
    int c = lane + 64*i;
    hr[c] = (v[i] - mean) * rs * ldw(g, c, fl) + ldw(beta, c, fl);
  }
}

extern "C" void kernel_launch(void* const* d_in, const int* in_sizes, int n_in,
                              void* d_out, int out_size, void* d_ws, size_t ws_size,
                              hipStream_t stream)
{
  const int B_ = 2, L_ = 2048, H_ = 4;
  const long BLE = (long)B_ * L_ * 256;       // 1,048,576 floats
  const long BHLb = 2L * B_ * H_ * L_;        // 32,768 (batched pseudo-heads)

  int* flagp = (int*)d_ws;
  float* base = (float*)d_ws + 64;

  // ---- workspace map (units of BLE fp32) ----
  float* cat0   = base + 0*BLE;    // 3 BLE, ld 768 (fp32; k_rope reads)
  float* cat1   = base + 3*BLE;
  float* xz01   = base + 6*BLE;    // 4 BLE fp32, pseudo-b ld 512
  u16*   q01    = (u16*)(base + 10*BLE);
  u16*   k01    = (u16*)(base + 11*BLE);
  u16*   v01    = (u16*)(base + 12*BLE);
  float* Opart  = base + 13*BLE;   // 4 BLE (2 z-planes x 2 BLE batched)
  u16*   obb    = (u16*)(base + 17*BLE);   // attn comb out bf16 (2M u16)
  float* mml    = base + 18*BLE;   // 2*32768
  float* mll    = mml + 2*32768;
  float* xc_f   = base + 19*BLE;   // 2 BLE fp32 (aux + dt resid)
  u16*   xcb    = (u16*)(base + 21*BLE);   // bf16 xc (xproj A)
  u16*   zcb    = (u16*)(base + 22*BLE);   // bf16 zc (o-proj A)
  float* xdbl01 = base + 23*BLE;   // 0.5 BLE
  float* delta01= base + 24*BLE;   // 2 BLE (TRANSPOSED 256 x 8192)
  float* dxc01  = base + 26*BLE;   // 2 BLE (TRANSPOSED)
  float* scE    = base + 28*BLE;
  float* scF    = scE + 524288;
  float* scH    = scF + 524288;
  float* y01    = base + 30*BLE;   // 2 BLE fp32
  u16*   catc0b = (u16*)(base + 32*BLE);   // bf16 cat (4096 x 1024) 2 BLE
  u16*   catc1b = (u16*)(base + 34*BLE);
  float* h0     = base + 36*BLE;   // 2 BLE fp32 (4096 x 512)
  float* part0  = base + 38*BLE;
  float* h1     = base + 40*BLE;
  float* part1  = base + 42*BLE;
  float* dbuf0  = base + 44*BLE;   // fp32 (resid / csrc)
  float* dbuf1  = base + 45*BLE;
  u16*   dbuf0b = (u16*)(base + 46*BLE);   // bf16 copies (cross-qkv A)
  u16*   dbuf1b = dbuf0b + 1048576;
  u16*   qc     = (u16*)(base + 47*BLE);   // cross q/k/v/o bf16, contiguous
  u16*   kc     = qc + 1048576;
  u16*   vc     = kc + 1048576;
  u16*   oc     = vc + 1048576;
  u16*   cm     = (u16*)(base + 49*BLE);   // cross comb out bf16 (2M u16)
  u16*   catAb  = (u16*)(base + 50*BLE);   // bf16 (4096 x 512) 1 BLE
  u16*   catBb  = (u16*)(base + 51*BLE);
  u16*   px     = (u16*)(base + 52*BLE);
  u16*   pd     = px + 16384;
  float* pb     = (float*)(pd + 16384);
  u16*   wbuf   = (u16*)(base + 53*BLE);   // bf16 weights + inputs (3.8M u16 = 2 BLE)

  const void* in[35];
  for (int i = 0; i < 35 && i < n_in; ++i) in[i] = d_in[i];

  // ---- bf16 buffer layout (element offsets): 11 weights + 2 inputs ----
  const int woff[14] = {
    0,        // in[4]  qkv_w       768*256
    196608,   // in[14] m_in_w      512*256
    327680,   // in[6]  attn_out_w  256*256
    393216,   // in[8]  ma_ffn_w1   512*1024
    917504,   // in[12] ma_ffn_w2   256*512
    1048576,  // in[22] m_out_w     256*256
    1114112,  // in[23] ca_qk_w     256*256
    1179648,  // in[25] ca_v_w      256*256
    1245184,  // in[27] ca_out_w    256*256
    1310720,  // in[29] ca_ffn_w1   512*512
    1572864,  // in[33] ca_ffn_w2   256*512
    1703936,  // in[0]  desc0       B*L*256
    2752512,  // in[1]  desc1
    3801088 };
  const u16* wqkv  = wbuf + woff[0];
  const u16* wxz   = wbuf + woff[1];
  const u16* wattn = wbuf + woff[2];
  const u16* wffn1 = wbuf + woff[3];
  const u16* wffn2 = wbuf + woff[4];
  const u16* wout  = wbuf + woff[5];
  const u16* wcqk  = wbuf + woff[6];
  const u16* wcv   = wbuf + woff[7];
  const u16* wcout = wbuf + woff[8];
  const u16* wcf1  = wbuf + woff[9];
  const u16* wcf2  = wbuf + woff[10];
  const u16* bin0  = wbuf + woff[11];
  const u16* bin1  = wbuf + woff[12];

  k_sniff<<<1, 256, 0, stream>>>((const unsigned int*)in[0], 2048, flagp);
  {
    WC wc = {};
    wc.src[0]=in[4]; wc.src[1]=in[14]; wc.src[2]=in[6]; wc.src[3]=in[8];
    wc.src[4]=in[12]; wc.src[5]=in[22]; wc.src[6]=in[23]; wc.src[7]=in[25];
    wc.src[8]=in[27]; wc.src[9]=in[29]; wc.src[10]=in[33];
    wc.src[11]=in[0]; wc.src[12]=in[1];
    for (int t = 0; t < 14; ++t) wc.off[t] = woff[t];
    k_wconv<<<(woff[13] + 255)/256, 256, 0, stream>>>(wc, wbuf, flagp);
  }
  k_pad<<<130, 256, 0, stream>>>(in[17], in[18], in[19], px, pd, pb, flagp);

  const int BIG = 1 << 30;
  const long sbP = (long)H_ * L_ * 64, shP = (long)L_ * 64, slP = 64;
  const long sbF = (long)L_ * 256,     shF = 64,            slF = 256;
  const int NZ = 2;
  const int kchunk = L_ / NZ;          // 1024
  const int MROWS = 4 * L_;            // 8192 (transposed ld)
  const float LOG2E = 1.4426950408889634f;

  // ---------------- batched mamba_attention (both descriptors) ----------------
  // merged qkv + xz; z-batched over descriptors; A = bf16 inputs (copy path)
  k_gemm_mfma<<<dim3(20, 64, 2), 256, 0, stream>>>(
      bin0, 2, 256, 256, 1280, wqkv, wxz, 768, 0, in[5],
      cat0, nullptr, 768, xz01, 512,
      nullptr, 1, 0, 1.f, 0, 0,
      bin1, 3*BLE, 2*BLE, flagp);
  k_rope<<<dim3(L_/4, 16), 256, 0, stream>>>(cat0, cat1, in[2], in[3],
      q01, k01, v01, L_, B_, H_, flagp);
  k_attn_mfma<<<dim3(L_/64, 16, NZ), 256, 0, stream>>>(
      q01, sbP, shP, slP, k01, sbP, shP, slP, v01, sbP, shP, slP,
      Opart, mml, mll, L_, H_, kchunk, 0);
  k_attn_comb<<<8192, 256, 0, stream>>>(Opart, mml, mll, obb, BHLb, NZ);
  k_conv2<<<dim3(2*B_*L_, 2), 256, 0, stream>>>(xz01, in[15], in[16], xc_f, xcb, zcb, L_, flagp);
  // xproj (padded N=64) A = bf16 xc; output xdbl fp32
  k_gemm_mfma<<<dim3(1, 128), 256, 0, stream>>>(
      xcb, 2, 256, 256, 64, px, nullptr, BIG, 1, nullptr,
      xdbl01, nullptr, 64, nullptr, 0,
      nullptr, 1, 0, 1.f, 0, 0,
      nullptr, 0, 0, flagp);
  // dt (padded K=64, fp32 bias, fp32 resid=xc_f) + fused softplus -> deltaT, dxcT
  k_gemm_mfma<<<dim3(4, 128), 256, 0, stream>>>(
      xdbl01, 1, 64, 64, 256, pd, nullptr, BIG, 1, pb,
      delta01, nullptr, MROWS, dxc01, MROWS,
      xc_f, 1, 256, 1.f, 0, 4,
      nullptr, 0, 0, flagp);
  k_scan1<<<2048, 256, 0, stream>>>(delta01, dxc01, xdbl01, in[20], scE, scF, L_, MROWS, flagp);
  k_scan2<<<64, 256, 0, stream>>>(scE, scF, scH);
  k_scan3<<<2048, 256, 0, stream>>>(delta01, dxc01, xdbl01, in[20], scH, y01, L_, MROWS, flagp);
  // batched s_x / c_x / o-proj (+fused raw-input copy), z=6; bf16 cat out
  {
    GB8 gb = {};
    gb.dvec = in[21];
    gb.A[0] = y01;        gb.aux[0] = xc_f;       gb.W[0] = wout; gb.Cb[0] = catc0b + 512; gb.osc[0] = 1.f; gb.cfl[0] = 1;
    gb.A[1] = zcb;        gb.afli[1] = 1;         gb.W[1] = wout; gb.Cb[1] = catc0b + 768; gb.osc[1] = 1.f; gb.cfl[1] = 1;
    gb.A[2] = obb;        gb.afli[2] = 1;         gb.W[2] = wattn; gb.bias[2] = in[7];     gb.Cb[2] = catc0b + 256;
    gb.csrc[2] = in[0];   gb.cdst[2] = catc0b;    gb.osc[2] = 1.f; gb.cfl[2] = 0;
    gb.A[3] = y01 + BLE;  gb.aux[3] = xc_f + BLE; gb.W[3] = wout; gb.Cb[3] = catc1b + 512; gb.osc[3] = 1.f; gb.cfl[3] = 1;
    gb.A[4] = zcb + 1048576; gb.afli[4] = 1;      gb.W[4] = wout; gb.Cb[4] = catc1b + 768; gb.osc[4] = 1.f; gb.cfl[4] = 1;
    gb.A[5] = obb + 1048576; gb.afli[5] = 1;      gb.W[5] = wattn; gb.bias[5] = in[7];     gb.Cb[5] = catc1b + 256;
    gb.csrc[5] = in[1];   gb.cdst[5] = catc1b;    gb.osc[5] = 1.f; gb.cfl[5] = 0;
    k_gemmb<<<dim3(4, 64, 6), 256, 0, stream>>>(gb, 256, 256, 256, 1024, 0, 256, 0, 3, flagp);
  }
  // ffn1 split-K=2 per descriptor (z=4); A = bf16 catc
  {
    GB8 gb = {};
    gb.cfl[0] = gb.cfl[1] = gb.cfl[2] = gb.cfl[3] = 1;
    gb.afli[0] = gb.afli[1] = gb.afli[2] = gb.afli[3] = 1;
    gb.A[0] = catc0b;       gb.W[0] = wffn1; gb.bias[0] = in[9]; gb.Cf[0] = h0;    gb.osc[0] = 1.f;
    gb.A[1] = catc0b + 512; gb.W[1] = wffn1; gb.wkoff[1] = 512;  gb.Cf[1] = part0; gb.osc[1] = 1.f;
    gb.A[2] = catc1b;       gb.W[2] = wffn1; gb.bias[2] = in[9]; gb.Cf[2] = h1;    gb.osc[2] = 1.f;
    gb.A[3] = catc1b + 512; gb.W[3] = wffn1; gb.wkoff[3] = 512;  gb.Cf[3] = part1; gb.osc[3] = 1.f;
    k_gemmb<<<dim3(8, 64, 4), 256, 0, stream>>>(gb, 1024, 512, 512, 512, 0, 1024, 0, 0, flagp);
  }
  k_ln2<<<2048, 256, 0, stream>>>(h0, part0, h1, part1, in[10], in[11], flagp);
  // ffn2: gelu(h) @ W^T + bias + raw-input residual; dual fp32+bf16 out (outmode 5)
  {
    GB8 gb = {};
    gb.cfl[0] = gb.cfl[1] = 1;
    gb.A[0] = h0; gb.W[0] = wffn2; gb.bias[0] = in[13]; gb.resid[0] = in[0]; gb.rfli[0] = 0;
    gb.Cf[0] = dbuf0; gb.Cb[0] = dbuf0b; gb.osc[0] = 1.f;
    gb.A[1] = h1; gb.W[1] = wffn2; gb.bias[1] = in[13]; gb.resid[1] = in[1]; gb.rfli[1] = 0;
    gb.Cf[1] = dbuf1; gb.Cb[1] = dbuf1b; gb.osc[1] = 1.f;
    k_gemmb<<<dim3(4, 64, 2), 256, 0, stream>>>(gb, 512, 512, 256, 256, 256, 512, 1, 5, flagp);
  }

  // ---------------- cross attention (both directions in ONE launch) ----------------
  const float s4 = 0.35355339059327373f;  // 64^-0.25
  {
    GB8 gb = {};
    gb.cfl[0] = gb.cfl[1] = gb.cfl[2] = gb.cfl[3] = 1;
    gb.afli[0] = gb.afli[1] = gb.afli[2] = gb.afli[3] = 1;
    gb.A[0] = dbuf0b; gb.W[0] = wcqk; gb.bias[0] = in[24]; gb.Cb[0] = qc; gb.osc[0] = s4 * LOG2E;
    gb.A[1] = dbuf1b; gb.W[1] = wcqk; gb.bias[1] = in[24]; gb.Cb[1] = kc; gb.osc[1] = s4;
    gb.A[2] = dbuf0b; gb.W[2] = wcv;  gb.bias[2] = in[26]; gb.Cb[2] = vc; gb.osc[2] = 1.f;
    gb.A[3] = dbuf1b; gb.W[3] = wcv;  gb.bias[3] = in[26]; gb.Cb[3] = oc; gb.osc[3] = 1.f;
    k_gemmb<<<dim3(4, 64, 4), 256, 0, stream>>>(gb, 256, 256, 256, 256, 0, 256, 0, 3, flagp);
  }
  // pseudo-b 0..3 over contiguous {qc,kc}: Q = qc+b*sbF, K/V index b^2
  k_attn_mfma<<<dim3(L_/64, 16, NZ), 256, 0, stream>>>(
      qc, sbF, shF, slF, qc, sbF, shF, slF, vc, sbF, shF, slF,
      Opart, mml, mll, L_, H_, kchunk, 2);
  k_attn_comb<<<8192, 256, 0, stream>>>(Opart, mml, mll, cm, BHLb, NZ);
  {
    GB8 gb = {};
    gb.cfl[0] = gb.cfl[1] = 1;
    gb.afli[0] = gb.afli[1] = 1;
    gb.A[0] = cm;           gb.W[0] = wcout; gb.bias[0] = in[28]; gb.Cb[0] = catAb + 256;
    gb.csrc[0] = dbuf0;     gb.cdst[0] = catAb; gb.osc[0] = 1.f;
    gb.A[1] = cm + 1048576; gb.W[1] = wcout; gb.bias[1] = in[28]; gb.Cb[1] = catBb + 256;
    gb.csrc[1] = dbuf1;     gb.cdst[1] = catBb; gb.osc[1] = 1.f;
    k_gemmb<<<dim3(4, 64, 2), 256, 0, stream>>>(gb, 256, 256, 256, 512, 0, 256, 0, 3, flagp);
  }
  // ca-ffn1 split-K=2 per descriptor (z=4); A = bf16 catA/B
  {
    GB8 gb = {};
    gb.cfl[0] = gb.cfl[1] = gb.cfl[2] = gb.cfl[3] = 1;
    gb.afli[0] = gb.afli[1] = gb.afli[2] = gb.afli[3] = 1;
    gb.A[0] = catAb;       gb.W[0] = wcf1; gb.bias[0] = in[30]; gb.Cf[0] = h0;    gb.osc[0] = 1.f;
    gb.A[1] = catAb + 256; gb.W[1] = wcf1; gb.wkoff[1] = 256;   gb.Cf[1] = part0; gb.osc[1] = 1.f;
    gb.A[2] = catBb;       gb.W[2] = wcf1; gb.bias[2] = in[30]; gb.Cf[2] = h1;    gb.osc[2] = 1.f;
    gb.A[3] = catBb + 256; gb.W[3] = wcf1; gb.wkoff[3] = 256;   gb.Cf[3] = part1; gb.osc[3] = 1.f;
    k_gemmb<<<dim3(8, 64, 4), 256, 0, stream>>>(gb, 512, 256, 512, 512, 0, 512, 0, 0, flagp);
  }
  k_ln2<<<2048, 256, 0, stream>>>(h0, part0, h1, part1, in[31], in[32], flagp);
  {
    GB8 gb = {};
    gb.cfl[0] = gb.cfl[1] = 1;
    gb.rfli[0] = gb.rfli[1] = 1;
    gb.A[0] = h0; gb.W[0] = wcf2; gb.bias[0] = in[34]; gb.resid[0] = dbuf0;
    gb.Cf[0] = (float*)d_out; gb.Cb[0] = (u16*)d_out; gb.osc[0] = 1.f;
    gb.A[1] = h1; gb.W[1] = wcf2; gb.bias[1] = in[34]; gb.resid[1] = dbuf1;
    gb.Cf[1] = (float*)d_out + BLE; gb.Cb[1] = (u16*)d_out + BLE; gb.osc[1] = 1.f;
    k_gemmb<<<dim3(4, 64, 2), 256, 0, stream>>>(gb, 512, 512, 256, 256, 256, 512, 1, 2, flagp);
  }
}

// Round 11
// 588.267 us; speedup vs baseline: 1.3942x; 1.0310x over previous
//
#include <hip/hip_runtime.h>

typedef unsigned short u16;
typedef short s16;
typedef s16 s16x8 __attribute__((ext_vector_type(8)));
typedef float f32x4 __attribute__((ext_vector_type(4)));

__device__ __forceinline__ float bf2f(u16 u){
  union { unsigned int i; float f; } v; v.i = ((unsigned int)u) << 16; return v.f;
}
__device__ __forceinline__ u16 f2bf(float f){
  union { float f; unsigned int u; } v; v.f = f;
  unsigned int r = (v.u + 0x7fffu + ((v.u >> 16) & 1u)) >> 16;
  return (u16)r;
}
// packed f32x2 -> bf16x2 (RNE, identical to f2bf) in ONE VALU op
__device__ __forceinline__ unsigned int cvtpk(float lo, float hi){
  unsigned int d;
  asm("v_cvt_pk_bf16_f32 %0, %1, %2" : "=v"(d) : "v"(lo), "v"(hi));
  return d;
}
__device__ __forceinline__ uint4 pack8(float4 a0, float4 a1){
  uint4 v;
  v.x = cvtpk(a0.x, a0.y); v.y = cvtpk(a0.z, a0.w);
  v.z = cvtpk(a1.x, a1.y); v.w = cvtpk(a1.z, a1.w);
  return v;
}
__device__ __forceinline__ float gelu_f(float x){
  return 0.5f * x * (1.f + erff(x * 0.70710678118654752440f));
}
__device__ __forceinline__ float ldw(const void* p, long i, int fl){
  return fl ? bf2f(((const u16*)p)[i]) : ((const float*)p)[i];
}
__device__ __forceinline__ float4 ldw4(const void* p, long i, int fl){
  if (fl){
    ushort4 w = *(const ushort4*)((const u16*)p + i);
    return make_float4(bf2f(w.x), bf2f(w.y), bf2f(w.z), bf2f(w.w));
  }
  return *(const float4*)((const float*)p + i);
}

// ---- DPP 16-lane butterfly reductions (VALU pipe, zero LDS traffic) ----
template<int C>
__device__ __forceinline__ float dppf(float x){
  return __int_as_float(__builtin_amdgcn_update_dpp(0, __float_as_int(x), C, 0xf, 0xf, true));
}
__device__ __forceinline__ float dppmax16(float v){
  v = fmaxf(v, dppf<0xB1>(v));
  v = fmaxf(v, dppf<0x4E>(v));
  v = fmaxf(v, dppf<0x141>(v));
  v = fmaxf(v, dppf<0x140>(v));
  return v;
}
__device__ __forceinline__ float dppsum16(float v){
  v += dppf<0xB1>(v);
  v += dppf<0x4E>(v);
  v += dppf<0x141>(v);
  v += dppf<0x140>(v);
  return v;
}

// ---------------- dtype sniffer (flag[0]=dtype, flag[1]=0, flag[2]=1) --------
__global__ __launch_bounds__(256) void k_sniff(const unsigned int* __restrict__ w,
                                               int n, int* __restrict__ flag){
  __shared__ int cnt[256];
  int c = 0;
  for (int i = threadIdx.x; i < n; i += 256){
    unsigned e = (w[i] >> 7) & 0xFFu;
    c += (e >= 120u && e <= 127u) ? 1 : 0;
  }
  cnt[threadIdx.x] = c; __syncthreads();
  for (int s = 128; s > 0; s >>= 1){
    if (threadIdx.x < s) cnt[threadIdx.x] += cnt[threadIdx.x + s];
    __syncthreads();
  }
  if (threadIdx.x == 0) flag[0] = (2 * cnt[0] > n) ? 1 : 0;
  if (threadIdx.x == 1) flag[1] = 0;
  if (threadIdx.x == 2) flag[2] = 1;
}

// ---- conversion: 11 weights + 2 inputs -> contiguous bf16 buffer ----
struct WC { const void* src[13]; int off[14]; };
__global__ __launch_bounds__(256) void k_wconv(WC wc, u16* __restrict__ dst,
                                               const int* __restrict__ flagp){
  int fl = *flagp;
  int i = blockIdx.x * 256 + threadIdx.x;
  if (i >= wc.off[13]) return;
  int s = 0;
  #pragma unroll
  for (int t = 1; t < 13; ++t) s += (i >= wc.off[t]) ? 1 : 0;
  dst[i] = f2bf(ldw(wc.src[s], i - wc.off[s], fl));
}

// ---- zero-pad xproj (48x256 -> 64x256) / dt_w (256x16 -> 256x64) -> bf16; dt_b fp32 ----
__global__ __launch_bounds__(256) void k_pad(
  const void* __restrict__ wx, const void* __restrict__ wd,
  const void* __restrict__ bd,
  u16* __restrict__ px, u16* __restrict__ pd, float* __restrict__ pb,
  const int* __restrict__ flagp)
{
  int fl = *flagp;
  int i = blockIdx.x * 256 + threadIdx.x;
  if (i < 16384){
    int r = i >> 8, c = i & 255;
    px[i] = f2bf((r < 48) ? ldw(wx, r*256 + c, fl) : 0.f);
  } else if (i < 32768){
    int j = i - 16384;
    int n = j >> 6, k = j & 63;
    pd[j] = f2bf((k < 16) ? ldw(wd, n*16 + k, fl) : 0.f);
  } else if (i < 33024){
    pb[i - 32768] = ldw(bd, i - 32768, fl);
  }
}

// ---------------- MFMA GEMM (staged 64x64 tile; weights always bf16) ----------------
// outmode: 0 fp32, 2 dynamic, 3 bf16,
//          4 softplus(dt+2*bias) -> Cf TRANSPOSED (d-major), delta*resid -> C2 TRANSPOSED.
// A1/coff1/c2off1: optional z-batch (blockIdx.z==1 uses A1, Cf+coff1, C2+c2off1).
__global__ __launch_bounds__(256) void k_gemm_mfma(
  const void* __restrict__ A0, int aflidx, int lda, int K, int N,
  const u16* __restrict__ W, const u16* __restrict__ W2, int nsplit, int wflidx,
  const void* __restrict__ bias,
  float* __restrict__ Cf0, u16* __restrict__ Cb, int ldc,
  float* __restrict__ C20, int ldc2,
  const void* __restrict__ resid, int rflidx, int ldr,
  float oscale, int act_gelu, int outmode,
  const void* __restrict__ A1, long coff1, long c2off1,
  const int* __restrict__ flagp)
{
  const int fl  = flagp[0];
  const int afl = flagp[aflidx];
  const int wfl = flagp[wflidx];     // bias dtype only
  const int rfl = flagp[rflidx];
  const void* A = A0;
  float* Cf = Cf0;
  float* C2 = C20;
  if (blockIdx.z){ A = A1; Cf += coff1; C2 += c2off1; }
  __shared__ u16 As[64*72];
  __shared__ u16 Bs[64*72];
  const int tid = threadIdx.x;
  const int w = tid >> 6, lane = tid & 63, quad = lane >> 4, m = lane & 15;
  const int m0 = blockIdx.y << 6, n0 = blockIdx.x << 6;
  const int srow = tid >> 2, sc0 = (tid & 3) << 4;
  const int reg2 = (n0 >= nsplit);
  const u16* Wp = reg2 ? W2 : W;
  const int nbase = reg2 ? nsplit : 0;

  f32x4 acc[4];
  #pragma unroll
  for (int ct = 0; ct < 4; ++ct) acc[ct] = (f32x4){0.f,0.f,0.f,0.f};

  for (int k0 = 0; k0 < K; k0 += 64){
    {
      long ab = (long)(m0 + srow) * lda + k0 + sc0;
      if (afl && !act_gelu){
        #pragma unroll
        for (int g = 0; g < 2; ++g)
          *(uint4*)&As[srow*72 + sc0 + g*8] = *(const uint4*)((const u16*)A + ab + g*8);
      } else {
        #pragma unroll
        for (int g = 0; g < 2; ++g){
          float4 a0 = ldw4(A, ab + g*8, afl);
          float4 a1 = ldw4(A, ab + g*8 + 4, afl);
          if (act_gelu){
            a0.x=gelu_f(a0.x); a0.y=gelu_f(a0.y); a0.z=gelu_f(a0.z); a0.w=gelu_f(a0.w);
            a1.x=gelu_f(a1.x); a1.y=gelu_f(a1.y); a1.z=gelu_f(a1.z); a1.w=gelu_f(a1.w);
          }
          *(uint4*)&As[srow*72 + sc0 + g*8] = pack8(a0, a1);
        }
      }
    }
    {
      long wb = (long)(n0 + srow - nbase) * K + k0 + sc0;
      #pragma unroll
      for (int g = 0; g < 2; ++g)
        *(uint4*)&Bs[srow*72 + sc0 + g*8] = *(const uint4*)(Wp + wb + g*8);
    }
    __syncthreads();

    s16x8 av[2];
    #pragma unroll
    for (int s = 0; s < 2; ++s)
      av[s] = *(const s16x8*)&As[(w*16 + m)*72 + s*32 + quad*8];
    #pragma unroll
    for (int ct = 0; ct < 4; ++ct)
      #pragma unroll
      for (int s = 0; s < 2; ++s){
        s16x8 bv = *(const s16x8*)&Bs[(ct*16 + m)*72 + s*32 + quad*8];
        acc[ct] = __builtin_amdgcn_mfma_f32_16x16x32_bf16(av[s], bv, acc[ct], 0, 0, 0);
      }
    __syncthreads();
  }

  if (outmode == 4){
    // transposed float4 stores: acc[ct] = 4 consecutive rows for column gn
    const int gmb = m0 + w*16 + quad*4;
    #pragma unroll
    for (int ct = 0; ct < 4; ++ct){
      int gn = n0 + ct*16 + m;
      float bv = ldw(bias, gn, wfl);
      float dl4[4], dx4[4];
      #pragma unroll
      for (int r = 0; r < 4; ++r){
        float dl = acc[ct][r] + bv + bv;     // dt + 2*dt_bias (ref's double add)
        float delta = (dl > 20.f) ? dl : __logf(1.f + __expf(dl));
        dl4[r] = delta;
        dx4[r] = delta * ldw(resid, (long)(gmb + r) * ldr + gn, rfl);
      }
      *(float4*)&Cf[(long)gn * ldc + gmb] = make_float4(dl4[0], dl4[1], dl4[2], dl4[3]);
      *(float4*)&C2[(long)gn * ldc2 + gmb] = make_float4(dx4[0], dx4[1], dx4[2], dx4[3]);
    }
    return;
  }

  #pragma unroll
  for (int r = 0; r < 4; ++r){
    int gm = m0 + w*16 + quad*4 + r;
    #pragma unroll
    for (int ct = 0; ct < 4; ++ct){
      int gn = n0 + ct*16 + m;
      float v = acc[ct][r];
      if (reg2){
        C2[(long)gm * ldc2 + (gn - nsplit)] = v;
      } else {
        if (bias) v += ldw(bias, gn, wfl);
        v *= oscale;
        if (resid) v += ldw(resid, (long)gm * ldr + gn, rfl);
        long off = (long)gm * ldc + gn;
        if (outmode == 2){
          if (fl) Cb[off] = f2bf(v); else Cf[off] = v;
        } else if (outmode == 3){
          Cb[off] = f2bf(v);
        } else {
          Cf[off] = v;
        }
      }
    }
  }
}

// ---------------- z-batched MFMA GEMM (up to 8 independent problems) ----------------
// Weights always bf16. afli[z]=1: A is bf16 (plain copy path, no aux/gelu).
// outmode: 0 fp32 Cf, 2 dynamic, 3 bf16 Cb, 5 both Cf+Cb. cdst (bf16) copy from csrc.
struct GB8 {
  const void* A[8]; const u16* W[8]; const void* bias[8];
  float* Cf[8]; u16* Cb[8]; const void* resid[8];
  const void* csrc[8]; u16* cdst[8]; float osc[8];
  int cfl[8]; int wkoff[8]; int rfli[8]; int afli[8];
  const float* aux[8]; const void* dvec;
};

__global__ __launch_bounds__(256) void k_gemmb(
  GB8 gb, int lda, int K, int N, int ldc, int ldr, int ldwq,
  int act_gelu, int outmode, const int* __restrict__ flagp)
{
  const int fl = flagp[0];
  const int z = blockIdx.z;
  const void* A = gb.A[z]; const u16* W = gb.W[z]; const void* bias = gb.bias[z];
  float* Cf = gb.Cf[z]; u16* Cb = gb.Cb[z]; const void* resid = gb.resid[z];
  const void* csrc = gb.csrc[z]; u16* cdst = gb.cdst[z];
  const float osc = gb.osc[z];
  const int cfl = flagp[gb.cfl[z]];
  const int rfl = flagp[gb.rfli[z]];
  const int wkoff = gb.wkoff[z];
  const int abf = gb.afli[z];
  const float* aux = gb.aux[z];

  __shared__ u16 As[64*72];
  __shared__ u16 Bs[64*72];
  const int tid = threadIdx.x;
  const int w = tid >> 6, lane = tid & 63, quad = lane >> 4, m = lane & 15;
  const int m0 = blockIdx.y << 6, n0 = blockIdx.x << 6;
  const int srow = tid >> 2, sc0 = (tid & 3) << 4;

  f32x4 acc[4];
  #pragma unroll
  for (int ct = 0; ct < 4; ++ct) acc[ct] = (f32x4){0.f,0.f,0.f,0.f};

  for (int k0 = 0; k0 < K; k0 += 64){
    if (abf){
      const u16* ar = (const u16*)A + (long)(m0 + srow) * lda + k0 + sc0;
      #pragma unroll
      for (int g = 0; g < 2; ++g)
        *(uint4*)&As[srow*72 + sc0 + g*8] = *(const uint4*)(ar + g*8);
    } else {
      const float* ar = (const float*)A + (long)(m0 + srow) * lda + k0 + sc0;
      #pragma unroll
      for (int g = 0; g < 2; ++g){
        float4 a0 = *(const float4*)(ar + g*8);
        float4 a1 = *(const float4*)(ar + g*8 + 4);
        if (aux){
          const float* xr = aux + (long)(m0 + srow) * lda + k0 + sc0;
          float4 x0 = *(const float4*)(xr + g*8);
          float4 x1 = *(const float4*)(xr + g*8 + 4);
          float4 d0 = ldw4(gb.dvec, k0 + sc0 + g*8, fl);
          float4 d1 = ldw4(gb.dvec, k0 + sc0 + g*8 + 4, fl);
          a0.x += d0.x*x0.x; a0.y += d0.y*x0.y; a0.z += d0.z*x0.z; a0.w += d0.w*x0.w;
          a1.x += d1.x*x1.x; a1.y += d1.y*x1.y; a1.z += d1.z*x1.z; a1.w += d1.w*x1.w;
        }
        if (act_gelu){
          a0.x=gelu_f(a0.x); a0.y=gelu_f(a0.y); a0.z=gelu_f(a0.z); a0.w=gelu_f(a0.w);
          a1.x=gelu_f(a1.x); a1.y=gelu_f(a1.y); a1.z=gelu_f(a1.z); a1.w=gelu_f(a1.w);
        }
        *(uint4*)&As[srow*72 + sc0 + g*8] = pack8(a0, a1);
      }
    }
    {
      long wb = (long)(n0 + srow) * ldwq + wkoff + k0 + sc0;
      #pragma unroll
      for (int g = 0; g < 2; ++g)
        *(uint4*)&Bs[srow*72 + sc0 + g*8] = *(const uint4*)(W + wb + g*8);
    }
    __syncthreads();

    s16x8 av[2];
    #pragma unroll
    for (int s = 0; s < 2; ++s)
      av[s] = *(const s16x8*)&As[(w*16 + m)*72 + s*32 + quad*8];
    #pragma unroll
    for (int ct = 0; ct < 4; ++ct)
      #pragma unroll
      for (int s = 0; s < 2; ++s){
        s16x8 bv = *(const s16x8*)&Bs[(ct*16 + m)*72 + s*32 + quad*8];
        acc[ct] = __builtin_amdgcn_mfma_f32_16x16x32_bf16(av[s], bv, acc[ct], 0, 0, 0);
      }
    __syncthreads();
  }

  #pragma unroll
  for (int r = 0; r < 4; ++r){
    int gm = m0 + w*16 + quad*4 + r;
    #pragma unroll
    for (int ct = 0; ct < 4; ++ct){
      int gn = n0 + ct*16 + m;
      float v = acc[ct][r];
      if (bias) v += ldw(bias, gn, fl);
      v *= osc;
      if (resid) v += ldw(resid, (long)gm * ldr + gn, rfl);
      long off = (long)gm * ldc + gn;
      if (outmode == 2){
        if (fl) Cb[off] = f2bf(v); else Cf[off] = v;
      } else if (outmode == 3){
        Cb[off] = f2bf(v);
      } else if (outmode == 5){
        Cf[off] = v; Cb[off] = f2bf(v);
      } else {
        Cf[off] = v;
      }
      if (cdst) cdst[(long)gm * ldc + gn] = f2bf(ldw(csrc, (long)gm * 256 + gn, cfl));
    }
  }
}

// ---------------- QKV extract + rotary, 2-descriptor batched --------------
// grid.y = 16: bh = dsc*8 + b*4 + h. Output bf16 head-major (bh,L,64).
// q pre-scaled by 0.125*log2(e): scores land in log2 domain (exp2 softmax).
__global__ __launch_bounds__(256) void k_rope(
  const float* __restrict__ qkv0, const float* __restrict__ qkv1,
  const void* __restrict__ pe0, const void* __restrict__ pe1,
  u16* __restrict__ q, u16* __restrict__ k, u16* __restrict__ v,
  int L, int B, int H, const int* __restrict__ flagp)
{
  int fl = *flagp;
  int tid = threadIdx.x;
  int lq = tid >> 6, d = tid & 63;
  int l = blockIdx.x * 4 + lq;
  int bh = blockIdx.y;
  int dsc = bh >> 3;
  int bh7 = bh & 7;
  int b = bh7 >> 2, h = bh7 & 3;
  const float* qkv = dsc ? qkv1 : qkv0;
  const void* pe = dsc ? pe1 : pe0;
  const float* row = qkv + ((long)b * L + l) * 768 + h * 192;
  float qv = row[d*3+0], kv = row[d*3+1], vv = row[d*3+2];
  int dn = (d & 1) ? (d - 1) : (d + 1);
  float qn = row[dn*3+0], kn = row[dn*3+1];
  float rq = (d & 1) ? qn : -qn;
  float rk = (d & 1) ? kn : -kn;
  long peo = ((long)b * L + l) * 64 + d;
  float p0 = ldw(pe, peo, fl);
  float p1 = ldw(pe, (long)B * L * 64 + peo, fl);
  long o = ((long)bh * L + l) * 64 + d;
  q[o] = f2bf((qv * p0 + rq * p1) * 0.18033688011112042f);  // 0.125 * log2(e)
  k[o] = f2bf(kv * p0 + rk * p1);
  v[o] = f2bf(vv);
}

// ---------------- MFMA flash attention, bf16 in / fp32 partials out ------
// Scores in log2 domain (exp2 softmax). K-split via blockIdx.z (NZ=2).
// bxor: K/V batch index = b^bxor. Lazy row-max (per-lane detect, cross-lane
// only on rescale); per-lane l-partials, one dppsum at epilogue.
// XCD swizzle (grid 32x16x2 only): keep all 32 q-blocks of a (bh,z) combo
// on one XCD so its K/V panel stays in that XCD's L2.
__global__ __launch_bounds__(256, 8) void k_attn_mfma(
  const u16* __restrict__ Q, long qsb, long qsh, long qsl,
  const u16* __restrict__ Kp, long ksb, long ksh, long ksl,
  const u16* __restrict__ Vp, long vsb, long vsh, long vsl,
  float* __restrict__ Opart, float* __restrict__ mpart, float* __restrict__ lpart,
  int L, int H, int kchunk, int bxor)
{
  __shared__ u16 Kt[64*72];
  __shared__ u16 Vt[64*72];
  __shared__ u16 Ps[64*72];     // wave-private rows: no barrier needed around it
  const int tid  = threadIdx.x;
  const int w    = tid >> 6;
  const int lane = tid & 63;
  const int quad = lane >> 4;
  const int m    = lane & 15;

  int bx = blockIdx.x, by = blockIdx.y, bz = blockIdx.z;
  if (gridDim.x == 32 && gridDim.y == 16 && gridDim.z == 2){
    int lid = bx + (by << 5) + (bz << 9);
    int xcd = lid & 7, slot = lid >> 3;
    int combo = xcd * 4 + (slot >> 5);
    bx = slot & 31; by = combo & 15; bz = combo >> 4;
  }
  const int bh = by, b = bh / H, h = bh % H;
  const int iq0 = bx * 64;
  const int z = bz;
  const long BHL = (long)gridDim.y * L;

  const u16* Qb = Q  + (long)b*qsb + h*qsh;
  const u16* Kb = Kp + (long)(b^bxor)*ksb + h*ksh;
  const u16* Vb = Vp + (long)(b^bxor)*vsb + h*vsh;

  s16x8 aq[2];
  {
    const u16* qr = Qb + (long)(iq0 + w*16 + m) * qsl + quad*8;
    aq[0] = *(const s16x8*)(qr);
    aq[1] = *(const s16x8*)(qr + 32);
  }

  f32x4 o_acc[4];
  #pragma unroll
  for (int nt = 0; nt < 4; ++nt) o_acc[nt] = (f32x4){0.f,0.f,0.f,0.f};
  float mrow[4] = {-1e30f,-1e30f,-1e30f,-1e30f};
  float lsum[4] = {0.f,0.f,0.f,0.f};     // per-lane partials; reduced at end

  const int srow = tid >> 2, sc0 = (tid & 3) << 4;
  const int kg = tid & 15;
  const int dg = tid >> 4;
  const int vcb = ((((dg >> 2) * 2) + (kg >> 1)) & 7) * 8 + (kg & 1) * 4;
  const int modd = m & 1;
  const int pcolb = m & 6;
  const int jend = z * kchunk + kchunk;

  for (int j0 = z * kchunk; j0 < jend; j0 += 64){
    {
      const u16* kr = Kb + (long)(j0 + srow) * ksl + sc0;
      *(uint4*)&Kt[srow*72 + sc0]     = *(const uint4*)kr;
      *(uint4*)&Kt[srow*72 + sc0 + 8] = *(const uint4*)(kr + 8);
      const u16* vr = Vb + (long)(j0 + 4*kg) * vsl + 4*dg;
      ushort4 r0 = *(const ushort4*)(vr);
      ushort4 r1 = *(const ushort4*)(vr + vsl);
      ushort4 r2 = *(const ushort4*)(vr + 2*vsl);
      ushort4 r3 = *(const ushort4*)(vr + 3*vsl);
      u16* vt = &Vt[(4*dg)*72 + vcb];
      *(ushort4*)(vt)       = make_ushort4(r0.x, r1.x, r2.x, r3.x);
      *(ushort4*)(vt + 72)  = make_ushort4(r0.y, r1.y, r2.y, r3.y);
      *(ushort4*)(vt + 144) = make_ushort4(r0.z, r1.z, r2.z, r3.z);
      *(ushort4*)(vt + 216) = make_ushort4(r0.w, r1.w, r2.w, r3.w);
    }
    __syncthreads();

    float sv[4][4];
    #pragma unroll
    for (int ct = 0; ct < 4; ++ct){
      f32x4 acc = (f32x4){0.f,0.f,0.f,0.f};
      #pragma unroll
      for (int s = 0; s < 2; ++s){
        s16x8 bk = *(const s16x8*)&Kt[(ct*16 + m)*72 + s*32 + quad*8];
        acc = __builtin_amdgcn_mfma_f32_16x16x32_bf16(aq[s], bk, acc, 0, 0, 0);
      }
      #pragma unroll
      for (int r = 0; r < 4; ++r) sv[ct][r] = acc[r];
    }

    // lazy defer-max: per-lane detect only; cross-lane max only when rescale fires.
    // (any lane's local max > mrow+8  <=>  group max > mrow+8)
    float v0[4];
    int need = 0;
    #pragma unroll
    for (int r = 0; r < 4; ++r){
      v0[r] = fmaxf(fmaxf(sv[0][r], sv[1][r]), fmaxf(sv[2][r], sv[3][r]));
      need |= (v0[r] > mrow[r] + 8.f) ? 1 : 0;
    }
    if (__any(need)){
      float alpha[4];
      #pragma unroll
      for (int r = 0; r < 4; ++r){
        float mx = dppmax16(v0[r]);
        float mn = fmaxf(mrow[r], mx);
        alpha[r] = exp2f(mrow[r] - mn);
        mrow[r] = mn;
        lsum[r] *= alpha[r];
      }
      #pragma unroll
      for (int nt = 0; nt < 4; ++nt)
        #pragma unroll
        for (int r = 0; r < 4; ++r) o_acc[nt][r] *= alpha[r];
    }
    #pragma unroll
    for (int ct = 0; ct < 4; ++ct)
      #pragma unroll
      for (int r = 0; r < 4; ++r){
        float p = exp2f(sv[ct][r] - mrow[r]);
        sv[ct][r] = p;
        lsum[r] += p;
      }

    // Ps packed b32 writes (DPP xor1 pair exchange + cvt_pk)
    #pragma unroll
    for (int ct = 0; ct < 4; ++ct){
      const int kb = (2*w + 2*ct + (m >> 3)) & 7;
      const int col = (kb << 3) | pcolb;
      #pragma unroll
      for (int rr = 0; rr < 2; ++rr){
        float nb_lo = dppf<0xB1>(sv[ct][rr]);
        float nb_hi = dppf<0xB1>(sv[ct][2+rr]);
        float lo = modd ? nb_hi       : sv[ct][rr];
        float hi = modd ? sv[ct][2+rr] : nb_lo;
        unsigned int pk = cvtpk(lo, hi);
        int row = w*16 + quad*4 + rr + 2*modd;
        *(unsigned int*)&Ps[row*72 + col] = pk;
      }
    }
    asm volatile("s_waitcnt lgkmcnt(0)" ::: "memory");  // own-wave rows RAW

    s16x8 ap[2];
    #pragma unroll
    for (int s = 0; s < 2; ++s)
      ap[s] = *(const s16x8*)&Ps[(w*16 + m)*72 + (((2*w + 4*s + quad) & 7) << 3)];
    #pragma unroll
    for (int nt = 0; nt < 4; ++nt)
      #pragma unroll
      for (int s = 0; s < 2; ++s){
        s16x8 bv = *(const s16x8*)&Vt[(nt*16 + m)*72 + (((2*nt + 4*s + quad) & 7) << 3)];
        o_acc[nt] = __builtin_amdgcn_mfma_f32_16x16x32_bf16(ap[s], bv, o_acc[nt], 0, 0, 0);
      }
    __syncthreads();
  }

  const long zOoff = (long)z * BHL * 64;
  #pragma unroll
  for (int r = 0; r < 4; ++r){
    int iq = iq0 + w*16 + quad*4 + r;
    long rowid = ((long)b*L + iq) * H + h;
    #pragma unroll
    for (int nt = 0; nt < 4; ++nt)
      Opart[zOoff + rowid*64 + nt*16 + m] = o_acc[nt][r];
    float lr = dppsum16(lsum[r]);        // one reduction per row (was per-iter)
    if (m == 0){
      mpart[(long)z*BHL + rowid] = mrow[r];
      lpart[(long)z*BHL + rowid] = lr;
    }
  }
}

// ---------------- attention split combine (nz-way, log2-domain m; bf16 out) --------
__global__ __launch_bounds__(256) void k_attn_comb(
  const float* Opart, const float* mpart, const float* lpart,
  u16* O, long BHL, int nz)
{
  long i = (long)blockIdx.x * 256 + threadIdx.x;
  long row = i >> 6;
  float mv[4];
  float M = -1e30f;
  for (int z = 0; z < nz; ++z){
    mv[z] = mpart[(long)z*BHL + row];
    M = fmaxf(M, mv[z]);
  }
  long N64 = BHL * 64;
  float T = 0.f, acc = 0.f;
  for (int z = 0; z < nz; ++z){
    float wz = exp2f(mv[z] - M);
    T   += lpart[(long)z*BHL + row] * wz;
    acc += Opart[(long)z*N64 + i] * wz;
  }
  O[i] = f2bf(acc / T);
}

// ---------------- depthwise conv K=5 SAME + silu (batched pseudo-b) ------
// x path: fp32 + bf16 outputs; z path: bf16 only.
__global__ __launch_bounds__(256) void k_conv2(
  const float* __restrict__ xz,
  const void* __restrict__ wx, const void* __restrict__ wz,
  float* __restrict__ outxf, u16* __restrict__ outxb, u16* __restrict__ outzb,
  int L, const int* __restrict__ flagp)
{
  int fl = *flagp;
  int c = threadIdx.x;
  int bl = blockIdx.x; int b = bl / L, l = bl % L;
  int choff = blockIdx.y ? 256 : 0;
  const void* w = blockIdx.y ? wz : wx;
  const float* base = xz + ((long)b * L) * 512 + choff + c;
  float s = 0.f;
  #pragma unroll
  for (int kk = 0; kk < 5; ++kk){
    int ll = l + kk - 2;
    if (ll >= 0 && ll < L) s += base[(long)ll * 512] * ldw(w, c*5 + kk, fl);
  }
  s = s / (1.f + __expf(-s));   // silu
  long idx = ((long)b * L + l) * 256 + c;
  if (blockIdx.y){
    outzb[idx] = f2bf(s);
  } else {
    outxf[idx] = s;
    outxb[idx] = f2bf(s);
  }
}

// ---------------- chunk-parallel selective scan ----------------
#define SC_CS 64
#define SC_NC 32

__global__ __launch_bounds__(256) void k_scan1(
  const float* __restrict__ deltaT, const float* __restrict__ dxcT,
  const float* __restrict__ xdbl, const void* __restrict__ Alog,
  float* __restrict__ E_out, float* __restrict__ F_out,
  int L, int ldt, const int* __restrict__ flagp)
{
  int fl = *flagp;
  int tid = threadIdx.x;
  int g = tid >> 4, n = tid & 15;
  int gid = blockIdx.x * 16 + g;
  int chunk = gid & (SC_NC - 1);
  int p = gid >> 5;
  int b = p >> 8, d = p & 255;
  float A = -__expf(ldw(Alog, d*16 + n, fl));
  const float* dTp = deltaT + (long)d*ldt + (long)b*L;
  const float* dxp = dxcT  + (long)d*ldt + (long)b*L;
  const float* xdb = xdbl + (long)b*L*64;
  int l0 = chunk * SC_CS;
  float E = 1.f, F = 0.f;
  for (int i = 0; i < SC_CS; i += 4){
    int l = l0 + i;
    float4 dt4 = *(const float4*)(dTp + l);
    float4 dx4 = *(const float4*)(dxp + l);
    float e[4], u[4];
    e[0] = __expf(dt4.x * A); e[1] = __expf(dt4.y * A);
    e[2] = __expf(dt4.z * A); e[3] = __expf(dt4.w * A);
    u[0] = dx4.x * xdb[(l+0)*64 + 16 + n];
    u[1] = dx4.y * xdb[(l+1)*64 + 16 + n];
    u[2] = dx4.z * xdb[(l+2)*64 + 16 + n];
    u[3] = dx4.w * xdb[(l+3)*64 + 16 + n];
    F = e[0]*F + u[0]; F = e[1]*F + u[1];
    F = e[2]*F + u[2]; F = e[3]*F + u[3];
    E *= (e[0]*e[1]) * (e[2]*e[3]);
  }
  long idx = (long)(p*16 + n) * SC_NC + chunk;
  E_out[idx] = E; F_out[idx] = F;
}

__global__ __launch_bounds__(256) void k_scan2(
  const float* __restrict__ E, const float* __restrict__ F,
  float* __restrict__ Hin)
{
  int pn = blockIdx.x * 256 + threadIdx.x;
  const float* Ep = E + (long)pn * SC_NC;
  const float* Fp = F + (long)pn * SC_NC;
  float* Hp = Hin + (long)pn * SC_NC;
  float h = 0.f;
  #pragma unroll
  for (int c = 0; c < SC_NC; ++c){
    Hp[c] = h;
    h = Ep[c] * h + Fp[c];
  }
}

// y = scan partial only (D*xc folded into o-proj GEMM A-staging)
__global__ __launch_bounds__(256) void k_scan3(
  const float* __restrict__ deltaT, const float* __restrict__ dxcT,
  const float* __restrict__ xdbl, const void* __restrict__ Alog,
  const float* __restrict__ Hin, float* __restrict__ y,
  int L, int ldt, const int* __restrict__ flagp)
{
  int fl = *flagp;
  int tid = threadIdx.x;
  int g = tid >> 4, n = tid & 15;
  int gid = blockIdx.x * 16 + g;
  int chunk = gid & (SC_NC - 1);
  int p = gid >> 5;
  int b = p >> 8, d = p & 255;
  float A = -__expf(ldw(Alog, d*16 + n, fl));
  const float* dTp = deltaT + (long)d*ldt + (long)b*L;
  const float* dxp = dxcT  + (long)d*ldt + (long)b*L;
  const float* xdb = xdbl + (long)b*L*64;
  float* yb = y + (long)b*L*256 + d;
  long idx = (long)(p*16 + n) * SC_NC + chunk;
  float h = Hin[idx];
  int l0 = chunk * SC_CS;
  for (int i = 0; i < SC_CS; i += 4){
    int l = l0 + i;
    float4 dt4 = *(const float4*)(dTp + l);
    float4 dx4 = *(const float4*)(dxp + l);
    float e[4], u[4], cm[4];
    e[0] = __expf(dt4.x * A); e[1] = __expf(dt4.y * A);
    e[2] = __expf(dt4.z * A); e[3] = __expf(dt4.w * A);
    u[0] = dx4.x * xdb[(l+0)*64 + 16 + n];
    u[1] = dx4.y * xdb[(l+1)*64 + 16 + n];
    u[2] = dx4.z * xdb[(l+2)*64 + 16 + n];
    u[3] = dx4.w * xdb[(l+3)*64 + 16 + n];
    cm[0] = xdb[(l+0)*64 + 32 + n];
    cm[1] = xdb[(l+1)*64 + 32 + n];
    cm[2] = xdb[(l+2)*64 + 32 + n];
    cm[3] = xdb[(l+3)*64 + 32 + n];
    float s0, s1, s2, s3;
    h = e[0]*h + u[0]; s0 = h * cm[0];
    h = e[1]*h + u[1]; s1 = h * cm[1];
    h = e[2]*h + u[2]; s2 = h * cm[2];
    h = e[3]*h + u[3]; s3 = h * cm[3];
    s0 += __shfl_xor(s0, 1, 16); s1 += __shfl_xor(s1, 1, 16);
    s2 += __shfl_xor(s2, 1, 16); s3 += __shfl_xor(s3, 1, 16);
    s0 += __shfl_xor(s0, 2, 16); s1 += __shfl_xor(s1, 2, 16);
    s2 += __shfl_xor(s2, 2, 16); s3 += __shfl_xor(s3, 2, 16);
    s0 += __shfl_xor(s0, 4, 16); s1 += __shfl_xor(s1, 4, 16);
    s2 += __shfl_xor(s2, 4, 16); s3 += __shfl_xor(s3, 4, 16);
    s0 += __shfl_xor(s0, 8, 16); s1 += __shfl_xor(s1, 8, 16);
    s2 += __shfl_xor(s2, 8, 16); s3 += __shfl_xor(s3, 8, 16);
    if (n < 4){
      float out = (n == 0) ? s0 : (n == 1) ? s1 : (n == 2) ? s2 : s3;
      yb[(long)(l + n)*256] = out;
    }
  }
}

// two-buffer LN with split-K partial sum (both descriptors batched)
__global__ __launch_bounds__(256) void k_ln2(
  float* __restrict__ hA, const float* __restrict__ hA2,
  float* __restrict__ hB, const float* __restrict__ hB2,
  const void* __restrict__ g, const void* __restrict__ beta,
  const int* __restrict__ flagp)
{
  int fl = *flagp;
  int r = blockIdx.x * 4 + (threadIdx.x >> 6);
  float* hbase = (r < 4096) ? hA : hB;
  const float* h2base = (r < 4096) ? hA2 : hB2;
  int row = r & 4095;
  int lane = threadIdx.x & 63;
  float* hr = hbase + (long)row * 512;
  const float* h2r = h2base + (long)row * 512;
  float v[8]; float s = 0.f, ss = 0.f;
  #pragma unroll
  for (int i = 0; i < 8; ++i){
    v[i] = hr[lane + 64*i] + h2r[lane + 64*i];
    s += v[i]; ss += v[i]*v[i];
  }
  #pragma unroll
  for (int off = 1; off < 64; off <<= 1){ s += __shfl_xor(s, off); ss += __shfl_xor(ss, off); }
  float mean = s * (1.f/512.f);
  float var  = ss * (1.f/512.f) - mean * mean;
  float rs = rsqrtf(var + 1e-5f);
  #pragma unroll
  for (int i = 0; i < 8; ++i){
    int c = lane + 64*i;
    hr[c] = (v[i] - mean) * rs * ldw(g, c, fl) + ldw(beta, c, fl);
  }
}

extern "C" void kernel_launch(void* const* d_in, const int* in_sizes, int n_in,
                              void* d_out, int out_size, void* d_ws, size_t ws_size,
                              hipStream_t stream)
{
  const int B_ = 2, L_ = 2048, H_ = 4;
  const long BLE = (long)B_ * L_ * 256;       // 1,048,576 floats
  const long BHLb = 2L * B_ * H_ * L_;        // 32,768 (batched pseudo-heads)

  int* flagp = (int*)d_ws;
  float* base = (float*)d_ws + 64;

  // ---- workspace map (units of BLE fp32) ----
  float* cat0   = base + 0*BLE;    // 3 BLE, ld 768 (fp32; k_rope reads)
  float* cat1   = base + 3*BLE;
  float* xz01   = base + 6*BLE;    // 4 BLE fp32, pseudo-b ld 512
  u16*   q01    = (u16*)(base + 10*BLE);
  u16*   k01    = (u16*)(base + 11*BLE);
  u16*   v01    = (u16*)(base + 12*BLE);
  float* Opart  = base + 13*BLE;   // 4 BLE (2 z-planes x 2 BLE batched)
  u16*   obb    = (u16*)(base + 17*BLE);   // attn comb out bf16 (2M u16)
  float* mml    = base + 18*BLE;   // 2*32768
  float* mll    = mml + 2*32768;
  float* xc_f   = base + 19*BLE;   // 2 BLE fp32 (aux + dt resid)
  u16*   xcb    = (u16*)(base + 21*BLE);   // bf16 xc (xproj A)
  u16*   zcb    = (u16*)(base + 22*BLE);   // bf16 zc (o-proj A)
  float* xdbl01 = base + 23*BLE;   // 0.5 BLE
  float* delta01= base + 24*BLE;   // 2 BLE (TRANSPOSED 256 x 8192)
  float* dxc01  = base + 26*BLE;   // 2 BLE (TRANSPOSED)
  float* scE    = base + 28*BLE;
  float* scF    = scE + 524288;
  float* scH    = scF + 524288;
  float* y01    = base + 30*BLE;   // 2 BLE fp32
  u16*   catc0b = (u16*)(base + 32*BLE);   // bf16 cat (4096 x 1024) 2 BLE
  u16*   catc1b = (u16*)(base + 34*BLE);
  float* h0     = base + 36*BLE;   // 2 BLE fp32 (4096 x 512)
  float* part0  = base + 38*BLE;
  float* h1     = base + 40*BLE;
  float* part1  = base + 42*BLE;
  float* dbuf0  = base + 44*BLE;   // fp32 (resid / csrc)
  float* dbuf1  = base + 45*BLE;
  u16*   dbuf0b = (u16*)(base + 46*BLE);   // bf16 copies (cross-qkv A)
  u16*   dbuf1b = dbuf0b + 1048576;
  u16*   qc     = (u16*)(base + 47*BLE);   // cross q/k/v/o bf16, contiguous
  u16*   kc     = qc + 1048576;
  u16*   vc     = kc + 1048576;
  u16*   oc     = vc + 1048576;
  u16*   cm     = (u16*)(base + 49*BLE);   // cross comb out bf16 (2M u16)
  u16*   catAb  = (u16*)(base + 50*BLE);   // bf16 (4096 x 512) 1 BLE
  u16*   catBb  = (u16*)(base + 51*BLE);
  u16*   px     = (u16*)(base + 52*BLE);
  u16*   pd     = px + 16384;
  float* pb     = (float*)(pd + 16384);
  u16*   wbuf   = (u16*)(base + 53*BLE);   // bf16 weights + inputs (3.8M u16 = 2 BLE)

  const void* in[35];
  for (int i = 0; i < 35 && i < n_in; ++i) in[i] = d_in[i];

  // ---- bf16 buffer layout (element offsets): 11 weights + 2 inputs ----
  const int woff[14] = {
    0,        // in[4]  qkv_w       768*256
    196608,   // in[14] m_in_w      512*256
    327680,   // in[6]  attn_out_w  256*256
    393216,   // in[8]  ma_ffn_w1   512*1024
    917504,   // in[12] ma_ffn_w2   256*512
    1048576,  // in[22] m_out_w     256*256
    1114112,  // in[23] ca_qk_w     256*256
    1179648,  // in[25] ca_v_w      256*256
    1245184,  // in[27] ca_out_w    256*256
    1310720,  // in[29] ca_ffn_w1   512*512
    1572864,  // in[33] ca_ffn_w2   256*512
    1703936,  // in[0]  desc0       B*L*256
    2752512,  // in[1]  desc1
    3801088 };
  const u16* wqkv  = wbuf + woff[0];
  const u16* wxz   = wbuf + woff[1];
  const u16* wattn = wbuf + woff[2];
  const u16* wffn1 = wbuf + woff[3];
  const u16* wffn2 = wbuf + woff[4];
  const u16* wout  = wbuf + woff[5];
  const u16* wcqk  = wbuf + woff[6];
  const u16* wcv   = wbuf + woff[7];
  const u16* wcout = wbuf + woff[8];
  const u16* wcf1  = wbuf + woff[9];
  const u16* wcf2  = wbuf + woff[10];
  const u16* bin0  = wbuf + woff[11];
  const u16* bin1  = wbuf + woff[12];

  k_sniff<<<1, 256, 0, stream>>>((const unsigned int*)in[0], 2048, flagp);
  {
    WC wc = {};
    wc.src[0]=in[4]; wc.src[1]=in[14]; wc.src[2]=in[6]; wc.src[3]=in[8];
    wc.src[4]=in[12]; wc.src[5]=in[22]; wc.src[6]=in[23]; wc.src[7]=in[25];
    wc.src[8]=in[27]; wc.src[9]=in[29]; wc.src[10]=in[33];
    wc.src[11]=in[0]; wc.src[12]=in[1];
    for (int t = 0; t < 14; ++t) wc.off[t] = woff[t];
    k_wconv<<<(woff[13] + 255)/256, 256, 0, stream>>>(wc, wbuf, flagp);
  }
  k_pad<<<130, 256, 0, stream>>>(in[17], in[18], in[19], px, pd, pb, flagp);

  const int BIG = 1 << 30;
  const long sbP = (long)H_ * L_ * 64, shP = (long)L_ * 64, slP = 64;
  const long sbF = (long)L_ * 256,     shF = 64,            slF = 256;
  const int NZ = 2;
  const int kchunk = L_ / NZ;          // 1024
  const int MROWS = 4 * L_;            // 8192 (transposed ld)
  const float LOG2E = 1.4426950408889634f;

  // ---------------- batched mamba_attention (both descriptors) ----------------
  // merged qkv + xz; z-batched over descriptors; A = bf16 inputs (copy path)
  k_gemm_mfma<<<dim3(20, 64, 2), 256, 0, stream>>>(
      bin0, 2, 256, 256, 1280, wqkv, wxz, 768, 0, in[5],
      cat0, nullptr, 768, xz01, 512,
      nullptr, 1, 0, 1.f, 0, 0,
      bin1, 3*BLE, 2*BLE, flagp);
  k_rope<<<dim3(L_/4, 16), 256, 0, stream>>>(cat0, cat1, in[2], in[3],
      q01, k01, v01, L_, B_, H_, flagp);
  k_attn_mfma<<<dim3(L_/64, 16, NZ), 256, 0, stream>>>(
      q01, sbP, shP, slP, k01, sbP, shP, slP, v01, sbP, shP, slP,
      Opart, mml, mll, L_, H_, kchunk, 0);
  k_attn_comb<<<8192, 256, 0, stream>>>(Opart, mml, mll, obb, BHLb, NZ);
  k_conv2<<<dim3(2*B_*L_, 2), 256, 0, stream>>>(xz01, in[15], in[16], xc_f, xcb, zcb, L_, flagp);
  // xproj (padded N=64) A = bf16 xc; output xdbl fp32
  k_gemm_mfma<<<dim3(1, 128), 256, 0, stream>>>(
      xcb, 2, 256, 256, 64, px, nullptr, BIG, 1, nullptr,
      xdbl01, nullptr, 64, nullptr, 0,
      nullptr, 1, 0, 1.f, 0, 0,
      nullptr, 0, 0, flagp);
  // dt (padded K=64, fp32 bias, fp32 resid=xc_f) + fused softplus -> deltaT, dxcT
  k_gemm_mfma<<<dim3(4, 128), 256, 0, stream>>>(
      xdbl01, 1, 64, 64, 256, pd, nullptr, BIG, 1, pb,
      delta01, nullptr, MROWS, dxc01, MROWS,
      xc_f, 1, 256, 1.f, 0, 4,
      nullptr, 0, 0, flagp);
  k_scan1<<<2048, 256, 0, stream>>>(delta01, dxc01, xdbl01, in[20], scE, scF, L_, MROWS, flagp);
  k_scan2<<<64, 256, 0, stream>>>(scE, scF, scH);
  k_scan3<<<2048, 256, 0, stream>>>(delta01, dxc01, xdbl01, in[20], scH, y01, L_, MROWS, flagp);
  // batched s_x / c_x / o-proj (+fused raw-input copy), z=6; bf16 cat out
  {
    GB8 gb = {};
    gb.dvec = in[21];
    gb.A[0] = y01;        gb.aux[0] = xc_f;       gb.W[0] = wout; gb.Cb[0] = catc0b + 512; gb.osc[0] = 1.f; gb.cfl[0] = 1;
    gb.A[1] = zcb;        gb.afli[1] = 1;         gb.W[1] = wout; gb.Cb[1] = catc0b + 768; gb.osc[1] = 1.f; gb.cfl[1] = 1;
    gb.A[2] = obb;        gb.afli[2] = 1;         gb.W[2] = wattn; gb.bias[2] = in[7];     gb.Cb[2] = catc0b + 256;
    gb.csrc[2] = in[0];   gb.cdst[2] = catc0b;    gb.osc[2] = 1.f; gb.cfl[2] = 0;
    gb.A[3] = y01 + BLE;  gb.aux[3] = xc_f + BLE; gb.W[3] = wout; gb.Cb[3] = catc1b + 512; gb.osc[3] = 1.f; gb.cfl[3] = 1;
    gb.A[4] = zcb + 1048576; gb.afli[4] = 1;      gb.W[4] = wout; gb.Cb[4] = catc1b + 768; gb.osc[4] = 1.f; gb.cfl[4] = 1;
    gb.A[5] = obb + 1048576; gb.afli[5] = 1;      gb.W[5] = wattn; gb.bias[5] = in[7];     gb.Cb[5] = catc1b + 256;
    gb.csrc[5] = in[1];   gb.cdst[5] = catc1b;    gb.osc[5] = 1.f; gb.cfl[5] = 0;
    k_gemmb<<<dim3(4, 64, 6), 256, 0, stream>>>(gb, 256, 256, 256, 1024, 0, 256, 0, 3, flagp);
  }
  // ffn1 split-K=2 per descriptor (z=4); A = bf16 catc
  {
    GB8 gb = {};
    gb.cfl[0] = gb.cfl[1] = gb.cfl[2] = gb.cfl[3] = 1;
    gb.afli[0] = gb.afli[1] = gb.afli[2] = gb.afli[3] = 1;
    gb.A[0] = catc0b;       gb.W[0] = wffn1; gb.bias[0] = in[9]; gb.Cf[0] = h0;    gb.osc[0] = 1.f;
    gb.A[1] = catc0b + 512; gb.W[1] = wffn1; gb.wkoff[1] = 512;  gb.Cf[1] = part0; gb.osc[1] = 1.f;
    gb.A[2] = catc1b;       gb.W[2] = wffn1; gb.bias[2] = in[9]; gb.Cf[2] = h1;    gb.osc[2] = 1.f;
    gb.A[3] = catc1b + 512; gb.W[3] = wffn1; gb.wkoff[3] = 512;  gb.Cf[3] = part1; gb.osc[3] = 1.f;
    k_gemmb<<<dim3(8, 64, 4), 256, 0, stream>>>(gb, 1024, 512, 512, 512, 0, 1024, 0, 0, flagp);
  }
  k_ln2<<<2048, 256, 0, stream>>>(h0, part0, h1, part1, in[10], in[11], flagp);
  // ffn2: gelu(h) @ W^T + bias + raw-input residual; dual fp32+bf16 out (outmode 5)
  {
    GB8 gb = {};
    gb.cfl[0] = gb.cfl[1] = 1;
    gb.A[0] = h0; gb.W[0] = wffn2; gb.bias[0] = in[13]; gb.resid[0] = in[0]; gb.rfli[0] = 0;
    gb.Cf[0] = dbuf0; gb.Cb[0] = dbuf0b; gb.osc[0] = 1.f;
    gb.A[1] = h1; gb.W[1] = wffn2; gb.bias[1] = in[13]; gb.resid[1] = in[1]; gb.rfli[1] = 0;
    gb.Cf[1] = dbuf1; gb.Cb[1] = dbuf1b; gb.osc[1] = 1.f;
    k_gemmb<<<dim3(4, 64, 2), 256, 0, stream>>>(gb, 512, 512, 256, 256, 256, 512, 1, 5, flagp);
  }

  // ---------------- cross attention (both directions in ONE launch) ----------------
  const float s4 = 0.35355339059327373f;  // 64^-0.25
  {
    GB8 gb = {};
    gb.cfl[0] = gb.cfl[1] = gb.cfl[2] = gb.cfl[3] = 1;
    gb.afli[0] = gb.afli[1] = gb.afli[2] = gb.afli[3] = 1;
    gb.A[0] = dbuf0b; gb.W[0] = wcqk; gb.bias[0] = in[24]; gb.Cb[0] = qc; gb.osc[0] = s4 * LOG2E;
    gb.A[1] = dbuf1b; gb.W[1] = wcqk; gb.bias[1] = in[24]; gb.Cb[1] = kc; gb.osc[1] = s4;
    gb.A[2] = dbuf0b; gb.W[2] = wcv;  gb.bias[2] = in[26]; gb.Cb[2] = vc; gb.osc[2] = 1.f;
    gb.A[3] = dbuf1b; gb.W[3] = wcv;  gb.bias[3] = in[26]; gb.Cb[3] = oc; gb.osc[3] = 1.f;
    k_gemmb<<<dim3(4, 64, 4), 256, 0, stream>>>(gb, 256, 256, 256, 256, 0, 256, 0, 3, flagp);
  }
  // pseudo-b 0..3 over contiguous {qc,kc}: Q = qc+b*sbF, K/V index b^2
  k_attn_mfma<<<dim3(L_/64, 16, NZ), 256, 0, stream>>>(
      qc, sbF, shF, slF, qc, sbF, shF, slF, vc, sbF, shF, slF,
      Opart, mml, mll, L_, H_, kchunk, 2);
  k_attn_comb<<<8192, 256, 0, stream>>>(Opart, mml, mll, cm, BHLb, NZ);
  {
    GB8 gb = {};
    gb.cfl[0] = gb.cfl[1] = 1;
    gb.afli[0] = gb.afli[1] = 1;
    gb.A[0] = cm;           gb.W[0] = wcout; gb.bias[0] = in[28]; gb.Cb[0] = catAb + 256;
    gb.csrc[0] = dbuf0;     gb.cdst[0] = catAb; gb.osc[0] = 1.f;
    gb.A[1] = cm + 1048576; gb.W[1] = wcout; gb.bias[1] = in[28]; gb.Cb[1] = catBb + 256;
    gb.csrc[1] = dbuf1;     gb.cdst[1] = catBb; gb.osc[1] = 1.f;
    k_gemmb<<<dim3(4, 64, 2), 256, 0, stream>>>(gb, 256, 256, 256, 512, 0, 256, 0, 3, flagp);
  }
  // ca-ffn1 split-K=2 per descriptor (z=4); A = bf16 catA/B
  {
    GB8 gb = {};
    gb.cfl[0] = gb.cfl[1] = gb.cfl[2] = gb.cfl[3] = 1;
    gb.afli[0] = gb.afli[1] = gb.afli[2] = gb.afli[3] = 1;
    gb.A[0] = catAb;       gb.W[0] = wcf1; gb.bias[0] = in[30]; gb.Cf[0] = h0;    gb.osc[0] = 1.f;
    gb.A[1] = catAb + 256; gb.W[1] = wcf1; gb.wkoff[1] = 256;   gb.Cf[1] = part0; gb.osc[1] = 1.f;
    gb.A[2] = catBb;       gb.W[2] = wcf1; gb.bias[2] = in[30]; gb.Cf[2] = h1;    gb.osc[2] = 1.f;
    gb.A[3] = catBb + 256; gb.W[3] = wcf1; gb.wkoff[3] = 256;   gb.Cf[3] = part1; gb.osc[3] = 1.f;
    k_gemmb<<<dim3(8, 64, 4), 256, 0, stream>>>(gb, 512, 256, 512, 512, 0, 512, 0, 0, flagp);
  }
  k_ln2<<<2048, 256, 0, stream>>>(h0, part0, h1, part1, in[31], in[32], flagp);
  {
    GB8 gb = {};
    gb.cfl[0] = gb.cfl[1] = 1;
    gb.rfli[0] = gb.rfli[1] = 1;
    gb.A[0] = h0; gb.W[0] = wcf2; gb.bias[0] = in[34]; gb.resid[0] = dbuf0;
    gb.Cf[0] = (float*)d_out; gb.Cb[0] = (u16*)d_out; gb.osc[0] = 1.f;
    gb.A[1] = h1; gb.W[1] = wcf2; gb.bias[1] = in[34]; gb.resid[1] = dbuf1;
    gb.Cf[1] = (float*)d_out + BLE; gb.Cb[1] = (u16*)d_out + BLE; gb.osc[1] = 1.f;
    k_gemmb<<<dim3(4, 64, 2), 256, 0, stream>>>(gb, 512, 512, 256, 256, 256, 512, 1, 2, flagp);
  }
}